// Round 5
// baseline (1322.267 us; speedup 1.0000x reference)
//
#include <hip/hip_runtime.h>
#include <math.h>

// Problem constants (fixed by reference)
#define BB   4
#define SS   4096
#define DD   1024
#define HH   16
#define HDIM 64
#define CC   1024      // MAX_CHUNKS
#define DFF  4096
#define LL   4

static constexpr float F32_EPS = 1.1920928955078125e-07f;  // jnp.finfo(f32).eps

typedef __attribute__((ext_vector_type(8))) __bf16 bf16x8;
typedef __attribute__((ext_vector_type(4))) float  f32x4;

__device__ __forceinline__ uint f2bf(float f) {
    uint u = __float_as_uint(f);
    return (u + 0x7fffu + ((u >> 16) & 1u)) >> 16;   // RNE
}

// direct global->LDS DMA, 16 bytes per lane; lds dest must be wave-uniform
__device__ __forceinline__ void gl_lds16(const ushort* g, ushort* l) {
    __builtin_amdgcn_global_load_lds(
        (const __attribute__((address_space(1))) unsigned int*)g,
        (__attribute__((address_space(3))) unsigned int*)l, 16, 0, 0);
}

// ---------------- RoPE tables ----------------
__global__ void rope_init_kernel(float* __restrict__ cosT, float* __restrict__ sinT) {
    int idx = blockIdx.x * blockDim.x + threadIdx.x;   // over CC*32
    int pos = idx >> 5;
    int i   = idx & 31;
    float inv = powf(10000.0f, -(float)i / 32.0f);
    float f = (float)pos * inv;
    cosT[idx] = cosf(f);
    sinT[idx] = sinf(f);
}

// ---------------- boundary scan -> chunk starts, num_chunks ----------------
__global__ __launch_bounds__(1024) void scan_kernel(const int* __restrict__ boundary,
                                                    int* __restrict__ starts,
                                                    int* __restrict__ nch) {
    __shared__ int tmp[1024];
    int b = blockIdx.x, t = threadIdx.x;
    int base = b * SS + t * 4;
    int v0 = boundary[base + 0], v1 = boundary[base + 1];
    int v2 = boundary[base + 2], v3 = boundary[base + 3];
    int p0 = v0, p1 = p0 + v1, p2 = p1 + v2, p3 = p2 + v3;
    tmp[t] = p3;
    __syncthreads();
    for (int off = 1; off < 1024; off <<= 1) {
        int add = (t >= off) ? tmp[t - off] : 0;
        __syncthreads();
        tmp[t] += add;
        __syncthreads();
    }
    int excl = tmp[t] - p3;
    if (v0) starts[b * (CC + 1) + (excl + p0 - 1)] = t * 4 + 0;
    if (v1) starts[b * (CC + 1) + (excl + p1 - 1)] = t * 4 + 1;
    if (v2) starts[b * (CC + 1) + (excl + p2 - 1)] = t * 4 + 2;
    if (v3) starts[b * (CC + 1) + (excl + p3 - 1)] = t * 4 + 3;
    int total = tmp[1023];
    if (t == 0) nch[b] = total;
    for (int c = t; c <= CC; c += 1024)
        if (c >= total) starts[b * (CC + 1) + c] = SS;
}

// ---------------- chunk means -> h and x0 ----------------
__global__ __launch_bounds__(256) void latents_kernel(const float* __restrict__ x,
                                                      const int* __restrict__ starts,
                                                      float* __restrict__ h,
                                                      float* __restrict__ x0) {
    int c = blockIdx.x, b = blockIdx.y, t = threadIdx.x;
    int s0 = starts[b * (CC + 1) + c];
    int s1 = starts[b * (CC + 1) + c + 1];
    float a0 = 0.f, a1 = 0.f, a2 = 0.f, a3 = 0.f;
    for (int r = s0; r < s1; ++r) {
        const float4 xv = *(const float4*)&x[((size_t)(b * SS + r)) * DD + t * 4];
        a0 += xv.x; a1 += xv.y; a2 += xv.z; a3 += xv.w;
    }
    float inv = (s1 > s0) ? 1.0f / (float)(s1 - s0) : 0.0f;
    float4 o = make_float4(a0 * inv, a1 * inv, a2 * inv, a3 * inv);
    size_t off = ((size_t)(b * CC + c)) * DD + t * 4;
    *(float4*)&h[off]  = o;
    *(float4*)&x0[off] = o;
}

// ---------------- resid-mix + row RMS norm (layer-0 entry), bf16 normed out ----------------
__global__ __launch_bounds__(256) void rmsmix_kernel(const float* __restrict__ hin,
                                                     const float* __restrict__ x0,
                                                     const float* __restrict__ mix,
                                                     float* __restrict__ hout,
                                                     ushort* __restrict__ xnout) {
    int row = blockIdx.x, t = threadIdx.x;
    size_t off = (size_t)row * DD + t * 4;
    float4 hv = *(const float4*)&hin[off];
    float4 m0 = *(const float4*)&mix[t * 4];
    float4 m1 = *(const float4*)&mix[DD + t * 4];
    float4 xv = *(const float4*)&x0[off];
    hv.x = m0.x * hv.x + m1.x * xv.x;
    hv.y = m0.y * hv.y + m1.y * xv.y;
    hv.z = m0.z * hv.z + m1.z * xv.z;
    hv.w = m0.w * hv.w + m1.w * xv.w;
    float ss = hv.x * hv.x + hv.y * hv.y + hv.z * hv.z + hv.w * hv.w;
    for (int o = 32; o; o >>= 1) ss += __shfl_xor(ss, o);
    __shared__ float wsum[4];
    int lane = t & 63, wid = t >> 6;
    if (lane == 0) wsum[wid] = ss;
    __syncthreads();
    float tot = wsum[0] + wsum[1] + wsum[2] + wsum[3];
    float r = rsqrtf(tot * (1.0f / DD) + F32_EPS);
    *(float4*)&hout[off] = hv;
    uint2 pk;
    pk.x = f2bf(hv.x * r) | (f2bf(hv.y * r) << 16);
    pk.y = f2bf(hv.z * r) | (f2bf(hv.w * r) << 16);
    *(uint2*)&xnout[off] = pk;
}

// ---------------- fused: h += scale*(a0+a1); [h = m0*h+m1*x0]; xn = bf16(rms(h)) ----------------
template <int HASMIX>
__global__ __launch_bounds__(256) void residrms_kernel(float* __restrict__ h,
                                                       const float* __restrict__ a0,
                                                       const float* __restrict__ a1,
                                                       const float* __restrict__ scale,
                                                       const float* __restrict__ x0,
                                                       const float* __restrict__ mix,
                                                       ushort* __restrict__ xnout) {
    int row = blockIdx.x, t = threadIdx.x;
    size_t off = (size_t)row * DD + t * 4;
    float4 hv = *(const float4*)&h[off];
    float4 av = *(const float4*)&a0[off];
    float4 bv = *(const float4*)&a1[off];
    float4 sv = *(const float4*)&scale[t * 4];
    hv.x += sv.x * (av.x + bv.x);
    hv.y += sv.y * (av.y + bv.y);
    hv.z += sv.z * (av.z + bv.z);
    hv.w += sv.w * (av.w + bv.w);
    if (HASMIX) {
        float4 m0 = *(const float4*)&mix[t * 4];
        float4 m1 = *(const float4*)&mix[DD + t * 4];
        float4 xv = *(const float4*)&x0[off];
        hv.x = m0.x * hv.x + m1.x * xv.x;
        hv.y = m0.y * hv.y + m1.y * xv.y;
        hv.z = m0.z * hv.z + m1.z * xv.z;
        hv.w = m0.w * hv.w + m1.w * xv.w;
    }
    float ss = hv.x * hv.x + hv.y * hv.y + hv.z * hv.z + hv.w * hv.w;
    for (int o = 32; o; o >>= 1) ss += __shfl_xor(ss, o);
    __shared__ float wsum[4];
    int lane = t & 63, wid = t >> 6;
    if (lane == 0) wsum[wid] = ss;
    __syncthreads();
    float tot = wsum[0] + wsum[1] + wsum[2] + wsum[3];
    float r = rsqrtf(tot * (1.0f / DD) + F32_EPS);
    *(float4*)&h[off] = hv;
    uint2 pk;
    pk.x = f2bf(hv.x * r) | (f2bf(hv.y * r) << 16);
    pk.y = f2bf(hv.z * r) | (f2bf(hv.w * r) << 16);
    *(uint2*)&xnout[off] = pk;
}

// ---------------- bf16 MFMA GEMM with fused f32->bf16 weight cast ----------------
// C[M,N(slice)] = A[M,K] @ W[N,K]^T. 128x128 tile, BK=64, 4 waves (2x2).
// A: bf16, staged via global_load_lds w=16, inverse-swizzled source, linear dest.
// W: f32 (original input weights!), reg-staged: global f32x8 -> cvt bf16 -> swizzled ds_write_b128.
// Both produce the same swizzled LDS image; ds_read_b128 fragments conflict-free.
// EPI 0: f32 store (+blockIdx.z*partStride, split-K partials)
// EPI 1: relu(x)^2 bf16 store;  EPI 3: fused QKV routing (Wf/W2/W3, Cf/Cf2/Cb, ldc=1024)
template <int EPI>
__global__ __launch_bounds__(256) void gemm_bf16(const ushort* __restrict__ A,
                                                 const float* __restrict__ Wf,
                                                 const float* __restrict__ W2,
                                                 const float* __restrict__ W3,
                                                 float* __restrict__ Cf,
                                                 float* __restrict__ Cf2,
                                                 ushort* __restrict__ Cb,
                                                 int M, int N, int K, int lda, int ldw,
                                                 size_t partStride) {
    __shared__ __align__(16) ushort Als[128 * 64];
    __shared__ __align__(16) ushort Wls[128 * 64];
    const int tid  = threadIdx.x;
    const int wid  = tid >> 6, lane = tid & 63;
    const int wr   = wid >> 1, wc   = wid & 1;
    const int l15  = lane & 15, lhi = lane >> 4;
    const int mbase = blockIdx.y * 128, nbase = blockIdx.x * 128;

    A  += (size_t)blockIdx.z * K;          // split-K slice (columns)
    Cf += (size_t)blockIdx.z * partStride;

    const float* Wsel = Wf; int nrow = nbase;
    if (EPI == 3) {
        if (nbase >= 2048)      { Wsel = W3; nrow = nbase - 2048; }
        else if (nbase >= 1024) { Wsel = W2; nrow = nbase - 1024; }
    }
    Wsel += (size_t)blockIdx.z * K;

    // A staging (DMA): wave w covers rows [w*32, w*32+32)
    const int srow8  = lane >> 3;
    const int gchunk = ((lane & 7) ^ srow8) * 8;        // inverse-swizzled source chunk
    const ushort* Ag = A + (size_t)(mbase + wid * 32 + srow8) * lda + gchunk;
    ushort* Al = &Als[(wid * 32) * 64];

    // W staging (regs): thread covers rows rw + s*32
    const int rw = tid >> 3;                            // 0..31
    const int cwch = tid & 7;                           // 8-elem chunk
    const float* Wg = Wsel + (size_t)(nrow + rw) * ldw + cwch * 8;
    ushort* Wd = &Wls[rw * 64 + ((cwch ^ (rw & 7)) * 8)];

    f32x4 acc[4][4] = {};
    const int swz = (l15 & 7) << 3;
    const ushort* Afr = &Als[(wr * 64 + l15) * 64];
    const ushort* Wfr = &Wls[(wc * 64 + l15) * 64];

    for (int k0 = 0; k0 < K; k0 += 64) {
        // issue W f32 loads before the barrier (overlap with previous MFMA phase)
        float4 wa[4], wb[4];
#pragma unroll
        for (int s = 0; s < 4; ++s) {
            wa[s] = *(const float4*)(Wg + k0 + (size_t)s * 32 * ldw);
            wb[s] = *(const float4*)(Wg + k0 + (size_t)s * 32 * ldw + 4);
        }
        __syncthreads();                                 // LDS consumers of prev tile done
#pragma unroll
        for (int s = 0; s < 4; ++s)
            gl_lds16(Ag + k0 + (size_t)s * 8 * lda, Al + s * 8 * 64);
#pragma unroll
        for (int s = 0; s < 4; ++s) {
            uint4 o;
            o.x = f2bf(wa[s].x) | (f2bf(wa[s].y) << 16);
            o.y = f2bf(wa[s].z) | (f2bf(wa[s].w) << 16);
            o.z = f2bf(wb[s].x) | (f2bf(wb[s].y) << 16);
            o.w = f2bf(wb[s].z) | (f2bf(wb[s].w) << 16);
            *(uint4*)(Wd + s * 32 * 64) = o;
        }
        __syncthreads();                                 // drains vmcnt+lgkm before MFMA
#pragma unroll
        for (int ks = 0; ks < 2; ++ks) {
            const int fcol = (ks * 32 + lhi * 8) ^ swz;
            bf16x8 af[4], bfm[4];
#pragma unroll
            for (int m = 0; m < 4; ++m)
                af[m] = *(const bf16x8*)(Afr + m * 1024 + fcol);
#pragma unroll
            for (int n = 0; n < 4; ++n)
                bfm[n] = *(const bf16x8*)(Wfr + n * 1024 + fcol);
#pragma unroll
            for (int m = 0; m < 4; ++m)
#pragma unroll
                for (int n = 0; n < 4; ++n)
                    acc[m][n] = __builtin_amdgcn_mfma_f32_16x16x32_bf16(
                        af[m], bfm[n], acc[m][n], 0, 0, 0);
        }
    }

    // epilogue
    int   colb = nbase;
    float* fdst = Cf;
    ushort* bdst = Cb;
    if (EPI == 3) {
        if (nbase < 1024)      { fdst = Cf;  colb = nbase; }
        else if (nbase < 2048) { fdst = Cf2; colb = nbase - 1024; }
        else                   { fdst = nullptr; colb = nbase - 2048; }
    }
    const int ldc = (EPI == 3) ? 1024 : N;
    const int row0 = mbase + wr * 64 + lhi * 4;
    const int col0 = colb + wc * 64 + l15;
#pragma unroll
    for (int m = 0; m < 4; ++m)
#pragma unroll
        for (int n = 0; n < 4; ++n) {
            int cc = col0 + n * 16;
#pragma unroll
            for (int r = 0; r < 4; ++r) {
                int rr = row0 + m * 16 + r;
                float v = acc[m][n][r];
                if (EPI == 0) {
                    fdst[(size_t)rr * ldc + cc] = v;
                } else if (EPI == 1) {
                    v = fmaxf(v, 0.0f); v = v * v;
                    bdst[(size_t)rr * ldc + cc] = (ushort)f2bf(v);
                } else {
                    if (fdst) fdst[(size_t)rr * ldc + cc] = v;
                    else      bdst[(size_t)rr * ldc + cc] = (ushort)f2bf(v);
                }
            }
        }
}

// ---------------- per-head RMS + RoPE, q (with gain) and k in one launch ----------------
__global__ __launch_bounds__(256) void qknorm2_kernel(const float* __restrict__ qin,
                                                      const float* __restrict__ kin,
                                                      ushort* __restrict__ qout,
                                                      ushort* __restrict__ kout,
                                                      const float* __restrict__ cosT,
                                                      const float* __restrict__ sinT,
                                                      const float* __restrict__ gain) {
    int which = blockIdx.y;
    const float* src = which ? kin : qin;
    ushort* dst = which ? kout : qout;
    int gid = blockIdx.x * blockDim.x + threadIdx.x;
    int gw = gid >> 6, lane = gid & 63;
    int head = gw & (HH - 1);
    int c = (gw >> 4) & (CC - 1);
    int b = gw >> 14;
    size_t off = ((size_t)(b * CC + c)) * DD + head * HDIM + lane;
    float v = src[off];
    float ss = v * v;
    for (int o = 32; o; o >>= 1) ss += __shfl_xor(ss, o);
    float r = rsqrtf(ss * (1.0f / HDIM) + F32_EPS);
    float vn = v * r;
    float other = __shfl_xor(vn, 32);
    int i = lane & 31;
    float cv = cosT[c * 32 + i], sv = sinT[c * 32 + i];
    float out = (lane < 32) ? (vn * cv + other * sv) : (vn * cv - other * sv);
    if (which == 0) out *= gain[head];
    dst[off] = (ushort)f2bf(out);
}

// ---------------- V transpose: v[b*CC+kv][h*64+d] -> vt[(b*16+h)*64+d][kv] ----------------
__global__ __launch_bounds__(256) void vtrans_kernel(const ushort* __restrict__ v,
                                                     ushort* __restrict__ vt) {
    __shared__ ushort Ls[64][72];
    int kt = blockIdx.x, head = blockIdx.y, b = blockIdx.z;
    int tid = threadIdx.x;
    int r = tid >> 3;               // 0..31
    int ch = (tid & 7) * 8;         // element chunk
#pragma unroll
    for (int s = 0; s < 2; ++s) {
        int kv = r + s * 32;
        int4 t4 = *(const int4*)&v[((size_t)(b * CC + kt * 64 + kv)) * DD + head * HDIM + ch];
        *(int4*)&Ls[kv][ch] = t4;
    }
    __syncthreads();
#pragma unroll
    for (int s = 0; s < 2; ++s) {
        int d = r + s * 32;
        ushort o[8];
#pragma unroll
        for (int j = 0; j < 8; ++j) o[j] = Ls[ch + j][d];
        *(int4*)&vt[((size_t)((b * HH + head) * HDIM + d)) * CC + kt * 64 + ch] = *(int4*)o;
    }
}

// ---------------- bf16 MFMA causal flash attention (V pre-transposed) ----------------
__global__ __launch_bounds__(256) void attn_mfma(const ushort* __restrict__ q,
                                                 const ushort* __restrict__ k,
                                                 const ushort* __restrict__ vt,
                                                 ushort* __restrict__ y) {
    __shared__ __align__(16) ushort Qs[64 * 64];  // [qrow][d  ^ sw]
    __shared__ __align__(16) ushort Ks[64 * 64];  // [kv]  [d  ^ sw]
    __shared__ __align__(16) ushort VT[64 * 64];  // [d]   [kv ^ sw]
    __shared__ __align__(16) ushort Ps[64 * 64];  // [qrow][kv ^ sw] (wave-private rows)
    const int qt = 15 - blockIdx.x;               // longest-first dispatch
    const int head = blockIdx.y, b = blockIdx.z;
    const int tid = threadIdx.x;
    const int wid = tid >> 6, lane = tid & 63;
    const int l15 = lane & 15, lhi = lane >> 4;
    const int wq0 = wid * 16;
    const int qbase = qt * 64;

    const int srow = tid >> 3;            // 0..31
    const int scol = (tid & 7) * 8;       // 0..56 step 8

#pragma unroll
    for (int s = 0; s < 2; ++s) {
        int r = srow + s * 32;
        int4 t4 = *(const int4*)&q[((size_t)(b * CC + qbase + r)) * DD + head * HDIM + scol];
        *(int4*)&Qs[r * 64 + (scol ^ ((r & 7) << 3))] = t4;
    }

    f32x4 oacc[4] = {};
    float mrow[4] = {-INFINITY, -INFINITY, -INFINITY, -INFINITY};
    float lrow[4] = {0.f, 0.f, 0.f, 0.f};

    for (int kt = 0; kt <= qt; ++kt) {
        __syncthreads();
#pragma unroll
        for (int s = 0; s < 2; ++s) {
            int r = srow + s * 32;
            int4 kv4 = *(const int4*)&k[((size_t)(b * CC + kt * 64 + r)) * DD + head * HDIM + scol];
            *(int4*)&Ks[r * 64 + (scol ^ ((r & 7) << 3))] = kv4;
            // V^T staged exactly like K: rows = d, cols = kv (coalesced from vt)
            int4 vv4 = *(const int4*)&vt[((size_t)((b * HH + head) * HDIM + r)) * CC + kt * 64 + scol];
            *(int4*)&VT[r * 64 + (scol ^ ((r & 7) << 3))] = vv4;
        }
        __syncthreads();

        f32x4 sac[4] = {};
        __builtin_amdgcn_s_setprio(1);
#pragma unroll
        for (int ks = 0; ks < 2; ++ks) {
            int dcol = ks * 32 + lhi * 8;
            int arow = wq0 + l15;
            bf16x8 af = *(const bf16x8*)&Qs[arow * 64 + (dcol ^ ((arow & 7) << 3))];
#pragma unroll
            for (int n = 0; n < 4; ++n) {
                int krow = n * 16 + l15;
                bf16x8 bfr = *(const bf16x8*)&Ks[krow * 64 + (dcol ^ ((krow & 7) << 3))];
                sac[n] = __builtin_amdgcn_mfma_f32_16x16x32_bf16(af, bfr, sac[n], 0, 0, 0);
            }
        }
        __builtin_amdgcn_s_setprio(0);

        const bool diag = (kt == qt);
#pragma unroll
        for (int r = 0; r < 4; ++r) {
            int qrow_l = wq0 + lhi * 4 + r;
            int qrow_g = qbase + qrow_l;
            float sv[4];
#pragma unroll
            for (int n = 0; n < 4; ++n) {
                float t = sac[n][r] * 0.125f;
                if (diag && (kt * 64 + n * 16 + l15) > qrow_g) t = -INFINITY;
                sv[n] = t;
            }
            float tmax = fmaxf(fmaxf(sv[0], sv[1]), fmaxf(sv[2], sv[3]));
#pragma unroll
            for (int off = 1; off < 16; off <<= 1) tmax = fmaxf(tmax, __shfl_xor(tmax, off));
            float mn = fmaxf(mrow[r], tmax);
            float al = __expf(mrow[r] - mn);
            float p0 = __expf(sv[0] - mn), p1 = __expf(sv[1] - mn);
            float p2 = __expf(sv[2] - mn), p3 = __expf(sv[3] - mn);
            float ts = p0 + p1 + p2 + p3;
#pragma unroll
            for (int off = 1; off < 16; off <<= 1) ts += __shfl_xor(ts, off);
            lrow[r] = lrow[r] * al + ts;
            mrow[r] = mn;
#pragma unroll
            for (int n = 0; n < 4; ++n) oacc[n][r] *= al;
            int pb = qrow_l * 64, sw = (qrow_l & 7) << 3;
            Ps[pb + ((l15)      ^ sw)] = (ushort)f2bf(p0);
            Ps[pb + ((16 + l15) ^ sw)] = (ushort)f2bf(p1);
            Ps[pb + ((32 + l15) ^ sw)] = (ushort)f2bf(p2);
            Ps[pb + ((48 + l15) ^ sw)] = (ushort)f2bf(p3);
        }

        __builtin_amdgcn_s_setprio(1);
#pragma unroll
        for (int ks = 0; ks < 2; ++ks) {
            int kcol = ks * 32 + lhi * 8;
            int arow = wq0 + l15;
            bf16x8 pf = *(const bf16x8*)&Ps[arow * 64 + (kcol ^ ((arow & 7) << 3))];
#pragma unroll
            for (int n = 0; n < 4; ++n) {
                int vrow = n * 16 + l15;
                bf16x8 vf = *(const bf16x8*)&VT[vrow * 64 + (kcol ^ ((vrow & 7) << 3))];
                oacc[n] = __builtin_amdgcn_mfma_f32_16x16x32_bf16(pf, vf, oacc[n], 0, 0, 0);
            }
        }
        __builtin_amdgcn_s_setprio(0);
    }

#pragma unroll
    for (int r = 0; r < 4; ++r) {
        float inv = 1.0f / lrow[r];
        int qrow_g = qbase + wq0 + lhi * 4 + r;
        size_t base = ((size_t)(b * CC + qrow_g)) * DD + head * HDIM;
#pragma unroll
        for (int n = 0; n < 4; ++n)
            y[base + n * 16 + l15] = (ushort)f2bf(oacc[n][r] * inv);
    }
}

// ---------------- h += scale (.) (a0 + a1) (final layer, no rms) ----------------
__global__ void resid_kernel(float* __restrict__ h, const float* __restrict__ a0,
                             const float* __restrict__ a1,
                             const float* __restrict__ scale) {
    int idx = blockIdx.x * blockDim.x + threadIdx.x;   // per float4
    size_t off = (size_t)idx * 4;
    float4 hv = *(float4*)&h[off];
    float4 av = *(const float4*)&a0[off];
    float4 bv = *(const float4*)&a1[off];
    float4 sv = *(const float4*)&scale[(idx & 255) * 4];
    hv.x += sv.x * (av.x + bv.x);
    hv.y += sv.y * (av.y + bv.y);
    hv.z += sv.z * (av.z + bv.z);
    hv.w += sv.w * (av.w + bv.w);
    *(float4*)&h[off] = hv;
}

// ---------------- out = h * valid ----------------
__global__ void mask_kernel(const float* __restrict__ h, const int* __restrict__ nch,
                            float* __restrict__ out) {
    int idx = blockIdx.x * blockDim.x + threadIdx.x;   // per float4
    int c = (idx >> 8) & (CC - 1);
    int b = idx >> 18;
    float4 hv = *(const float4*)&h[(size_t)idx * 4];
    if (c >= nch[b]) hv = make_float4(0.f, 0.f, 0.f, 0.f);
    *(float4*)&out[(size_t)idx * 4] = hv;
}

extern "C" void kernel_launch(void* const* d_in, const int* in_sizes, int n_in,
                              void* d_out, int out_size, void* d_ws, size_t ws_size,
                              hipStream_t stream) {
    const float* x        = (const float*)d_in[0];
    const int*   boundary = (const int*)d_in[1];
    const float* Wq       = (const float*)d_in[2];
    const float* Wk       = (const float*)d_in[3];
    const float* Wv       = (const float*)d_in[4];
    const float* Wo       = (const float*)d_in[5];
    const float* qg       = (const float*)d_in[6];
    const float* fcw      = (const float*)d_in[7];
    const float* projw    = (const float*)d_in[8];
    const float* ascale   = (const float*)d_in[9];
    const float* mscale   = (const float*)d_in[10];
    const float* rmix     = (const float*)d_in[11];
    float* out = (float*)d_out;

    const size_t NTOK = (size_t)BB * CC * DD;           // 4M elems
    const size_t NHID = (size_t)BB * CC * DFF;          // 16M elems

    float* ws   = (float*)d_ws;
    float*  h    = ws;
    float*  x0   = h  + NTOK;
    float*  qb   = x0 + NTOK;            // f32 q (pre-norm) / split-K partial 0
    float*  kb   = qb + NTOK;            // f32 k (pre-norm) / split-K partial 1 (contiguous)
    ushort* xnb  = (ushort*)(kb + NTOK);
    ushort* ybf  = xnb + NTOK;
    ushort* hidb = ybf + NTOK;           // 16M bf16; doubles as qbb/kbb/vbb during attn
    ushort* vtb  = hidb + NHID;          // 4M bf16 (V transposed)
    float*  cosT = (float*)(vtb + NTOK);
    float*  sinT = cosT + (size_t)CC * 32;
    int*    starts = (int*)(sinT + (size_t)CC * 32);
    int*    nch    = starts + BB * (CC + 1);

    ushort* qbb = hidb;                  // bf16 q (post-norm)
    ushort* kbb = hidb + NTOK;           // bf16 k (post-norm)
    ushort* vbb = hidb + 2 * NTOK;       // bf16 v

    const int M = BB * CC;  // 4096 rows

    rope_init_kernel<<<CC * 32 / 256, 256, 0, stream>>>(cosT, sinT);
    scan_kernel<<<BB, 1024, 0, stream>>>(boundary, starts, nch);
    latents_kernel<<<dim3(CC, BB), 256, 0, stream>>>(x, starts, h, x0);
    rmsmix_kernel<<<M, 256, 0, stream>>>(h, x0, rmix, h, xnb);   // layer-0 entry

    for (int l = 0; l < LL; ++l) {
        // fused QKV: C[M,3072] routed -> qb(f32), kb(f32), vbb(bf16); weights f32 direct
        gemm_bf16<3><<<dim3(3 * DD / 128, M / 128, 1), 256, 0, stream>>>(
            xnb, Wq + (size_t)l * DD * DD, Wk + (size_t)l * DD * DD, Wv + (size_t)l * DD * DD,
            qb, kb, vbb, M, 3 * DD, DD, DD, DD, 0);
        // per-head RMS + RoPE -> bf16 (q and k in one launch)
        qknorm2_kernel<<<dim3((BB * CC * HH * 64) / 256, 2), 256, 0, stream>>>(
            qb, kb, qbb, kbb, cosT, sinT, qg + l * HH);
        // V transpose (once), then MFMA attention -> ybf
        vtrans_kernel<<<dim3(CC / 64, HH, BB), 256, 0, stream>>>(vbb, vtb);
        attn_mfma<<<dim3(16, HH, BB), 256, 0, stream>>>(qbb, kbb, vtb, ybf);
        // a = y @ Wo^T, split-K=2 -> partials qb,kb; fused resid+rms -> xnb
        gemm_bf16<0><<<dim3(DD / 128, M / 128, 2), 256, 0, stream>>>(
            ybf, Wo + (size_t)l * DD * DD, nullptr, nullptr,
            qb, nullptr, nullptr, M, DD, DD / 2, DD, DD, NTOK);
        residrms_kernel<0><<<M, 256, 0, stream>>>(h, qb, kb, ascale + l * DD,
                                                  nullptr, nullptr, xnb);
        // MLP: fc (relu^2, bf16) then proj split-K=2
        gemm_bf16<1><<<dim3(DFF / 128, M / 128, 1), 256, 0, stream>>>(
            xnb, fcw + (size_t)l * DFF * DD, nullptr, nullptr,
            nullptr, nullptr, hidb, M, DFF, DD, DD, DD, 0);
        gemm_bf16<0><<<dim3(DD / 128, M / 128, 2), 256, 0, stream>>>(
            hidb, projw + (size_t)l * DD * DFF, nullptr, nullptr,
            qb, nullptr, nullptr, M, DD, DFF / 2, DFF, DFF, NTOK);
        if (l < LL - 1) {
            residrms_kernel<1><<<M, 256, 0, stream>>>(h, qb, kb, mscale + l * DD,
                                                      x0, rmix + (size_t)(l + 1) * 2 * DD, xnb);
        } else {
            resid_kernel<<<(int)(NTOK / 4 / 256), 256, 0, stream>>>(h, qb, kb, mscale + l * DD);
        }
    }
    mask_kernel<<<(int)(NTOK / 4 / 256), 256, 0, stream>>>(h, nch, out);
}

// Round 6
// 1169.914 us; speedup vs baseline: 1.1302x; 1.1302x over previous
//
#include <hip/hip_runtime.h>
#include <math.h>

// Problem constants (fixed by reference)
#define BB   4
#define SS   4096
#define DD   1024
#define HH   16
#define HDIM 64
#define CC   1024      // MAX_CHUNKS
#define DFF  4096
#define LL   4

static constexpr float F32_EPS = 1.1920928955078125e-07f;  // jnp.finfo(f32).eps

typedef __attribute__((ext_vector_type(8))) __bf16 bf16x8;
typedef __attribute__((ext_vector_type(4))) float  f32x4;

__device__ __forceinline__ uint f2bf(float f) {
    uint u = __float_as_uint(f);
    return (u + 0x7fffu + ((u >> 16) & 1u)) >> 16;   // RNE
}

// direct global->LDS DMA, 16 bytes per lane; lds dest must be wave-uniform
__device__ __forceinline__ void gl_lds16(const ushort* g, ushort* l) {
    __builtin_amdgcn_global_load_lds(
        (const __attribute__((address_space(1))) unsigned int*)g,
        (__attribute__((address_space(3))) unsigned int*)l, 16, 0, 0);
}

// ---------------- f32 -> bf16 cast (8 elems/thread) ----------------
__global__ __launch_bounds__(256) void cast_kernel(const float* __restrict__ in,
                                                   ushort* __restrict__ out, int n8) {
    int i = blockIdx.x * blockDim.x + threadIdx.x;
    if (i >= n8) return;
    const float4* p = (const float4*)(in + (size_t)i * 8);
    float4 a = p[0], b = p[1];
    uint4 o;
    o.x = f2bf(a.x) | (f2bf(a.y) << 16);
    o.y = f2bf(a.z) | (f2bf(a.w) << 16);
    o.z = f2bf(b.x) | (f2bf(b.y) << 16);
    o.w = f2bf(b.z) | (f2bf(b.w) << 16);
    *(uint4*)(out + (size_t)i * 8) = o;
}

// cast Wq|Wk|Wv (each DD*DD) into one contiguous 3072xDD bf16 buffer
__global__ __launch_bounds__(256) void castqkv_kernel(const float* __restrict__ Wq,
                                                      const float* __restrict__ Wk,
                                                      const float* __restrict__ Wv,
                                                      ushort* __restrict__ out) {
    int i = blockIdx.x * blockDim.x + threadIdx.x;          // 0 .. 3*DD*DD/8
    const int SEG = DD * DD / 8;                            // 131072
    int seg = i / SEG, r = i - seg * SEG;
    const float* src = (seg == 0 ? Wq : (seg == 1 ? Wk : Wv)) + (size_t)r * 8;
    const float4* p = (const float4*)src;
    float4 a = p[0], b = p[1];
    uint4 o;
    o.x = f2bf(a.x) | (f2bf(a.y) << 16);
    o.y = f2bf(a.z) | (f2bf(a.w) << 16);
    o.z = f2bf(b.x) | (f2bf(b.y) << 16);
    o.w = f2bf(b.z) | (f2bf(b.w) << 16);
    *(uint4*)(out + (size_t)i * 8) = o;
}

// ---------------- RoPE tables ----------------
__global__ void rope_init_kernel(float* __restrict__ cosT, float* __restrict__ sinT) {
    int idx = blockIdx.x * blockDim.x + threadIdx.x;   // over CC*32
    int pos = idx >> 5;
    int i   = idx & 31;
    float inv = powf(10000.0f, -(float)i / 32.0f);
    float f = (float)pos * inv;
    cosT[idx] = cosf(f);
    sinT[idx] = sinf(f);
}

// ---------------- boundary scan -> chunk starts, num_chunks ----------------
__global__ __launch_bounds__(1024) void scan_kernel(const int* __restrict__ boundary,
                                                    int* __restrict__ starts,
                                                    int* __restrict__ nch) {
    __shared__ int tmp[1024];
    int b = blockIdx.x, t = threadIdx.x;
    int base = b * SS + t * 4;
    int v0 = boundary[base + 0], v1 = boundary[base + 1];
    int v2 = boundary[base + 2], v3 = boundary[base + 3];
    int p0 = v0, p1 = p0 + v1, p2 = p1 + v2, p3 = p2 + v3;
    tmp[t] = p3;
    __syncthreads();
    for (int off = 1; off < 1024; off <<= 1) {
        int add = (t >= off) ? tmp[t - off] : 0;
        __syncthreads();
        tmp[t] += add;
        __syncthreads();
    }
    int excl = tmp[t] - p3;
    if (v0) starts[b * (CC + 1) + (excl + p0 - 1)] = t * 4 + 0;
    if (v1) starts[b * (CC + 1) + (excl + p1 - 1)] = t * 4 + 1;
    if (v2) starts[b * (CC + 1) + (excl + p2 - 1)] = t * 4 + 2;
    if (v3) starts[b * (CC + 1) + (excl + p3 - 1)] = t * 4 + 3;
    int total = tmp[1023];
    if (t == 0) nch[b] = total;
    for (int c = t; c <= CC; c += 1024)
        if (c >= total) starts[b * (CC + 1) + c] = SS;
}

// ---------------- chunk means -> h and x0 ----------------
__global__ __launch_bounds__(256) void latents_kernel(const float* __restrict__ x,
                                                      const int* __restrict__ starts,
                                                      float* __restrict__ h,
                                                      float* __restrict__ x0) {
    int c = blockIdx.x, b = blockIdx.y, t = threadIdx.x;
    int s0 = starts[b * (CC + 1) + c];
    int s1 = starts[b * (CC + 1) + c + 1];
    float a0 = 0.f, a1 = 0.f, a2 = 0.f, a3 = 0.f;
    for (int r = s0; r < s1; ++r) {
        const float4 xv = *(const float4*)&x[((size_t)(b * SS + r)) * DD + t * 4];
        a0 += xv.x; a1 += xv.y; a2 += xv.z; a3 += xv.w;
    }
    float inv = (s1 > s0) ? 1.0f / (float)(s1 - s0) : 0.0f;
    float4 o = make_float4(a0 * inv, a1 * inv, a2 * inv, a3 * inv);
    size_t off = ((size_t)(b * CC + c)) * DD + t * 4;
    *(float4*)&h[off]  = o;
    *(float4*)&x0[off] = o;
}

// ---------------- resid-mix + row RMS norm (layer-0 entry), bf16 normed out ----------------
__global__ __launch_bounds__(256) void rmsmix_kernel(const float* __restrict__ hin,
                                                     const float* __restrict__ x0,
                                                     const float* __restrict__ mix,
                                                     float* __restrict__ hout,
                                                     ushort* __restrict__ xnout) {
    int row = blockIdx.x, t = threadIdx.x;
    size_t off = (size_t)row * DD + t * 4;
    float4 hv = *(const float4*)&hin[off];
    float4 m0 = *(const float4*)&mix[t * 4];
    float4 m1 = *(const float4*)&mix[DD + t * 4];
    float4 xv = *(const float4*)&x0[off];
    hv.x = m0.x * hv.x + m1.x * xv.x;
    hv.y = m0.y * hv.y + m1.y * xv.y;
    hv.z = m0.z * hv.z + m1.z * xv.z;
    hv.w = m0.w * hv.w + m1.w * xv.w;
    float ss = hv.x * hv.x + hv.y * hv.y + hv.z * hv.z + hv.w * hv.w;
    for (int o = 32; o; o >>= 1) ss += __shfl_xor(ss, o);
    __shared__ float wsum[4];
    int lane = t & 63, wid = t >> 6;
    if (lane == 0) wsum[wid] = ss;
    __syncthreads();
    float tot = wsum[0] + wsum[1] + wsum[2] + wsum[3];
    float r = rsqrtf(tot * (1.0f / DD) + F32_EPS);
    *(float4*)&hout[off] = hv;
    uint2 pk;
    pk.x = f2bf(hv.x * r) | (f2bf(hv.y * r) << 16);
    pk.y = f2bf(hv.z * r) | (f2bf(hv.w * r) << 16);
    *(uint2*)&xnout[off] = pk;
}

// ---------------- fused: h += scale*(a0+a1); [h = m0*h+m1*x0]; xn = bf16(rms(h)) ----------------
template <int HASMIX>
__global__ __launch_bounds__(256) void residrms_kernel(float* __restrict__ h,
                                                       const float* __restrict__ a0,
                                                       const float* __restrict__ a1,
                                                       const float* __restrict__ scale,
                                                       const float* __restrict__ x0,
                                                       const float* __restrict__ mix,
                                                       ushort* __restrict__ xnout) {
    int row = blockIdx.x, t = threadIdx.x;
    size_t off = (size_t)row * DD + t * 4;
    float4 hv = *(const float4*)&h[off];
    float4 av = *(const float4*)&a0[off];
    float4 bv = *(const float4*)&a1[off];
    float4 sv = *(const float4*)&scale[t * 4];
    hv.x += sv.x * (av.x + bv.x);
    hv.y += sv.y * (av.y + bv.y);
    hv.z += sv.z * (av.z + bv.z);
    hv.w += sv.w * (av.w + bv.w);
    if (HASMIX) {
        float4 m0 = *(const float4*)&mix[t * 4];
        float4 m1 = *(const float4*)&mix[DD + t * 4];
        float4 xv = *(const float4*)&x0[off];
        hv.x = m0.x * hv.x + m1.x * xv.x;
        hv.y = m0.y * hv.y + m1.y * xv.y;
        hv.z = m0.z * hv.z + m1.z * xv.z;
        hv.w = m0.w * hv.w + m1.w * xv.w;
    }
    float ss = hv.x * hv.x + hv.y * hv.y + hv.z * hv.z + hv.w * hv.w;
    for (int o = 32; o; o >>= 1) ss += __shfl_xor(ss, o);
    __shared__ float wsum[4];
    int lane = t & 63, wid = t >> 6;
    if (lane == 0) wsum[wid] = ss;
    __syncthreads();
    float tot = wsum[0] + wsum[1] + wsum[2] + wsum[3];
    float r = rsqrtf(tot * (1.0f / DD) + F32_EPS);
    *(float4*)&h[off] = hv;
    uint2 pk;
    pk.x = f2bf(hv.x * r) | (f2bf(hv.y * r) << 16);
    pk.y = f2bf(hv.z * r) | (f2bf(hv.w * r) << 16);
    *(uint2*)&xnout[off] = pk;
}

// ---------------- bf16 MFMA GEMM: C[M,N(slice)] = A[M,K] @ W[N,K]^T ----------------
// 128x128 tile, BK=64, 4 waves (2x2). Both A and W (bf16, pre-cast) staged via
// global_load_lds w=16 with inverse-swizzled per-lane source (linear LDS dest);
// ds_read_b128 fragments read with matching XOR swizzle -> conflict-free.
// XCD-aware remap: m-fastest within each XCD chunk so the W slab stays L2-hot.
// EPI 0: f32 store (+zt*partStride split-K partials)
// EPI 1: relu(x)^2 bf16 store
// EPI 3: fused QKV routing: n<1024 -> Cf(f32), n<2048 -> Cf2(f32), else Cb(bf16); ldc=1024
template <int EPI>
__global__ __launch_bounds__(256) void gemm_bf16(const ushort* __restrict__ A,
                                                 const ushort* __restrict__ W,
                                                 float* __restrict__ Cf,
                                                 float* __restrict__ Cf2,
                                                 ushort* __restrict__ Cb,
                                                 int M, int N, int K, int lda, int ldw,
                                                 size_t partStride) {
    __shared__ __align__(16) ushort Als[128 * 64];
    __shared__ __align__(16) ushort Wls[128 * 64];
    const int tid  = threadIdx.x;
    const int wid  = tid >> 6, lane = tid & 63;
    const int wr   = wid >> 1, wc   = wid & 1;
    const int l15  = lane & 15, lhi = lane >> 4;

    // XCD-aware remap (bijective, G % 8 == 0 for all our grids):
    // i%8 = XCD; each XCD owns G/8 consecutive v; m iterates fastest -> W L2-resident.
    const int gx = gridDim.x, gy = gridDim.y;
    int i = (blockIdx.z * gy + blockIdx.y) * gx + blockIdx.x;
    int G = gx * gy * (int)gridDim.z;
    int v = (i & 7) * (G >> 3) + (i >> 3);
    int mt = v % gy;
    int rest = v / gy;
    int nt = rest % gx;
    int zt = rest / gx;
    const int mbase = mt * 128, nbase = nt * 128;

    A  += (size_t)zt * K;          // split-K slice (columns)
    W  += (size_t)zt * K;
    Cf += (size_t)zt * partStride;

    // staging: wave w covers rows [w*32, w*32+32); per call s: 8 rows, 1KB LDS
    const int srow8  = lane >> 3;                       // 0..7
    const int gchunk = ((lane & 7) ^ srow8) * 8;        // inverse-swizzled source chunk
    const ushort* Ag = A + (size_t)(mbase + wid * 32 + srow8) * lda + gchunk;
    const ushort* Wg = W + (size_t)(nbase + wid * 32 + srow8) * ldw + gchunk;
    ushort* Al = &Als[(wid * 32) * 64];                 // wave-uniform LDS bases
    ushort* Wl = &Wls[(wid * 32) * 64];

    f32x4 acc[4][4] = {};
    const int swz = (l15 & 7) << 3;
    const ushort* Afr = &Als[(wr * 64 + l15) * 64];
    const ushort* Wfr = &Wls[(wc * 64 + l15) * 64];

    for (int k0 = 0; k0 < K; k0 += 64) {
        __syncthreads();                                 // LDS reuse safe
#pragma unroll
        for (int s = 0; s < 4; ++s) {
            gl_lds16(Ag + k0 + (size_t)s * 8 * lda, Al + s * 8 * 64);
            gl_lds16(Wg + k0 + (size_t)s * 8 * ldw, Wl + s * 8 * 64);
        }
        __syncthreads();                                 // vmcnt(0) drained before barrier
#pragma unroll
        for (int ks = 0; ks < 2; ++ks) {
            const int fcol = (ks * 32 + lhi * 8) ^ swz;
            bf16x8 af[4], bfm[4];
#pragma unroll
            for (int m = 0; m < 4; ++m)
                af[m] = *(const bf16x8*)(Afr + m * 1024 + fcol);
#pragma unroll
            for (int n = 0; n < 4; ++n)
                bfm[n] = *(const bf16x8*)(Wfr + n * 1024 + fcol);
#pragma unroll
            for (int m = 0; m < 4; ++m)
#pragma unroll
                for (int n = 0; n < 4; ++n)
                    acc[m][n] = __builtin_amdgcn_mfma_f32_16x16x32_bf16(
                        af[m], bfm[n], acc[m][n], 0, 0, 0);
        }
    }

    // epilogue
    int   colb = nbase;
    float* fdst = Cf;
    ushort* bdst = Cb;
    if (EPI == 3) {
        if (nbase < 1024)      { fdst = Cf;  colb = nbase; }
        else if (nbase < 2048) { fdst = Cf2; colb = nbase - 1024; }
        else                   { fdst = nullptr; colb = nbase - 2048; }
    }
    const int ldc = (EPI == 3) ? 1024 : N;
    const int row0 = mbase + wr * 64 + lhi * 4;
    const int col0 = colb + wc * 64 + l15;
#pragma unroll
    for (int m = 0; m < 4; ++m)
#pragma unroll
        for (int n = 0; n < 4; ++n) {
            int cc = col0 + n * 16;
#pragma unroll
            for (int r = 0; r < 4; ++r) {
                int rr = row0 + m * 16 + r;
                float v2 = acc[m][n][r];
                if (EPI == 0) {
                    fdst[(size_t)rr * ldc + cc] = v2;
                } else if (EPI == 1) {
                    v2 = fmaxf(v2, 0.0f); v2 = v2 * v2;
                    bdst[(size_t)rr * ldc + cc] = (ushort)f2bf(v2);
                } else {
                    if (fdst) fdst[(size_t)rr * ldc + cc] = v2;
                    else      bdst[(size_t)rr * ldc + cc] = (ushort)f2bf(v2);
                }
            }
        }
}

// ---------------- per-head RMS + RoPE, q (with gain) and k in one launch ----------------
__global__ __launch_bounds__(256) void qknorm2_kernel(const float* __restrict__ qin,
                                                      const float* __restrict__ kin,
                                                      ushort* __restrict__ qout,
                                                      ushort* __restrict__ kout,
                                                      const float* __restrict__ cosT,
                                                      const float* __restrict__ sinT,
                                                      const float* __restrict__ gain) {
    int which = blockIdx.y;
    const float* src = which ? kin : qin;
    ushort* dst = which ? kout : qout;
    int gid = blockIdx.x * blockDim.x + threadIdx.x;
    int gw = gid >> 6, lane = gid & 63;
    int head = gw & (HH - 1);
    int c = (gw >> 4) & (CC - 1);
    int b = gw >> 14;
    size_t off = ((size_t)(b * CC + c)) * DD + head * HDIM + lane;
    float v = src[off];
    float ss = v * v;
    for (int o = 32; o; o >>= 1) ss += __shfl_xor(ss, o);
    float r = rsqrtf(ss * (1.0f / HDIM) + F32_EPS);
    float vn = v * r;
    float other = __shfl_xor(vn, 32);
    int i = lane & 31;
    float cv = cosT[c * 32 + i], sv = sinT[c * 32 + i];
    float out = (lane < 32) ? (vn * cv + other * sv) : (vn * cv - other * sv);
    if (which == 0) out *= gain[head];
    dst[off] = (ushort)f2bf(out);
}

// ---------------- V transpose: v[b*CC+kv][h*64+d] -> vt[(b*16+h)*64+d][kv] ----------------
__global__ __launch_bounds__(256) void vtrans_kernel(const ushort* __restrict__ v,
                                                     ushort* __restrict__ vt) {
    __shared__ ushort Ls[64][72];
    int kt = blockIdx.x, head = blockIdx.y, b = blockIdx.z;
    int tid = threadIdx.x;
    int r = tid >> 3;               // 0..31
    int ch = (tid & 7) * 8;         // element chunk
#pragma unroll
    for (int s = 0; s < 2; ++s) {
        int kv = r + s * 32;
        int4 t4 = *(const int4*)&v[((size_t)(b * CC + kt * 64 + kv)) * DD + head * HDIM + ch];
        *(int4*)&Ls[kv][ch] = t4;
    }
    __syncthreads();
#pragma unroll
    for (int s = 0; s < 2; ++s) {
        int d = r + s * 32;
        ushort o[8];
#pragma unroll
        for (int j = 0; j < 8; ++j) o[j] = Ls[ch + j][d];
        *(int4*)&vt[((size_t)((b * HH + head) * HDIM + d)) * CC + kt * 64 + ch] = *(int4*)o;
    }
}

// ---------------- bf16 MFMA causal flash attention (V pre-transposed) ----------------
__global__ __launch_bounds__(256) void attn_mfma(const ushort* __restrict__ q,
                                                 const ushort* __restrict__ k,
                                                 const ushort* __restrict__ vt,
                                                 ushort* __restrict__ y) {
    __shared__ __align__(16) ushort Qs[64 * 64];  // [qrow][d  ^ sw]
    __shared__ __align__(16) ushort Ks[64 * 64];  // [kv]  [d  ^ sw]
    __shared__ __align__(16) ushort VT[64 * 64];  // [d]   [kv ^ sw]
    __shared__ __align__(16) ushort Ps[64 * 64];  // [qrow][kv ^ sw] (wave-private rows)
    const int qt = 15 - blockIdx.x;               // longest-first dispatch
    const int head = blockIdx.y, b = blockIdx.z;
    const int tid = threadIdx.x;
    const int wid = tid >> 6, lane = tid & 63;
    const int l15 = lane & 15, lhi = lane >> 4;
    const int wq0 = wid * 16;
    const int qbase = qt * 64;

    const int srow = tid >> 3;            // 0..31
    const int scol = (tid & 7) * 8;       // 0..56 step 8

#pragma unroll
    for (int s = 0; s < 2; ++s) {
        int r = srow + s * 32;
        int4 t4 = *(const int4*)&q[((size_t)(b * CC + qbase + r)) * DD + head * HDIM + scol];
        *(int4*)&Qs[r * 64 + (scol ^ ((r & 7) << 3))] = t4;
    }

    f32x4 oacc[4] = {};
    float mrow[4] = {-INFINITY, -INFINITY, -INFINITY, -INFINITY};
    float lrow[4] = {0.f, 0.f, 0.f, 0.f};

    for (int kt = 0; kt <= qt; ++kt) {
        __syncthreads();
#pragma unroll
        for (int s = 0; s < 2; ++s) {
            int r = srow + s * 32;
            int4 kv4 = *(const int4*)&k[((size_t)(b * CC + kt * 64 + r)) * DD + head * HDIM + scol];
            *(int4*)&Ks[r * 64 + (scol ^ ((r & 7) << 3))] = kv4;
            int4 vv4 = *(const int4*)&vt[((size_t)((b * HH + head) * HDIM + r)) * CC + kt * 64 + scol];
            *(int4*)&VT[r * 64 + (scol ^ ((r & 7) << 3))] = vv4;
        }
        __syncthreads();

        f32x4 sac[4] = {};
        __builtin_amdgcn_s_setprio(1);
#pragma unroll
        for (int ks = 0; ks < 2; ++ks) {
            int dcol = ks * 32 + lhi * 8;
            int arow = wq0 + l15;
            bf16x8 af = *(const bf16x8*)&Qs[arow * 64 + (dcol ^ ((arow & 7) << 3))];
#pragma unroll
            for (int n = 0; n < 4; ++n) {
                int krow = n * 16 + l15;
                bf16x8 bfr = *(const bf16x8*)&Ks[krow * 64 + (dcol ^ ((krow & 7) << 3))];
                sac[n] = __builtin_amdgcn_mfma_f32_16x16x32_bf16(af, bfr, sac[n], 0, 0, 0);
            }
        }
        __builtin_amdgcn_s_setprio(0);

        const bool diag = (kt == qt);
#pragma unroll
        for (int r = 0; r < 4; ++r) {
            int qrow_l = wq0 + lhi * 4 + r;
            int qrow_g = qbase + qrow_l;
            float sv[4];
#pragma unroll
            for (int n = 0; n < 4; ++n) {
                float t = sac[n][r] * 0.125f;
                if (diag && (kt * 64 + n * 16 + l15) > qrow_g) t = -INFINITY;
                sv[n] = t;
            }
            float tmax = fmaxf(fmaxf(sv[0], sv[1]), fmaxf(sv[2], sv[3]));
#pragma unroll
            for (int off = 1; off < 16; off <<= 1) tmax = fmaxf(tmax, __shfl_xor(tmax, off));
            float mn = fmaxf(mrow[r], tmax);
            float al = __expf(mrow[r] - mn);
            float p0 = __expf(sv[0] - mn), p1 = __expf(sv[1] - mn);
            float p2 = __expf(sv[2] - mn), p3 = __expf(sv[3] - mn);
            float ts = p0 + p1 + p2 + p3;
#pragma unroll
            for (int off = 1; off < 16; off <<= 1) ts += __shfl_xor(ts, off);
            lrow[r] = lrow[r] * al + ts;
            mrow[r] = mn;
#pragma unroll
            for (int n = 0; n < 4; ++n) oacc[n][r] *= al;
            int pb = qrow_l * 64, sw = (qrow_l & 7) << 3;
            Ps[pb + ((l15)      ^ sw)] = (ushort)f2bf(p0);
            Ps[pb + ((16 + l15) ^ sw)] = (ushort)f2bf(p1);
            Ps[pb + ((32 + l15) ^ sw)] = (ushort)f2bf(p2);
            Ps[pb + ((48 + l15) ^ sw)] = (ushort)f2bf(p3);
        }

        __builtin_amdgcn_s_setprio(1);
#pragma unroll
        for (int ks = 0; ks < 2; ++ks) {
            int kcol = ks * 32 + lhi * 8;
            int arow = wq0 + l15;
            bf16x8 pf = *(const bf16x8*)&Ps[arow * 64 + (kcol ^ ((arow & 7) << 3))];
#pragma unroll
            for (int n = 0; n < 4; ++n) {
                int vrow = n * 16 + l15;
                bf16x8 vf = *(const bf16x8*)&VT[vrow * 64 + (kcol ^ ((vrow & 7) << 3))];
                oacc[n] = __builtin_amdgcn_mfma_f32_16x16x32_bf16(pf, vf, oacc[n], 0, 0, 0);
            }
        }
        __builtin_amdgcn_s_setprio(0);
    }

#pragma unroll
    for (int r = 0; r < 4; ++r) {
        float inv = 1.0f / lrow[r];
        int qrow_g = qbase + wq0 + lhi * 4 + r;
        size_t base = ((size_t)(b * CC + qrow_g)) * DD + head * HDIM;
#pragma unroll
        for (int n = 0; n < 4; ++n)
            y[base + n * 16 + l15] = (ushort)f2bf(oacc[n][r] * inv);
    }
}

// ---------------- h += scale (.) (a0 + a1) (final layer, no rms) ----------------
__global__ void resid_kernel(float* __restrict__ h, const float* __restrict__ a0,
                             const float* __restrict__ a1,
                             const float* __restrict__ scale) {
    int idx = blockIdx.x * blockDim.x + threadIdx.x;   // per float4
    size_t off = (size_t)idx * 4;
    float4 hv = *(float4*)&h[off];
    float4 av = *(const float4*)&a0[off];
    float4 bv = *(const float4*)&a1[off];
    float4 sv = *(const float4*)&scale[(idx & 255) * 4];
    hv.x += sv.x * (av.x + bv.x);
    hv.y += sv.y * (av.y + bv.y);
    hv.z += sv.z * (av.z + bv.z);
    hv.w += sv.w * (av.w + bv.w);
    *(float4*)&h[off] = hv;
}

// ---------------- out = h * valid ----------------
__global__ void mask_kernel(const float* __restrict__ h, const int* __restrict__ nch,
                            float* __restrict__ out) {
    int idx = blockIdx.x * blockDim.x + threadIdx.x;   // per float4
    int c = (idx >> 8) & (CC - 1);
    int b = idx >> 18;
    float4 hv = *(const float4*)&h[(size_t)idx * 4];
    if (c >= nch[b]) hv = make_float4(0.f, 0.f, 0.f, 0.f);
    *(float4*)&out[(size_t)idx * 4] = hv;
}

extern "C" void kernel_launch(void* const* d_in, const int* in_sizes, int n_in,
                              void* d_out, int out_size, void* d_ws, size_t ws_size,
                              hipStream_t stream) {
    const float* x        = (const float*)d_in[0];
    const int*   boundary = (const int*)d_in[1];
    const float* Wq       = (const float*)d_in[2];
    const float* Wk       = (const float*)d_in[3];
    const float* Wv       = (const float*)d_in[4];
    const float* Wo       = (const float*)d_in[5];
    const float* qg       = (const float*)d_in[6];
    const float* fcw      = (const float*)d_in[7];
    const float* projw    = (const float*)d_in[8];
    const float* ascale   = (const float*)d_in[9];
    const float* mscale   = (const float*)d_in[10];
    const float* rmix     = (const float*)d_in[11];
    float* out = (float*)d_out;

    const size_t NTOK = (size_t)BB * CC * DD;           // 4M elems
    const size_t NHID = (size_t)BB * CC * DFF;          // 16M elems

    float* ws   = (float*)d_ws;
    float*  h    = ws;
    float*  x0   = h  + NTOK;
    float*  qb   = x0 + NTOK;            // f32 q (pre-norm) / split-K partial 0
    float*  kb   = qb + NTOK;            // f32 k (pre-norm) / split-K partial 1 (contiguous)
    ushort* xnb  = (ushort*)(kb + NTOK);
    ushort* ybf  = xnb + NTOK;
    ushort* hidb = ybf + NTOK;           // 16M bf16; doubles as qbb/kbb/vbb during attn
    ushort* wbuf = hidb + NHID;          // 16M bf16 (reused for every weight matrix)
    ushort* vtb  = wbuf + NHID;          // 4M bf16 (V transposed)
    float*  cosT = (float*)(vtb + NTOK);
    float*  sinT = cosT + (size_t)CC * 32;
    int*    starts = (int*)(sinT + (size_t)CC * 32);
    int*    nch    = starts + BB * (CC + 1);

    ushort* qbb = hidb;                  // bf16 q (post-norm)
    ushort* kbb = hidb + NTOK;           // bf16 k (post-norm)
    ushort* vbb = hidb + 2 * NTOK;       // bf16 v

    const int M = BB * CC;  // 4096 rows
    const int CAST_D2  = (int)(DD * DD / 8 / 256);
    const int CAST_DF  = (int)(DD * DFF / 8 / 256);
    const int CAST_Q3  = (int)(3 * DD * DD / 8 / 256);

    rope_init_kernel<<<CC * 32 / 256, 256, 0, stream>>>(cosT, sinT);
    scan_kernel<<<BB, 1024, 0, stream>>>(boundary, starts, nch);
    latents_kernel<<<dim3(CC, BB), 256, 0, stream>>>(x, starts, h, x0);
    rmsmix_kernel<<<M, 256, 0, stream>>>(h, x0, rmix, h, xnb);   // layer-0 entry

    for (int l = 0; l < LL; ++l) {
        // fused QKV: C[M,3072] routed -> qb(f32), kb(f32), vbb(bf16); bf16 weights
        castqkv_kernel<<<CAST_Q3, 256, 0, stream>>>(Wq + (size_t)l * DD * DD,
                                                    Wk + (size_t)l * DD * DD,
                                                    Wv + (size_t)l * DD * DD, wbuf);
        gemm_bf16<3><<<dim3(3 * DD / 128, M / 128, 1), 256, 0, stream>>>(
            xnb, wbuf, qb, kb, vbb, M, 3 * DD, DD, DD, DD, 0);
        // per-head RMS + RoPE -> bf16 (q and k in one launch)
        qknorm2_kernel<<<dim3((BB * CC * HH * 64) / 256, 2), 256, 0, stream>>>(
            qb, kb, qbb, kbb, cosT, sinT, qg + l * HH);
        // V transpose (once), then MFMA attention -> ybf
        vtrans_kernel<<<dim3(CC / 64, HH, BB), 256, 0, stream>>>(vbb, vtb);
        attn_mfma<<<dim3(16, HH, BB), 256, 0, stream>>>(qbb, kbb, vtb, ybf);
        // a = y @ Wo^T, split-K=2 -> partials qb,kb; fused resid+rms -> xnb
        cast_kernel<<<CAST_D2, 256, 0, stream>>>(Wo + (size_t)l * DD * DD, wbuf, DD * DD / 8);
        gemm_bf16<0><<<dim3(DD / 128, M / 128, 2), 256, 0, stream>>>(
            ybf, wbuf, qb, nullptr, nullptr, M, DD, DD / 2, DD, DD, NTOK);
        residrms_kernel<0><<<M, 256, 0, stream>>>(h, qb, kb, ascale + l * DD,
                                                  nullptr, nullptr, xnb);
        // MLP: fc (relu^2, bf16) then proj split-K=2
        cast_kernel<<<CAST_DF, 256, 0, stream>>>(fcw + (size_t)l * DFF * DD, wbuf, DD * DFF / 8);
        gemm_bf16<1><<<dim3(DFF / 128, M / 128, 1), 256, 0, stream>>>(
            xnb, wbuf, nullptr, nullptr, hidb, M, DFF, DD, DD, DD, 0);
        cast_kernel<<<CAST_DF, 256, 0, stream>>>(projw + (size_t)l * DD * DFF, wbuf, DD * DFF / 8);
        gemm_bf16<0><<<dim3(DD / 128, M / 128, 2), 256, 0, stream>>>(
            hidb, wbuf, qb, nullptr, nullptr, M, DD, DFF / 2, DFF, DFF, NTOK);
        if (l < LL - 1) {
            residrms_kernel<1><<<M, 256, 0, stream>>>(h, qb, kb, mscale + l * DD,
                                                      x0, rmix + (size_t)(l + 1) * 2 * DD, xnb);
        } else {
            resid_kernel<<<(int)(NTOK / 4 / 256), 256, 0, stream>>>(h, qb, kb, mscale + l * DD);
        }
    }
    mask_kernel<<<(int)(NTOK / 4 / 256), 256, 0, stream>>>(h, nch, out);
}

// Round 7
// 1107.923 us; speedup vs baseline: 1.1935x; 1.0560x over previous
//
#include <hip/hip_runtime.h>
#include <math.h>

// Problem constants (fixed by reference)
#define BB   4
#define SS   4096
#define DD   1024
#define HH   16
#define HDIM 64
#define CC   1024      // MAX_CHUNKS
#define DFF  4096
#define LL   4

static constexpr float F32_EPS = 1.1920928955078125e-07f;  // jnp.finfo(f32).eps

typedef __attribute__((ext_vector_type(8))) __bf16 bf16x8;
typedef __attribute__((ext_vector_type(4))) float  f32x4;

__device__ __forceinline__ uint f2bf(float f) {
    uint u = __float_as_uint(f);
    return (u + 0x7fffu + ((u >> 16) & 1u)) >> 16;   // RNE
}

// direct global->LDS DMA, 16 bytes per lane; lds dest must be wave-uniform
__device__ __forceinline__ void gl_lds16(const ushort* g, ushort* l) {
    __builtin_amdgcn_global_load_lds(
        (const __attribute__((address_space(1))) unsigned int*)g,
        (__attribute__((address_space(3))) unsigned int*)l, 16, 0, 0);
}

// ---------------- f32 -> bf16 cast (8 elems/thread) ----------------
__global__ __launch_bounds__(256) void cast_kernel(const float* __restrict__ in,
                                                   ushort* __restrict__ out, int n8) {
    int i = blockIdx.x * blockDim.x + threadIdx.x;
    if (i >= n8) return;
    const float4* p = (const float4*)(in + (size_t)i * 8);
    float4 a = p[0], b = p[1];
    uint4 o;
    o.x = f2bf(a.x) | (f2bf(a.y) << 16);
    o.y = f2bf(a.z) | (f2bf(a.w) << 16);
    o.z = f2bf(b.x) | (f2bf(b.y) << 16);
    o.w = f2bf(b.z) | (f2bf(b.w) << 16);
    *(uint4*)(out + (size_t)i * 8) = o;
}

// cast Wq|Wk|Wv (each DD*DD) into one contiguous 3072xDD bf16 buffer
__global__ __launch_bounds__(256) void castqkv_kernel(const float* __restrict__ Wq,
                                                      const float* __restrict__ Wk,
                                                      const float* __restrict__ Wv,
                                                      ushort* __restrict__ out) {
    int i = blockIdx.x * blockDim.x + threadIdx.x;          // 0 .. 3*DD*DD/8
    const int SEG = DD * DD / 8;                            // 131072
    int seg = i / SEG, r = i - seg * SEG;
    const float* src = (seg == 0 ? Wq : (seg == 1 ? Wk : Wv)) + (size_t)r * 8;
    const float4* p = (const float4*)src;
    float4 a = p[0], b = p[1];
    uint4 o;
    o.x = f2bf(a.x) | (f2bf(a.y) << 16);
    o.y = f2bf(a.z) | (f2bf(a.w) << 16);
    o.z = f2bf(b.x) | (f2bf(b.y) << 16);
    o.w = f2bf(b.z) | (f2bf(b.w) << 16);
    *(uint4*)(out + (size_t)i * 8) = o;
}

// ---------------- RoPE tables ----------------
__global__ void rope_init_kernel(float* __restrict__ cosT, float* __restrict__ sinT) {
    int idx = blockIdx.x * blockDim.x + threadIdx.x;   // over CC*32
    int pos = idx >> 5;
    int i   = idx & 31;
    float inv = powf(10000.0f, -(float)i / 32.0f);
    float f = (float)pos * inv;
    cosT[idx] = cosf(f);
    sinT[idx] = sinf(f);
}

// ---------------- boundary scan -> chunk starts, num_chunks ----------------
__global__ __launch_bounds__(1024) void scan_kernel(const int* __restrict__ boundary,
                                                    int* __restrict__ starts,
                                                    int* __restrict__ nch) {
    __shared__ int tmp[1024];
    int b = blockIdx.x, t = threadIdx.x;
    int base = b * SS + t * 4;
    int v0 = boundary[base + 0], v1 = boundary[base + 1];
    int v2 = boundary[base + 2], v3 = boundary[base + 3];
    int p0 = v0, p1 = p0 + v1, p2 = p1 + v2, p3 = p2 + v3;
    tmp[t] = p3;
    __syncthreads();
    for (int off = 1; off < 1024; off <<= 1) {
        int add = (t >= off) ? tmp[t - off] : 0;
        __syncthreads();
        tmp[t] += add;
        __syncthreads();
    }
    int excl = tmp[t] - p3;
    if (v0) starts[b * (CC + 1) + (excl + p0 - 1)] = t * 4 + 0;
    if (v1) starts[b * (CC + 1) + (excl + p1 - 1)] = t * 4 + 1;
    if (v2) starts[b * (CC + 1) + (excl + p2 - 1)] = t * 4 + 2;
    if (v3) starts[b * (CC + 1) + (excl + p3 - 1)] = t * 4 + 3;
    int total = tmp[1023];
    if (t == 0) nch[b] = total;
    for (int c = t; c <= CC; c += 1024)
        if (c >= total) starts[b * (CC + 1) + c] = SS;
}

// ---------------- chunk means -> h and x0 ----------------
__global__ __launch_bounds__(256) void latents_kernel(const float* __restrict__ x,
                                                      const int* __restrict__ starts,
                                                      float* __restrict__ h,
                                                      float* __restrict__ x0) {
    int c = blockIdx.x, b = blockIdx.y, t = threadIdx.x;
    int s0 = starts[b * (CC + 1) + c];
    int s1 = starts[b * (CC + 1) + c + 1];
    float a0 = 0.f, a1 = 0.f, a2 = 0.f, a3 = 0.f;
    for (int r = s0; r < s1; ++r) {
        const float4 xv = *(const float4*)&x[((size_t)(b * SS + r)) * DD + t * 4];
        a0 += xv.x; a1 += xv.y; a2 += xv.z; a3 += xv.w;
    }
    float inv = (s1 > s0) ? 1.0f / (float)(s1 - s0) : 0.0f;
    float4 o = make_float4(a0 * inv, a1 * inv, a2 * inv, a3 * inv);
    size_t off = ((size_t)(b * CC + c)) * DD + t * 4;
    *(float4*)&h[off]  = o;
    *(float4*)&x0[off] = o;
}

// ---------------- resid-mix + row RMS norm (layer-0 entry), bf16 normed out ----------------
__global__ __launch_bounds__(256) void rmsmix_kernel(const float* __restrict__ hin,
                                                     const float* __restrict__ x0,
                                                     const float* __restrict__ mix,
                                                     float* __restrict__ hout,
                                                     ushort* __restrict__ xnout) {
    int row = blockIdx.x, t = threadIdx.x;
    size_t off = (size_t)row * DD + t * 4;
    float4 hv = *(const float4*)&hin[off];
    float4 m0 = *(const float4*)&mix[t * 4];
    float4 m1 = *(const float4*)&mix[DD + t * 4];
    float4 xv = *(const float4*)&x0[off];
    hv.x = m0.x * hv.x + m1.x * xv.x;
    hv.y = m0.y * hv.y + m1.y * xv.y;
    hv.z = m0.z * hv.z + m1.z * xv.z;
    hv.w = m0.w * hv.w + m1.w * xv.w;
    float ss = hv.x * hv.x + hv.y * hv.y + hv.z * hv.z + hv.w * hv.w;
    for (int o = 32; o; o >>= 1) ss += __shfl_xor(ss, o);
    __shared__ float wsum[4];
    int lane = t & 63, wid = t >> 6;
    if (lane == 0) wsum[wid] = ss;
    __syncthreads();
    float tot = wsum[0] + wsum[1] + wsum[2] + wsum[3];
    float r = rsqrtf(tot * (1.0f / DD) + F32_EPS);
    *(float4*)&hout[off] = hv;
    uint2 pk;
    pk.x = f2bf(hv.x * r) | (f2bf(hv.y * r) << 16);
    pk.y = f2bf(hv.z * r) | (f2bf(hv.w * r) << 16);
    *(uint2*)&xnout[off] = pk;
}

// ---------------- fused: h += scale*(a0+a1); [h = m0*h+m1*x0]; xn = bf16(rms(h)) ----------------
template <int HASMIX>
__global__ __launch_bounds__(256) void residrms_kernel(float* __restrict__ h,
                                                       const float* __restrict__ a0,
                                                       const float* __restrict__ a1,
                                                       const float* __restrict__ scale,
                                                       const float* __restrict__ x0,
                                                       const float* __restrict__ mix,
                                                       ushort* __restrict__ xnout) {
    int row = blockIdx.x, t = threadIdx.x;
    size_t off = (size_t)row * DD + t * 4;
    float4 hv = *(const float4*)&h[off];
    float4 av = *(const float4*)&a0[off];
    float4 bv = *(const float4*)&a1[off];
    float4 sv = *(const float4*)&scale[t * 4];
    hv.x += sv.x * (av.x + bv.x);
    hv.y += sv.y * (av.y + bv.y);
    hv.z += sv.z * (av.z + bv.z);
    hv.w += sv.w * (av.w + bv.w);
    if (HASMIX) {
        float4 m0 = *(const float4*)&mix[t * 4];
        float4 m1 = *(const float4*)&mix[DD + t * 4];
        float4 xv = *(const float4*)&x0[off];
        hv.x = m0.x * hv.x + m1.x * xv.x;
        hv.y = m0.y * hv.y + m1.y * xv.y;
        hv.z = m0.z * hv.z + m1.z * xv.z;
        hv.w = m0.w * hv.w + m1.w * xv.w;
    }
    float ss = hv.x * hv.x + hv.y * hv.y + hv.z * hv.z + hv.w * hv.w;
    for (int o = 32; o; o >>= 1) ss += __shfl_xor(ss, o);
    __shared__ float wsum[4];
    int lane = t & 63, wid = t >> 6;
    if (lane == 0) wsum[wid] = ss;
    __syncthreads();
    float tot = wsum[0] + wsum[1] + wsum[2] + wsum[3];
    float r = rsqrtf(tot * (1.0f / DD) + F32_EPS);
    *(float4*)&h[off] = hv;
    uint2 pk;
    pk.x = f2bf(hv.x * r) | (f2bf(hv.y * r) << 16);
    pk.y = f2bf(hv.z * r) | (f2bf(hv.w * r) << 16);
    *(uint2*)&xnout[off] = pk;
}

// ---------------- bf16 MFMA GEMM, 2-phase double-buffered pipeline ----------------
// C[M,N(slice)] = A[M,K] @ W[N,K]^T. 128x128 tile, BK=64, 4 waves (2x2).
// T3-minimum schedule: STAGE(next buf) issued BEFORE COMPUTE(cur buf); one barrier
// per K-step. global_load_lds w=16, inverse-swizzled source, linear LDS dest,
// swizzled ds_read_b128 fragments (conflict-free). XCD-aware remap (m-fastest).
// Requires K % 128 == 0 (all call sites: 512/1024/2048).
// EPI 0: f32 store (+zt*partStride split-K partials)
// EPI 1: relu(x)^2 bf16 store
// EPI 3: fused QKV routing: n<1024 -> Cf(f32), n<2048 -> Cf2(f32), else Cb(bf16); ldc=1024
template <int EPI>
__global__ __launch_bounds__(256) void gemm_bf16(const ushort* __restrict__ A,
                                                 const ushort* __restrict__ W,
                                                 float* __restrict__ Cf,
                                                 float* __restrict__ Cf2,
                                                 ushort* __restrict__ Cb,
                                                 int M, int N, int K, int lda, int ldw,
                                                 size_t partStride) {
    __shared__ __align__(16) ushort Als[2][128 * 64];
    __shared__ __align__(16) ushort Wls[2][128 * 64];
    const int tid  = threadIdx.x;
    const int wid  = tid >> 6, lane = tid & 63;
    const int wr   = wid >> 1, wc   = wid & 1;
    const int l15  = lane & 15, lhi = lane >> 4;

    // XCD-aware remap (bijective, G % 8 == 0 for all our grids), m-fastest
    const int gx = gridDim.x, gy = gridDim.y;
    int i = (blockIdx.z * gy + blockIdx.y) * gx + blockIdx.x;
    int G = gx * gy * (int)gridDim.z;
    int v = (i & 7) * (G >> 3) + (i >> 3);
    int mt = v % gy;
    int rest = v / gy;
    int nt = rest % gx;
    int zt = rest / gx;
    const int mbase = mt * 128, nbase = nt * 128;

    A  += (size_t)zt * K;          // split-K slice (columns)
    W  += (size_t)zt * K;
    Cf += (size_t)zt * partStride;

    const float* dummy = nullptr; (void)dummy;

    // staging addresses: wave w covers rows [w*32, w*32+32); 8 gl_lds16 per tile
    const int srow8  = lane >> 3;                       // 0..7
    const int gchunk = ((lane & 7) ^ srow8) * 8;        // inverse-swizzled source chunk
    const ushort* Ag = A + (size_t)(mbase + wid * 32 + srow8) * lda + gchunk;
    const ushort* Wg = W + (size_t)(nbase + wid * 32 + srow8) * ldw + gchunk;
    const int ldsoff = (wid * 32) * 64;                 // wave-uniform LDS base offset

    f32x4 acc[4][4] = {};
    const int swz  = (l15 & 7) << 3;
    const int aoff = (wr * 64 + l15) * 64;
    const int woff = (wc * 64 + l15) * 64;

    auto STAGE = [&](ushort* Alb, ushort* Wlb, int kk) {
#pragma unroll
        for (int s = 0; s < 4; ++s) {
            gl_lds16(Ag + kk + (size_t)s * 8 * lda, Alb + ldsoff + s * 8 * 64);
            gl_lds16(Wg + kk + (size_t)s * 8 * ldw, Wlb + ldsoff + s * 8 * 64);
        }
    };
    auto COMPUTE = [&](const ushort* Ab, const ushort* Wb) {
#pragma unroll
        for (int ks = 0; ks < 2; ++ks) {
            const int fcol = (ks * 32 + lhi * 8) ^ swz;
            bf16x8 af[4], bfm[4];
#pragma unroll
            for (int m = 0; m < 4; ++m)
                af[m] = *(const bf16x8*)(Ab + aoff + m * 1024 + fcol);
#pragma unroll
            for (int n = 0; n < 4; ++n)
                bfm[n] = *(const bf16x8*)(Wb + woff + n * 1024 + fcol);
#pragma unroll
            for (int m = 0; m < 4; ++m)
#pragma unroll
                for (int n = 0; n < 4; ++n)
                    acc[m][n] = __builtin_amdgcn_mfma_f32_16x16x32_bf16(
                        af[m], bfm[n], acc[m][n], 0, 0, 0);
        }
    };

    STAGE(Als[0], Wls[0], 0);                    // prologue
    __syncthreads();                             // drain vmcnt -> buf0 ready
    for (int k0 = 0; k0 < K; k0 += 128) {
        if (k0 + 64 < K) STAGE(Als[1], Wls[1], k0 + 64);   // prefetch under compute
        COMPUTE(Als[0], Wls[0]);
        __syncthreads();                         // buf1 staged + buf0 reads done
        if (k0 + 128 < K) STAGE(Als[0], Wls[0], k0 + 128);
        COMPUTE(Als[1], Wls[1]);
        __syncthreads();
    }

    // epilogue
    int   colb = nbase;
    float* fdst = Cf;
    ushort* bdst = Cb;
    if (EPI == 3) {
        if (nbase < 1024)      { fdst = Cf;  colb = nbase; }
        else if (nbase < 2048) { fdst = Cf2; colb = nbase - 1024; }
        else                   { fdst = nullptr; colb = nbase - 2048; }
    }
    const int ldc = (EPI == 3) ? 1024 : N;
    const int row0 = mbase + wr * 64 + lhi * 4;
    const int col0 = colb + wc * 64 + l15;
#pragma unroll
    for (int m = 0; m < 4; ++m)
#pragma unroll
        for (int n = 0; n < 4; ++n) {
            int cc = col0 + n * 16;
#pragma unroll
            for (int r = 0; r < 4; ++r) {
                int rr = row0 + m * 16 + r;
                float v2 = acc[m][n][r];
                if (EPI == 0) {
                    fdst[(size_t)rr * ldc + cc] = v2;
                } else if (EPI == 1) {
                    v2 = fmaxf(v2, 0.0f); v2 = v2 * v2;
                    bdst[(size_t)rr * ldc + cc] = (ushort)f2bf(v2);
                } else {
                    if (fdst) fdst[(size_t)rr * ldc + cc] = v2;
                    else      bdst[(size_t)rr * ldc + cc] = (ushort)f2bf(v2);
                }
            }
        }
}

// ---------------- per-head RMS + RoPE, q (with gain) and k in one launch ----------------
__global__ __launch_bounds__(256) void qknorm2_kernel(const float* __restrict__ qin,
                                                      const float* __restrict__ kin,
                                                      ushort* __restrict__ qout,
                                                      ushort* __restrict__ kout,
                                                      const float* __restrict__ cosT,
                                                      const float* __restrict__ sinT,
                                                      const float* __restrict__ gain) {
    int which = blockIdx.y;
    const float* src = which ? kin : qin;
    ushort* dst = which ? kout : qout;
    int gid = blockIdx.x * blockDim.x + threadIdx.x;
    int gw = gid >> 6, lane = gid & 63;
    int head = gw & (HH - 1);
    int c = (gw >> 4) & (CC - 1);
    int b = gw >> 14;
    size_t off = ((size_t)(b * CC + c)) * DD + head * HDIM + lane;
    float v = src[off];
    float ss = v * v;
    for (int o = 32; o; o >>= 1) ss += __shfl_xor(ss, o);
    float r = rsqrtf(ss * (1.0f / HDIM) + F32_EPS);
    float vn = v * r;
    float other = __shfl_xor(vn, 32);
    int i = lane & 31;
    float cv = cosT[c * 32 + i], sv = sinT[c * 32 + i];
    float out = (lane < 32) ? (vn * cv + other * sv) : (vn * cv - other * sv);
    if (which == 0) out *= gain[head];
    dst[off] = (ushort)f2bf(out);
}

// ---------------- V transpose: v[b*CC+kv][h*64+d] -> vt[(b*16+h)*64+d][kv] ----------------
__global__ __launch_bounds__(256) void vtrans_kernel(const ushort* __restrict__ v,
                                                     ushort* __restrict__ vt) {
    __shared__ ushort Ls[64][72];
    int kt = blockIdx.x, head = blockIdx.y, b = blockIdx.z;
    int tid = threadIdx.x;
    int r = tid >> 3;               // 0..31
    int ch = (tid & 7) * 8;         // element chunk
#pragma unroll
    for (int s = 0; s < 2; ++s) {
        int kv = r + s * 32;
        int4 t4 = *(const int4*)&v[((size_t)(b * CC + kt * 64 + kv)) * DD + head * HDIM + ch];
        *(int4*)&Ls[kv][ch] = t4;
    }
    __syncthreads();
#pragma unroll
    for (int s = 0; s < 2; ++s) {
        int d = r + s * 32;
        ushort o[8];
#pragma unroll
        for (int j = 0; j < 8; ++j) o[j] = Ls[ch + j][d];
        *(int4*)&vt[((size_t)((b * HH + head) * HDIM + d)) * CC + kt * 64 + ch] = *(int4*)o;
    }
}

// ---------------- bf16 MFMA causal flash attention (V pre-transposed) ----------------
__global__ __launch_bounds__(256) void attn_mfma(const ushort* __restrict__ q,
                                                 const ushort* __restrict__ k,
                                                 const ushort* __restrict__ vt,
                                                 ushort* __restrict__ y) {
    __shared__ __align__(16) ushort Qs[64 * 64];  // [qrow][d  ^ sw]
    __shared__ __align__(16) ushort Ks[64 * 64];  // [kv]  [d  ^ sw]
    __shared__ __align__(16) ushort VT[64 * 64];  // [d]   [kv ^ sw]
    __shared__ __align__(16) ushort Ps[64 * 64];  // [qrow][kv ^ sw] (wave-private rows)
    const int qt = 15 - blockIdx.x;               // longest-first dispatch
    const int head = blockIdx.y, b = blockIdx.z;
    const int tid = threadIdx.x;
    const int wid = tid >> 6, lane = tid & 63;
    const int l15 = lane & 15, lhi = lane >> 4;
    const int wq0 = wid * 16;
    const int qbase = qt * 64;

    const int srow = tid >> 3;            // 0..31
    const int scol = (tid & 7) * 8;       // 0..56 step 8

#pragma unroll
    for (int s = 0; s < 2; ++s) {
        int r = srow + s * 32;
        int4 t4 = *(const int4*)&q[((size_t)(b * CC + qbase + r)) * DD + head * HDIM + scol];
        *(int4*)&Qs[r * 64 + (scol ^ ((r & 7) << 3))] = t4;
    }

    f32x4 oacc[4] = {};
    float mrow[4] = {-INFINITY, -INFINITY, -INFINITY, -INFINITY};
    float lrow[4] = {0.f, 0.f, 0.f, 0.f};

    for (int kt = 0; kt <= qt; ++kt) {
        __syncthreads();
#pragma unroll
        for (int s = 0; s < 2; ++s) {
            int r = srow + s * 32;
            int4 kv4 = *(const int4*)&k[((size_t)(b * CC + kt * 64 + r)) * DD + head * HDIM + scol];
            *(int4*)&Ks[r * 64 + (scol ^ ((r & 7) << 3))] = kv4;
            int4 vv4 = *(const int4*)&vt[((size_t)((b * HH + head) * HDIM + r)) * CC + kt * 64 + scol];
            *(int4*)&VT[r * 64 + (scol ^ ((r & 7) << 3))] = vv4;
        }
        __syncthreads();

        f32x4 sac[4] = {};
        __builtin_amdgcn_s_setprio(1);
#pragma unroll
        for (int ks = 0; ks < 2; ++ks) {
            int dcol = ks * 32 + lhi * 8;
            int arow = wq0 + l15;
            bf16x8 af = *(const bf16x8*)&Qs[arow * 64 + (dcol ^ ((arow & 7) << 3))];
#pragma unroll
            for (int n = 0; n < 4; ++n) {
                int krow = n * 16 + l15;
                bf16x8 bfr = *(const bf16x8*)&Ks[krow * 64 + (dcol ^ ((krow & 7) << 3))];
                sac[n] = __builtin_amdgcn_mfma_f32_16x16x32_bf16(af, bfr, sac[n], 0, 0, 0);
            }
        }
        __builtin_amdgcn_s_setprio(0);

        const bool diag = (kt == qt);
#pragma unroll
        for (int r = 0; r < 4; ++r) {
            int qrow_l = wq0 + lhi * 4 + r;
            int qrow_g = qbase + qrow_l;
            float sv[4];
#pragma unroll
            for (int n = 0; n < 4; ++n) {
                float t = sac[n][r] * 0.125f;
                if (diag && (kt * 64 + n * 16 + l15) > qrow_g) t = -INFINITY;
                sv[n] = t;
            }
            float tmax = fmaxf(fmaxf(sv[0], sv[1]), fmaxf(sv[2], sv[3]));
#pragma unroll
            for (int off = 1; off < 16; off <<= 1) tmax = fmaxf(tmax, __shfl_xor(tmax, off));
            float mn = fmaxf(mrow[r], tmax);
            float al = __expf(mrow[r] - mn);
            float p0 = __expf(sv[0] - mn), p1 = __expf(sv[1] - mn);
            float p2 = __expf(sv[2] - mn), p3 = __expf(sv[3] - mn);
            float ts = p0 + p1 + p2 + p3;
#pragma unroll
            for (int off = 1; off < 16; off <<= 1) ts += __shfl_xor(ts, off);
            lrow[r] = lrow[r] * al + ts;
            mrow[r] = mn;
#pragma unroll
            for (int n = 0; n < 4; ++n) oacc[n][r] *= al;
            int pb = qrow_l * 64, sw = (qrow_l & 7) << 3;
            Ps[pb + ((l15)      ^ sw)] = (ushort)f2bf(p0);
            Ps[pb + ((16 + l15) ^ sw)] = (ushort)f2bf(p1);
            Ps[pb + ((32 + l15) ^ sw)] = (ushort)f2bf(p2);
            Ps[pb + ((48 + l15) ^ sw)] = (ushort)f2bf(p3);
        }

        __builtin_amdgcn_s_setprio(1);
#pragma unroll
        for (int ks = 0; ks < 2; ++ks) {
            int kcol = ks * 32 + lhi * 8;
            int arow = wq0 + l15;
            bf16x8 pf = *(const bf16x8*)&Ps[arow * 64 + (kcol ^ ((arow & 7) << 3))];
#pragma unroll
            for (int n = 0; n < 4; ++n) {
                int vrow = n * 16 + l15;
                bf16x8 vf = *(const bf16x8*)&VT[vrow * 64 + (kcol ^ ((vrow & 7) << 3))];
                oacc[n] = __builtin_amdgcn_mfma_f32_16x16x32_bf16(pf, vf, oacc[n], 0, 0, 0);
            }
        }
        __builtin_amdgcn_s_setprio(0);
    }

#pragma unroll
    for (int r = 0; r < 4; ++r) {
        float inv = 1.0f / lrow[r];
        int qrow_g = qbase + wq0 + lhi * 4 + r;
        size_t base = ((size_t)(b * CC + qrow_g)) * DD + head * HDIM;
#pragma unroll
        for (int n = 0; n < 4; ++n)
            y[base + n * 16 + l15] = (ushort)f2bf(oacc[n][r] * inv);
    }
}

// ---------------- final: out = (h + scale*(a0+a1)) * valid ----------------
__global__ void residmask_kernel(const float* __restrict__ h, const float* __restrict__ a0,
                                 const float* __restrict__ a1,
                                 const float* __restrict__ scale,
                                 const int* __restrict__ nch,
                                 float* __restrict__ out) {
    int idx = blockIdx.x * blockDim.x + threadIdx.x;   // per float4
    size_t off = (size_t)idx * 4;
    int c = (idx >> 8) & (CC - 1);
    int b = idx >> 18;
    float4 hv = *(const float4*)&h[off];
    float4 av = *(const float4*)&a0[off];
    float4 bv = *(const float4*)&a1[off];
    float4 sv = *(const float4*)&scale[(idx & 255) * 4];
    hv.x += sv.x * (av.x + bv.x);
    hv.y += sv.y * (av.y + bv.y);
    hv.z += sv.z * (av.z + bv.z);
    hv.w += sv.w * (av.w + bv.w);
    if (c >= nch[b]) hv = make_float4(0.f, 0.f, 0.f, 0.f);
    *(float4*)&out[off] = hv;
}

extern "C" void kernel_launch(void* const* d_in, const int* in_sizes, int n_in,
                              void* d_out, int out_size, void* d_ws, size_t ws_size,
                              hipStream_t stream) {
    const float* x        = (const float*)d_in[0];
    const int*   boundary = (const int*)d_in[1];
    const float* Wq       = (const float*)d_in[2];
    const float* Wk       = (const float*)d_in[3];
    const float* Wv       = (const float*)d_in[4];
    const float* Wo       = (const float*)d_in[5];
    const float* qg       = (const float*)d_in[6];
    const float* fcw      = (const float*)d_in[7];
    const float* projw    = (const float*)d_in[8];
    const float* ascale   = (const float*)d_in[9];
    const float* mscale   = (const float*)d_in[10];
    const float* rmix     = (const float*)d_in[11];
    float* out = (float*)d_out;

    const size_t NTOK = (size_t)BB * CC * DD;           // 4M elems
    const size_t NHID = (size_t)BB * CC * DFF;          // 16M elems

    float* ws   = (float*)d_ws;
    float*  h    = ws;
    float*  x0   = h  + NTOK;
    float*  qb   = x0 + NTOK;            // f32 q (pre-norm) / split-K partial 0
    float*  kb   = qb + NTOK;            // f32 k (pre-norm) / split-K partial 1 (contiguous)
    ushort* xnb  = (ushort*)(kb + NTOK);
    ushort* ybf  = xnb + NTOK;
    ushort* hidb = ybf + NTOK;           // 16M bf16; doubles as qbb/kbb/vbb during attn
    ushort* wbuf = hidb + NHID;          // 16M bf16 (reused for every weight matrix)
    ushort* vtb  = wbuf + NHID;          // 4M bf16 (V transposed)
    float*  cosT = (float*)(vtb + NTOK);
    float*  sinT = cosT + (size_t)CC * 32;
    int*    starts = (int*)(sinT + (size_t)CC * 32);
    int*    nch    = starts + BB * (CC + 1);

    ushort* qbb = hidb;                  // bf16 q (post-norm)
    ushort* kbb = hidb + NTOK;           // bf16 k (post-norm)
    ushort* vbb = hidb + 2 * NTOK;       // bf16 v

    const int M = BB * CC;  // 4096 rows
    const int CAST_D2  = (int)(DD * DD / 8 / 256);
    const int CAST_DF  = (int)(DD * DFF / 8 / 256);
    const int CAST_Q3  = (int)(3 * DD * DD / 8 / 256);

    rope_init_kernel<<<CC * 32 / 256, 256, 0, stream>>>(cosT, sinT);
    scan_kernel<<<BB, 1024, 0, stream>>>(boundary, starts, nch);
    latents_kernel<<<dim3(CC, BB), 256, 0, stream>>>(x, starts, h, x0);
    rmsmix_kernel<<<M, 256, 0, stream>>>(h, x0, rmix, h, xnb);   // layer-0 entry

    for (int l = 0; l < LL; ++l) {
        // fused QKV: C[M,3072] routed -> qb(f32), kb(f32), vbb(bf16); bf16 weights
        castqkv_kernel<<<CAST_Q3, 256, 0, stream>>>(Wq + (size_t)l * DD * DD,
                                                    Wk + (size_t)l * DD * DD,
                                                    Wv + (size_t)l * DD * DD, wbuf);
        gemm_bf16<3><<<dim3(3 * DD / 128, M / 128, 1), 256, 0, stream>>>(
            xnb, wbuf, qb, kb, vbb, M, 3 * DD, DD, DD, DD, 0);
        // per-head RMS + RoPE -> bf16 (q and k in one launch)
        qknorm2_kernel<<<dim3((BB * CC * HH * 64) / 256, 2), 256, 0, stream>>>(
            qb, kb, qbb, kbb, cosT, sinT, qg + l * HH);
        // V transpose (once), then MFMA attention -> ybf
        vtrans_kernel<<<dim3(CC / 64, HH, BB), 256, 0, stream>>>(vbb, vtb);
        attn_mfma<<<dim3(16, HH, BB), 256, 0, stream>>>(qbb, kbb, vtb, ybf);
        // a = y @ Wo^T, split-K=2 -> partials qb,kb; fused resid+rms -> xnb
        cast_kernel<<<CAST_D2, 256, 0, stream>>>(Wo + (size_t)l * DD * DD, wbuf, DD * DD / 8);
        gemm_bf16<0><<<dim3(DD / 128, M / 128, 2), 256, 0, stream>>>(
            ybf, wbuf, qb, nullptr, nullptr, M, DD, DD / 2, DD, DD, NTOK);
        residrms_kernel<0><<<M, 256, 0, stream>>>(h, qb, kb, ascale + l * DD,
                                                  nullptr, nullptr, xnb);
        // MLP: fc (relu^2, bf16) then proj split-K=2
        cast_kernel<<<CAST_DF, 256, 0, stream>>>(fcw + (size_t)l * DFF * DD, wbuf, DD * DFF / 8);
        gemm_bf16<1><<<dim3(DFF / 128, M / 128, 1), 256, 0, stream>>>(
            xnb, wbuf, nullptr, nullptr, hidb, M, DFF, DD, DD, DD, 0);
        cast_kernel<<<CAST_DF, 256, 0, stream>>>(projw + (size_t)l * DD * DFF, wbuf, DD * DFF / 8);
        gemm_bf16<0><<<dim3(DD / 128, M / 128, 2), 256, 0, stream>>>(
            hidb, wbuf, qb, nullptr, nullptr, M, DD, DFF / 2, DFF, DFF, NTOK);
        if (l < LL - 1) {
            residrms_kernel<1><<<M, 256, 0, stream>>>(h, qb, kb, mscale + l * DD,
                                                      x0, rmix + (size_t)(l + 1) * 2 * DD, xnb);
        } else {
            residmask_kernel<<<(int)(NTOK / 4 / 256), 256, 0, stream>>>(
                h, qb, kb, mscale + l * DD, nch, out);
        }
    }
}

// Round 8
// 1035.443 us; speedup vs baseline: 1.2770x; 1.0700x over previous
//
#include <hip/hip_runtime.h>
#include <math.h>

// Problem constants (fixed by reference)
#define BB   4
#define SS   4096
#define DD   1024
#define HH   16
#define HDIM 64
#define CC   1024      // MAX_CHUNKS
#define DFF  4096
#define LL   4

static constexpr float F32_EPS = 1.1920928955078125e-07f;  // jnp.finfo(f32).eps

typedef __attribute__((ext_vector_type(8))) __bf16 bf16x8;
typedef __attribute__((ext_vector_type(4))) float  f32x4;

__device__ __forceinline__ uint f2bf(float f) {
    uint u = __float_as_uint(f);
    return (u + 0x7fffu + ((u >> 16) & 1u)) >> 16;   // RNE
}

// direct global->LDS DMA, 16 bytes per lane; lds dest must be wave-uniform
__device__ __forceinline__ void gl_lds16(const ushort* g, ushort* l) {
    __builtin_amdgcn_global_load_lds(
        (const __attribute__((address_space(1))) unsigned int*)g,
        (__attribute__((address_space(3))) unsigned int*)l, 16, 0, 0);
}

// ---------------- per-layer mega-cast: all 5 weight mats f32 -> bf16 in one launch --------
// wbuf layout (ushort elems): [0,3M) Wq|Wk|Wv ; [3M,4M) Wo ; [4M,8M) fc ; [8M,12M) proj
__global__ __launch_bounds__(256) void castlayer_kernel(const float* __restrict__ Wq,
                                                        const float* __restrict__ Wk,
                                                        const float* __restrict__ Wv,
                                                        const float* __restrict__ Wo,
                                                        const float* __restrict__ fc,
                                                        const float* __restrict__ proj,
                                                        ushort* __restrict__ out) {
    int i = blockIdx.x * blockDim.x + threadIdx.x;      // 8-elem chunk id, 0..12M/8
    const int U = DD * DD / 8;                          // 131072
    const float* src;
    if (i < 3 * U) {
        src = (i < U ? Wq : (i < 2 * U ? Wk : Wv)) + (size_t)(i < U ? i : (i < 2*U ? i-U : i-2*U)) * 8;
    } else if (i < 4 * U) {
        src = Wo + (size_t)(i - 3 * U) * 8;
    } else if (i < 8 * U) {
        src = fc + (size_t)(i - 4 * U) * 8;
    } else {
        src = proj + (size_t)(i - 8 * U) * 8;
    }
    const float4* p = (const float4*)src;
    float4 a = p[0], b = p[1];
    uint4 o;
    o.x = f2bf(a.x) | (f2bf(a.y) << 16);
    o.y = f2bf(a.z) | (f2bf(a.w) << 16);
    o.z = f2bf(b.x) | (f2bf(b.y) << 16);
    o.w = f2bf(b.z) | (f2bf(b.w) << 16);
    *(uint4*)(out + (size_t)i * 8) = o;
}

// ---------------- RoPE tables ----------------
__global__ void rope_init_kernel(float* __restrict__ cosT, float* __restrict__ sinT) {
    int idx = blockIdx.x * blockDim.x + threadIdx.x;   // over CC*32
    int pos = idx >> 5;
    int i   = idx & 31;
    float inv = powf(10000.0f, -(float)i / 32.0f);
    float f = (float)pos * inv;
    cosT[idx] = cosf(f);
    sinT[idx] = sinf(f);
}

// ---------------- boundary scan -> chunk starts, num_chunks ----------------
__global__ __launch_bounds__(1024) void scan_kernel(const int* __restrict__ boundary,
                                                    int* __restrict__ starts,
                                                    int* __restrict__ nch) {
    __shared__ int tmp[1024];
    int b = blockIdx.x, t = threadIdx.x;
    int base = b * SS + t * 4;
    int v0 = boundary[base + 0], v1 = boundary[base + 1];
    int v2 = boundary[base + 2], v3 = boundary[base + 3];
    int p0 = v0, p1 = p0 + v1, p2 = p1 + v2, p3 = p2 + v3;
    tmp[t] = p3;
    __syncthreads();
    for (int off = 1; off < 1024; off <<= 1) {
        int add = (t >= off) ? tmp[t - off] : 0;
        __syncthreads();
        tmp[t] += add;
        __syncthreads();
    }
    int excl = tmp[t] - p3;
    if (v0) starts[b * (CC + 1) + (excl + p0 - 1)] = t * 4 + 0;
    if (v1) starts[b * (CC + 1) + (excl + p1 - 1)] = t * 4 + 1;
    if (v2) starts[b * (CC + 1) + (excl + p2 - 1)] = t * 4 + 2;
    if (v3) starts[b * (CC + 1) + (excl + p3 - 1)] = t * 4 + 3;
    int total = tmp[1023];
    if (t == 0) nch[b] = total;
    for (int c = t; c <= CC; c += 1024)
        if (c >= total) starts[b * (CC + 1) + c] = SS;
}

// ---------------- chunk means -> h and x0 ----------------
__global__ __launch_bounds__(256) void latents_kernel(const float* __restrict__ x,
                                                      const int* __restrict__ starts,
                                                      float* __restrict__ h,
                                                      float* __restrict__ x0) {
    int c = blockIdx.x, b = blockIdx.y, t = threadIdx.x;
    int s0 = starts[b * (CC + 1) + c];
    int s1 = starts[b * (CC + 1) + c + 1];
    float a0 = 0.f, a1 = 0.f, a2 = 0.f, a3 = 0.f;
    for (int r = s0; r < s1; ++r) {
        const float4 xv = *(const float4*)&x[((size_t)(b * SS + r)) * DD + t * 4];
        a0 += xv.x; a1 += xv.y; a2 += xv.z; a3 += xv.w;
    }
    float inv = (s1 > s0) ? 1.0f / (float)(s1 - s0) : 0.0f;
    float4 o = make_float4(a0 * inv, a1 * inv, a2 * inv, a3 * inv);
    size_t off = ((size_t)(b * CC + c)) * DD + t * 4;
    *(float4*)&h[off]  = o;
    *(float4*)&x0[off] = o;
}

// ---------------- resid-mix + row RMS norm (layer-0 entry), bf16 normed out ----------------
__global__ __launch_bounds__(256) void rmsmix_kernel(const float* __restrict__ hin,
                                                     const float* __restrict__ x0,
                                                     const float* __restrict__ mix,
                                                     float* __restrict__ hout,
                                                     ushort* __restrict__ xnout) {
    int row = blockIdx.x, t = threadIdx.x;
    size_t off = (size_t)row * DD + t * 4;
    float4 hv = *(const float4*)&hin[off];
    float4 m0 = *(const float4*)&mix[t * 4];
    float4 m1 = *(const float4*)&mix[DD + t * 4];
    float4 xv = *(const float4*)&x0[off];
    hv.x = m0.x * hv.x + m1.x * xv.x;
    hv.y = m0.y * hv.y + m1.y * xv.y;
    hv.z = m0.z * hv.z + m1.z * xv.z;
    hv.w = m0.w * hv.w + m1.w * xv.w;
    float ss = hv.x * hv.x + hv.y * hv.y + hv.z * hv.z + hv.w * hv.w;
    for (int o = 32; o; o >>= 1) ss += __shfl_xor(ss, o);
    __shared__ float wsum[4];
    int lane = t & 63, wid = t >> 6;
    if (lane == 0) wsum[wid] = ss;
    __syncthreads();
    float tot = wsum[0] + wsum[1] + wsum[2] + wsum[3];
    float r = rsqrtf(tot * (1.0f / DD) + F32_EPS);
    *(float4*)&hout[off] = hv;
    uint2 pk;
    pk.x = f2bf(hv.x * r) | (f2bf(hv.y * r) << 16);
    pk.y = f2bf(hv.z * r) | (f2bf(hv.w * r) << 16);
    *(uint2*)&xnout[off] = pk;
}

// ---------------- fused: h += scale*(a0+a1); [h = m0*h+m1*x0]; xn = bf16(rms(h)) ----------------
template <int HASMIX>
__global__ __launch_bounds__(256) void residrms_kernel(float* __restrict__ h,
                                                       const float* __restrict__ a0,
                                                       const float* __restrict__ a1,
                                                       const float* __restrict__ scale,
                                                       const float* __restrict__ x0,
                                                       const float* __restrict__ mix,
                                                       ushort* __restrict__ xnout) {
    int row = blockIdx.x, t = threadIdx.x;
    size_t off = (size_t)row * DD + t * 4;
    float4 hv = *(const float4*)&h[off];
    float4 av = *(const float4*)&a0[off];
    float4 bv = *(const float4*)&a1[off];
    float4 sv = *(const float4*)&scale[t * 4];
    hv.x += sv.x * (av.x + bv.x);
    hv.y += sv.y * (av.y + bv.y);
    hv.z += sv.z * (av.z + bv.z);
    hv.w += sv.w * (av.w + bv.w);
    if (HASMIX) {
        float4 m0 = *(const float4*)&mix[t * 4];
        float4 m1 = *(const float4*)&mix[DD + t * 4];
        float4 xv = *(const float4*)&x0[off];
        hv.x = m0.x * hv.x + m1.x * xv.x;
        hv.y = m0.y * hv.y + m1.y * xv.y;
        hv.z = m0.z * hv.z + m1.z * xv.z;
        hv.w = m0.w * hv.w + m1.w * xv.w;
    }
    float ss = hv.x * hv.x + hv.y * hv.y + hv.z * hv.z + hv.w * hv.w;
    for (int o = 32; o; o >>= 1) ss += __shfl_xor(ss, o);
    __shared__ float wsum[4];
    int lane = t & 63, wid = t >> 6;
    if (lane == 0) wsum[wid] = ss;
    __syncthreads();
    float tot = wsum[0] + wsum[1] + wsum[2] + wsum[3];
    float r = rsqrtf(tot * (1.0f / DD) + F32_EPS);
    *(float4*)&h[off] = hv;
    uint2 pk;
    pk.x = f2bf(hv.x * r) | (f2bf(hv.y * r) << 16);
    pk.y = f2bf(hv.z * r) | (f2bf(hv.w * r) << 16);
    *(uint2*)&xnout[off] = pk;
}

// ---------------- bf16 MFMA GEMM, 2-phase double-buffered pipeline ----------------
// (unchanged from round 7 — verified)
template <int EPI>
__global__ __launch_bounds__(256) void gemm_bf16(const ushort* __restrict__ A,
                                                 const ushort* __restrict__ W,
                                                 float* __restrict__ Cf,
                                                 float* __restrict__ Cf2,
                                                 ushort* __restrict__ Cb,
                                                 int M, int N, int K, int lda, int ldw,
                                                 size_t partStride) {
    __shared__ __align__(16) ushort Als[2][128 * 64];
    __shared__ __align__(16) ushort Wls[2][128 * 64];
    const int tid  = threadIdx.x;
    const int wid  = tid >> 6, lane = tid & 63;
    const int wr   = wid >> 1, wc   = wid & 1;
    const int l15  = lane & 15, lhi = lane >> 4;

    const int gx = gridDim.x, gy = gridDim.y;
    int i = (blockIdx.z * gy + blockIdx.y) * gx + blockIdx.x;
    int G = gx * gy * (int)gridDim.z;
    int v = (i & 7) * (G >> 3) + (i >> 3);
    int mt = v % gy;
    int rest = v / gy;
    int nt = rest % gx;
    int zt = rest / gx;
    const int mbase = mt * 128, nbase = nt * 128;

    A  += (size_t)zt * K;
    W  += (size_t)zt * K;
    Cf += (size_t)zt * partStride;

    const int srow8  = lane >> 3;
    const int gchunk = ((lane & 7) ^ srow8) * 8;
    const ushort* Ag = A + (size_t)(mbase + wid * 32 + srow8) * lda + gchunk;
    const ushort* Wg = W + (size_t)(nbase + wid * 32 + srow8) * ldw + gchunk;
    const int ldsoff = (wid * 32) * 64;

    f32x4 acc[4][4] = {};
    const int swz  = (l15 & 7) << 3;
    const int aoff = (wr * 64 + l15) * 64;
    const int woff = (wc * 64 + l15) * 64;

    auto STAGE = [&](ushort* Alb, ushort* Wlb, int kk) {
#pragma unroll
        for (int s = 0; s < 4; ++s) {
            gl_lds16(Ag + kk + (size_t)s * 8 * lda, Alb + ldsoff + s * 8 * 64);
            gl_lds16(Wg + kk + (size_t)s * 8 * ldw, Wlb + ldsoff + s * 8 * 64);
        }
    };
    auto COMPUTE = [&](const ushort* Ab, const ushort* Wb) {
#pragma unroll
        for (int ks = 0; ks < 2; ++ks) {
            const int fcol = (ks * 32 + lhi * 8) ^ swz;
            bf16x8 af[4], bfm[4];
#pragma unroll
            for (int m = 0; m < 4; ++m)
                af[m] = *(const bf16x8*)(Ab + aoff + m * 1024 + fcol);
#pragma unroll
            for (int n = 0; n < 4; ++n)
                bfm[n] = *(const bf16x8*)(Wb + woff + n * 1024 + fcol);
#pragma unroll
            for (int m = 0; m < 4; ++m)
#pragma unroll
                for (int n = 0; n < 4; ++n)
                    acc[m][n] = __builtin_amdgcn_mfma_f32_16x16x32_bf16(
                        af[m], bfm[n], acc[m][n], 0, 0, 0);
        }
    };

    STAGE(Als[0], Wls[0], 0);
    __syncthreads();
    for (int k0 = 0; k0 < K; k0 += 128) {
        if (k0 + 64 < K) STAGE(Als[1], Wls[1], k0 + 64);
        COMPUTE(Als[0], Wls[0]);
        __syncthreads();
        if (k0 + 128 < K) STAGE(Als[0], Wls[0], k0 + 128);
        COMPUTE(Als[1], Wls[1]);
        __syncthreads();
    }

    int   colb = nbase;
    float* fdst = Cf;
    ushort* bdst = Cb;
    if (EPI == 3) {
        if (nbase < 1024)      { fdst = Cf;  colb = nbase; }
        else if (nbase < 2048) { fdst = Cf2; colb = nbase - 1024; }
        else                   { fdst = nullptr; colb = nbase - 2048; }
    }
    const int ldc = (EPI == 3) ? 1024 : N;
    const int row0 = mbase + wr * 64 + lhi * 4;
    const int col0 = colb + wc * 64 + l15;
#pragma unroll
    for (int m = 0; m < 4; ++m)
#pragma unroll
        for (int n = 0; n < 4; ++n) {
            int cc = col0 + n * 16;
#pragma unroll
            for (int r = 0; r < 4; ++r) {
                int rr = row0 + m * 16 + r;
                float v2 = acc[m][n][r];
                if (EPI == 0) {
                    fdst[(size_t)rr * ldc + cc] = v2;
                } else if (EPI == 1) {
                    v2 = fmaxf(v2, 0.0f); v2 = v2 * v2;
                    bdst[(size_t)rr * ldc + cc] = (ushort)f2bf(v2);
                } else {
                    if (fdst) fdst[(size_t)rr * ldc + cc] = v2;
                    else      bdst[(size_t)rr * ldc + cc] = (ushort)f2bf(v2);
                }
            }
        }
}

// ---------------- per-head RMS + RoPE; q gets gain*0.125 folded (score scale) ----------------
__global__ __launch_bounds__(256) void qknorm2_kernel(const float* __restrict__ qin,
                                                      const float* __restrict__ kin,
                                                      ushort* __restrict__ qout,
                                                      ushort* __restrict__ kout,
                                                      const float* __restrict__ cosT,
                                                      const float* __restrict__ sinT,
                                                      const float* __restrict__ gain) {
    int which = blockIdx.y;
    const float* src = which ? kin : qin;
    ushort* dst = which ? kout : qout;
    int gid = blockIdx.x * blockDim.x + threadIdx.x;
    int gw = gid >> 6, lane = gid & 63;
    int head = gw & (HH - 1);
    int c = (gw >> 4) & (CC - 1);
    int b = gw >> 14;
    size_t off = ((size_t)(b * CC + c)) * DD + head * HDIM + lane;
    float v = src[off];
    float ss = v * v;
    for (int o = 32; o; o >>= 1) ss += __shfl_xor(ss, o);
    float r = rsqrtf(ss * (1.0f / HDIM) + F32_EPS);
    float vn = v * r;
    float other = __shfl_xor(vn, 32);
    int i = lane & 31;
    float cv = cosT[c * 32 + i], sv = sinT[c * 32 + i];
    float out = (lane < 32) ? (vn * cv + other * sv) : (vn * cv - other * sv);
    if (which == 0) out *= gain[head] * 0.125f;   // fold 1/sqrt(HD) into q (exact pow2)
    dst[off] = (ushort)f2bf(out);
}

// ---------------- V transpose: v[b*CC+kv][h*64+d] -> vt[(b*16+h)*64+d][kv] ----------------
__global__ __launch_bounds__(256) void vtrans_kernel(const ushort* __restrict__ v,
                                                     ushort* __restrict__ vt) {
    __shared__ ushort Ls[64][72];
    int kt = blockIdx.x, head = blockIdx.y, b = blockIdx.z;
    int tid = threadIdx.x;
    int r = tid >> 3;               // 0..31
    int ch = (tid & 7) * 8;         // element chunk
#pragma unroll
    for (int s = 0; s < 2; ++s) {
        int kv = r + s * 32;
        int4 t4 = *(const int4*)&v[((size_t)(b * CC + kt * 64 + kv)) * DD + head * HDIM + ch];
        *(int4*)&Ls[kv][ch] = t4;
    }
    __syncthreads();
#pragma unroll
    for (int s = 0; s < 2; ++s) {
        int d = r + s * 32;
        ushort o[8];
#pragma unroll
        for (int j = 0; j < 8; ++j) o[j] = Ls[ch + j][d];
        *(int4*)&vt[((size_t)((b * HH + head) * HDIM + d)) * CC + kt * 64 + ch] = *(int4*)o;
    }
}

// ---------------- bf16 MFMA causal flash attention, STATIC-MAX softmax ----------------
// |score| <= ||q'||*||k|| <= (8*gain*0.125)*8 = 8*gain  (q' has gain/8 folded; RMS+RoPE
// norm-preserving). p = exp(s - 8*|gain|) never overflows; uniform scale cancels in the
// final divide. No running max, no rescale, row-sum reduced ONCE at the end.
__global__ __launch_bounds__(256) void attn_mfma(const ushort* __restrict__ q,
                                                 const ushort* __restrict__ k,
                                                 const ushort* __restrict__ vt,
                                                 ushort* __restrict__ y,
                                                 const float* __restrict__ gain) {
    __shared__ __align__(16) ushort Qs[64 * 64];  // [qrow][d  ^ sw]
    __shared__ __align__(16) ushort Ks[64 * 64];  // [kv]  [d  ^ sw]
    __shared__ __align__(16) ushort VT[64 * 64];  // [d]   [kv ^ sw]
    __shared__ __align__(16) ushort Ps[64 * 64];  // [qrow][kv ^ sw] (wave-private rows)
    const int qt = 15 - blockIdx.x;               // longest-first dispatch
    const int head = blockIdx.y, b = blockIdx.z;
    const int tid = threadIdx.x;
    const int wid = tid >> 6, lane = tid & 63;
    const int l15 = lane & 15, lhi = lane >> 4;
    const int wq0 = wid * 16;
    const int qbase = qt * 64;
    const float mstat = 8.0f * fabsf(gain[head]); // static softmax max bound

    const int srow = tid >> 3;            // 0..31
    const int scol = (tid & 7) * 8;       // 0..56 step 8

#pragma unroll
    for (int s = 0; s < 2; ++s) {
        int r = srow + s * 32;
        int4 t4 = *(const int4*)&q[((size_t)(b * CC + qbase + r)) * DD + head * HDIM + scol];
        *(int4*)&Qs[r * 64 + (scol ^ ((r & 7) << 3))] = t4;
    }

    f32x4 oacc[4] = {};
    float lpart[4] = {0.f, 0.f, 0.f, 0.f};

    for (int kt = 0; kt <= qt; ++kt) {
        __syncthreads();
#pragma unroll
        for (int s = 0; s < 2; ++s) {
            int r = srow + s * 32;
            int4 kv4 = *(const int4*)&k[((size_t)(b * CC + kt * 64 + r)) * DD + head * HDIM + scol];
            *(int4*)&Ks[r * 64 + (scol ^ ((r & 7) << 3))] = kv4;
            int4 vv4 = *(const int4*)&vt[((size_t)((b * HH + head) * HDIM + r)) * CC + kt * 64 + scol];
            *(int4*)&VT[r * 64 + (scol ^ ((r & 7) << 3))] = vv4;
        }
        __syncthreads();

        f32x4 sac[4] = {};
        __builtin_amdgcn_s_setprio(1);
#pragma unroll
        for (int ks = 0; ks < 2; ++ks) {
            int dcol = ks * 32 + lhi * 8;
            int arow = wq0 + l15;
            bf16x8 af = *(const bf16x8*)&Qs[arow * 64 + (dcol ^ ((arow & 7) << 3))];
#pragma unroll
            for (int n = 0; n < 4; ++n) {
                int krow = n * 16 + l15;
                bf16x8 bfr = *(const bf16x8*)&Ks[krow * 64 + (dcol ^ ((krow & 7) << 3))];
                sac[n] = __builtin_amdgcn_mfma_f32_16x16x32_bf16(af, bfr, sac[n], 0, 0, 0);
            }
        }
        __builtin_amdgcn_s_setprio(0);

        // p = exp(s - mstat); causal zeroing only on the diagonal tile (uniform branch)
        if (kt == qt) {
            const int kb0 = kt * 64;
#pragma unroll
            for (int r = 0; r < 4; ++r) {
                int qrow_g = qbase + wq0 + lhi * 4 + r;
                float p0 = __expf(sac[0][r] - mstat);
                float p1 = __expf(sac[1][r] - mstat);
                float p2 = __expf(sac[2][r] - mstat);
                float p3 = __expf(sac[3][r] - mstat);
                if (kb0 + l15      > qrow_g) p0 = 0.f;
                if (kb0 + 16 + l15 > qrow_g) p1 = 0.f;
                if (kb0 + 32 + l15 > qrow_g) p2 = 0.f;
                if (kb0 + 48 + l15 > qrow_g) p3 = 0.f;
                lpart[r] += (p0 + p1) + (p2 + p3);
                int qrow_l = wq0 + lhi * 4 + r;
                int pb = qrow_l * 64, sw = (qrow_l & 7) << 3;
                Ps[pb + ((l15)      ^ sw)] = (ushort)f2bf(p0);
                Ps[pb + ((16 + l15) ^ sw)] = (ushort)f2bf(p1);
                Ps[pb + ((32 + l15) ^ sw)] = (ushort)f2bf(p2);
                Ps[pb + ((48 + l15) ^ sw)] = (ushort)f2bf(p3);
            }
        } else {
#pragma unroll
            for (int r = 0; r < 4; ++r) {
                float p0 = __expf(sac[0][r] - mstat);
                float p1 = __expf(sac[1][r] - mstat);
                float p2 = __expf(sac[2][r] - mstat);
                float p3 = __expf(sac[3][r] - mstat);
                lpart[r] += (p0 + p1) + (p2 + p3);
                int qrow_l = wq0 + lhi * 4 + r;
                int pb = qrow_l * 64, sw = (qrow_l & 7) << 3;
                Ps[pb + ((l15)      ^ sw)] = (ushort)f2bf(p0);
                Ps[pb + ((16 + l15) ^ sw)] = (ushort)f2bf(p1);
                Ps[pb + ((32 + l15) ^ sw)] = (ushort)f2bf(p2);
                Ps[pb + ((48 + l15) ^ sw)] = (ushort)f2bf(p3);
            }
        }

        __builtin_amdgcn_s_setprio(1);
#pragma unroll
        for (int ks = 0; ks < 2; ++ks) {
            int kcol = ks * 32 + lhi * 8;
            int arow = wq0 + l15;
            bf16x8 pf = *(const bf16x8*)&Ps[arow * 64 + (kcol ^ ((arow & 7) << 3))];
#pragma unroll
            for (int n = 0; n < 4; ++n) {
                int vrow = n * 16 + l15;
                bf16x8 vf = *(const bf16x8*)&VT[vrow * 64 + (kcol ^ ((vrow & 7) << 3))];
                oacc[n] = __builtin_amdgcn_mfma_f32_16x16x32_bf16(pf, vf, oacc[n], 0, 0, 0);
            }
        }
        __builtin_amdgcn_s_setprio(0);
    }

    // single deferred row-sum reduce (16 lanes per row), then divide + store
#pragma unroll
    for (int r = 0; r < 4; ++r) {
        float ls = lpart[r];
#pragma unroll
        for (int off = 1; off < 16; off <<= 1) ls += __shfl_xor(ls, off);
        float inv = 1.0f / ls;
        int qrow_g = qbase + wq0 + lhi * 4 + r;
        size_t base = ((size_t)(b * CC + qrow_g)) * DD + head * HDIM;
#pragma unroll
        for (int n = 0; n < 4; ++n)
            y[base + n * 16 + l15] = (ushort)f2bf(oacc[n][r] * inv);
    }
}

// ---------------- final: out = (h + scale*(a0+a1)) * valid ----------------
__global__ void residmask_kernel(const float* __restrict__ h, const float* __restrict__ a0,
                                 const float* __restrict__ a1,
                                 const float* __restrict__ scale,
                                 const int* __restrict__ nch,
                                 float* __restrict__ out) {
    int idx = blockIdx.x * blockDim.x + threadIdx.x;   // per float4
    size_t off = (size_t)idx * 4;
    int c = (idx >> 8) & (CC - 1);
    int b = idx >> 18;
    float4 hv = *(const float4*)&h[off];
    float4 av = *(const float4*)&a0[off];
    float4 bv = *(const float4*)&a1[off];
    float4 sv = *(const float4*)&scale[(idx & 255) * 4];
    hv.x += sv.x * (av.x + bv.x);
    hv.y += sv.y * (av.y + bv.y);
    hv.z += sv.z * (av.z + bv.z);
    hv.w += sv.w * (av.w + bv.w);
    if (c >= nch[b]) hv = make_float4(0.f, 0.f, 0.f, 0.f);
    *(float4*)&out[off] = hv;
}

extern "C" void kernel_launch(void* const* d_in, const int* in_sizes, int n_in,
                              void* d_out, int out_size, void* d_ws, size_t ws_size,
                              hipStream_t stream) {
    const float* x        = (const float*)d_in[0];
    const int*   boundary = (const int*)d_in[1];
    const float* Wq       = (const float*)d_in[2];
    const float* Wk       = (const float*)d_in[3];
    const float* Wv       = (const float*)d_in[4];
    const float* Wo       = (const float*)d_in[5];
    const float* qg       = (const float*)d_in[6];
    const float* fcw      = (const float*)d_in[7];
    const float* projw    = (const float*)d_in[8];
    const float* ascale   = (const float*)d_in[9];
    const float* mscale   = (const float*)d_in[10];
    const float* rmix     = (const float*)d_in[11];
    float* out = (float*)d_out;

    const size_t NTOK = (size_t)BB * CC * DD;           // 4M elems
    const size_t NHID = (size_t)BB * CC * DFF;          // 16M elems
    const size_t D2   = (size_t)DD * DD;                // 1M elems

    float* ws   = (float*)d_ws;
    float*  h    = ws;
    float*  x0   = h  + NTOK;
    float*  qb   = x0 + NTOK;            // f32 q (pre-norm) / split-K partial 0
    float*  kb   = qb + NTOK;            // f32 k (pre-norm) / split-K partial 1 (contiguous)
    ushort* xnb  = (ushort*)(kb + NTOK);
    ushort* ybf  = xnb + NTOK;
    ushort* hidb = ybf + NTOK;           // 16M bf16; doubles as qbb/kbb/vbb during attn
    ushort* wbuf = hidb + NHID;          // 16M bf16: per-layer weights (mega-cast)
    ushort* vtb  = wbuf + NHID;          // 4M bf16 (V transposed)
    float*  cosT = (float*)(vtb + NTOK);
    float*  sinT = cosT + (size_t)CC * 32;
    int*    starts = (int*)(sinT + (size_t)CC * 32);
    int*    nch    = starts + BB * (CC + 1);

    ushort* qbb = hidb;                  // bf16 q (post-norm)
    ushort* kbb = hidb + NTOK;           // bf16 k (post-norm)
    ushort* vbb = hidb + 2 * NTOK;       // bf16 v

    ushort* wqkv = wbuf;                 // [0, 3M)
    ushort* wwo  = wbuf + 3 * D2;        // [3M, 4M)
    ushort* wfc  = wbuf + 4 * D2;        // [4M, 8M)
    ushort* wpj  = wbuf + 8 * D2;        // [8M, 12M)

    const int M = BB * CC;  // 4096 rows
    const int CASTL = (int)(12 * D2 / 8 / 256);         // 6144 blocks

    rope_init_kernel<<<CC * 32 / 256, 256, 0, stream>>>(cosT, sinT);
    scan_kernel<<<BB, 1024, 0, stream>>>(boundary, starts, nch);
    latents_kernel<<<dim3(CC, BB), 256, 0, stream>>>(x, starts, h, x0);
    rmsmix_kernel<<<M, 256, 0, stream>>>(h, x0, rmix, h, xnb);   // layer-0 entry

    for (int l = 0; l < LL; ++l) {
        // one mega-cast for all this layer's weights
        castlayer_kernel<<<CASTL, 256, 0, stream>>>(Wq + l * D2, Wk + l * D2, Wv + l * D2,
                                                    Wo + l * D2,
                                                    fcw + (size_t)l * DFF * DD,
                                                    projw + (size_t)l * DD * DFF, wbuf);
        // fused QKV: C[M,3072] routed -> qb(f32), kb(f32), vbb(bf16)
        gemm_bf16<3><<<dim3(3 * DD / 128, M / 128, 1), 256, 0, stream>>>(
            xnb, wqkv, qb, kb, vbb, M, 3 * DD, DD, DD, DD, 0);
        // per-head RMS + RoPE -> bf16 (q with gain/8 folded)
        qknorm2_kernel<<<dim3((BB * CC * HH * 64) / 256, 2), 256, 0, stream>>>(
            qb, kb, qbb, kbb, cosT, sinT, qg + l * HH);
        // V transpose (once), then MFMA attention -> ybf
        vtrans_kernel<<<dim3(CC / 64, HH, BB), 256, 0, stream>>>(vbb, vtb);
        attn_mfma<<<dim3(16, HH, BB), 256, 0, stream>>>(qbb, kbb, vtb, ybf, qg + l * HH);
        // a = y @ Wo^T, split-K=2 -> partials qb,kb; fused resid+rms -> xnb
        gemm_bf16<0><<<dim3(DD / 128, M / 128, 2), 256, 0, stream>>>(
            ybf, wwo, qb, nullptr, nullptr, M, DD, DD / 2, DD, DD, NTOK);
        residrms_kernel<0><<<M, 256, 0, stream>>>(h, qb, kb, ascale + l * DD,
                                                  nullptr, nullptr, xnb);
        // MLP: fc (relu^2, bf16) then proj split-K=2
        gemm_bf16<1><<<dim3(DFF / 128, M / 128, 1), 256, 0, stream>>>(
            xnb, wfc, nullptr, nullptr, hidb, M, DFF, DD, DD, DD, 0);
        gemm_bf16<0><<<dim3(DD / 128, M / 128, 2), 256, 0, stream>>>(
            hidb, wpj, qb, nullptr, nullptr, M, DD, DFF / 2, DFF, DFF, NTOK);
        if (l < LL - 1) {
            residrms_kernel<1><<<M, 256, 0, stream>>>(h, qb, kb, mscale + l * DD,
                                                      x0, rmix + (size_t)(l + 1) * 2 * DD, xnb);
        } else {
            residmask_kernel<<<(int)(NTOK / 4 / 256), 256, 0, stream>>>(
                h, qb, kb, mscale + l * DD, nch, out);
        }
    }
}

// Round 10
// 977.601 us; speedup vs baseline: 1.3526x; 1.0592x over previous
//
#include <hip/hip_runtime.h>
#include <math.h>

// Problem constants (fixed by reference)
#define BB   4
#define SS   4096
#define DD   1024
#define HH   16
#define HDIM 64
#define CC   1024      // MAX_CHUNKS
#define DFF  4096
#define LL   4

static constexpr float F32_EPS = 1.1920928955078125e-07f;  // jnp.finfo(f32).eps

typedef __attribute__((ext_vector_type(8))) __bf16 bf16x8;
typedef __attribute__((ext_vector_type(4))) float  f32x4;

__device__ __forceinline__ uint f2bf(float f) {
    uint u = __float_as_uint(f);
    return (u + 0x7fffu + ((u >> 16) & 1u)) >> 16;   // RNE
}

// direct global->LDS DMA, 16 bytes per lane; lds dest must be wave-uniform
__device__ __forceinline__ void gl_lds16(const ushort* g, ushort* l) {
    __builtin_amdgcn_global_load_lds(
        (const __attribute__((address_space(1))) unsigned int*)g,
        (__attribute__((address_space(3))) unsigned int*)l, 16, 0, 0);
}

// ---------------- per-layer mega-cast: all 5 weight mats f32 -> bf16 in one launch --------
__global__ __launch_bounds__(256) void castlayer_kernel(const float* __restrict__ Wq,
                                                        const float* __restrict__ Wk,
                                                        const float* __restrict__ Wv,
                                                        const float* __restrict__ Wo,
                                                        const float* __restrict__ fc,
                                                        const float* __restrict__ proj,
                                                        ushort* __restrict__ out) {
    int i = blockIdx.x * blockDim.x + threadIdx.x;      // 8-elem chunk id, 0..12M/8
    const int U = DD * DD / 8;                          // 131072
    const float* src;
    if (i < 3 * U) {
        src = (i < U ? Wq : (i < 2 * U ? Wk : Wv)) + (size_t)(i < U ? i : (i < 2*U ? i-U : i-2*U)) * 8;
    } else if (i < 4 * U) {
        src = Wo + (size_t)(i - 3 * U) * 8;
    } else if (i < 8 * U) {
        src = fc + (size_t)(i - 4 * U) * 8;
    } else {
        src = proj + (size_t)(i - 8 * U) * 8;
    }
    const float4* p = (const float4*)src;
    float4 a = p[0], b = p[1];
    uint4 o;
    o.x = f2bf(a.x) | (f2bf(a.y) << 16);
    o.y = f2bf(a.z) | (f2bf(a.w) << 16);
    o.z = f2bf(b.x) | (f2bf(b.y) << 16);
    o.w = f2bf(b.z) | (f2bf(b.w) << 16);
    *(uint4*)(out + (size_t)i * 8) = o;
}

// ---------------- RoPE tables ----------------
__global__ void rope_init_kernel(float* __restrict__ cosT, float* __restrict__ sinT) {
    int idx = blockIdx.x * blockDim.x + threadIdx.x;   // over CC*32
    int pos = idx >> 5;
    int i   = idx & 31;
    float inv = powf(10000.0f, -(float)i / 32.0f);
    float f = (float)pos * inv;
    cosT[idx] = cosf(f);
    sinT[idx] = sinf(f);
}

// ---------------- boundary scan -> chunk starts, num_chunks ----------------
__global__ __launch_bounds__(1024) void scan_kernel(const int* __restrict__ boundary,
                                                    int* __restrict__ starts,
                                                    int* __restrict__ nch) {
    __shared__ int tmp[1024];
    int b = blockIdx.x, t = threadIdx.x;
    int base = b * SS + t * 4;
    int v0 = boundary[base + 0], v1 = boundary[base + 1];
    int v2 = boundary[base + 2], v3 = boundary[base + 3];
    int p0 = v0, p1 = p0 + v1, p2 = p1 + v2, p3 = p2 + v3;
    tmp[t] = p3;
    __syncthreads();
    for (int off = 1; off < 1024; off <<= 1) {
        int add = (t >= off) ? tmp[t - off] : 0;
        __syncthreads();
        tmp[t] += add;
        __syncthreads();
    }
    int excl = tmp[t] - p3;
    if (v0) starts[b * (CC + 1) + (excl + p0 - 1)] = t * 4 + 0;
    if (v1) starts[b * (CC + 1) + (excl + p1 - 1)] = t * 4 + 1;
    if (v2) starts[b * (CC + 1) + (excl + p2 - 1)] = t * 4 + 2;
    if (v3) starts[b * (CC + 1) + (excl + p3 - 1)] = t * 4 + 3;
    int total = tmp[1023];
    if (t == 0) nch[b] = total;
    for (int c = t; c <= CC; c += 1024)
        if (c >= total) starts[b * (CC + 1) + c] = SS;
}

// ---------------- chunk means -> h and x0 ----------------
__global__ __launch_bounds__(256) void latents_kernel(const float* __restrict__ x,
                                                      const int* __restrict__ starts,
                                                      float* __restrict__ h,
                                                      float* __restrict__ x0) {
    int c = blockIdx.x, b = blockIdx.y, t = threadIdx.x;
    int s0 = starts[b * (CC + 1) + c];
    int s1 = starts[b * (CC + 1) + c + 1];
    float a0 = 0.f, a1 = 0.f, a2 = 0.f, a3 = 0.f;
    for (int r = s0; r < s1; ++r) {
        const float4 xv = *(const float4*)&x[((size_t)(b * SS + r)) * DD + t * 4];
        a0 += xv.x; a1 += xv.y; a2 += xv.z; a3 += xv.w;
    }
    float inv = (s1 > s0) ? 1.0f / (float)(s1 - s0) : 0.0f;
    float4 o = make_float4(a0 * inv, a1 * inv, a2 * inv, a3 * inv);
    size_t off = ((size_t)(b * CC + c)) * DD + t * 4;
    *(float4*)&h[off]  = o;
    *(float4*)&x0[off] = o;
}

// ---------------- resid-mix + row RMS norm (layer-0 entry), bf16 normed out ----------------
__global__ __launch_bounds__(256) void rmsmix_kernel(const float* __restrict__ hin,
                                                     const float* __restrict__ x0,
                                                     const float* __restrict__ mix,
                                                     float* __restrict__ hout,
                                                     ushort* __restrict__ xnout) {
    int row = blockIdx.x, t = threadIdx.x;
    size_t off = (size_t)row * DD + t * 4;
    float4 hv = *(const float4*)&hin[off];
    float4 m0 = *(const float4*)&mix[t * 4];
    float4 m1 = *(const float4*)&mix[DD + t * 4];
    float4 xv = *(const float4*)&x0[off];
    hv.x = m0.x * hv.x + m1.x * xv.x;
    hv.y = m0.y * hv.y + m1.y * xv.y;
    hv.z = m0.z * hv.z + m1.z * xv.z;
    hv.w = m0.w * hv.w + m1.w * xv.w;
    float ss = hv.x * hv.x + hv.y * hv.y + hv.z * hv.z + hv.w * hv.w;
    for (int o = 32; o; o >>= 1) ss += __shfl_xor(ss, o);
    __shared__ float wsum[4];
    int lane = t & 63, wid = t >> 6;
    if (lane == 0) wsum[wid] = ss;
    __syncthreads();
    float tot = wsum[0] + wsum[1] + wsum[2] + wsum[3];
    float r = rsqrtf(tot * (1.0f / DD) + F32_EPS);
    *(float4*)&hout[off] = hv;
    uint2 pk;
    pk.x = f2bf(hv.x * r) | (f2bf(hv.y * r) << 16);
    pk.y = f2bf(hv.z * r) | (f2bf(hv.w * r) << 16);
    *(uint2*)&xnout[off] = pk;
}

// ---------------- fused: h += scale*(a0+a1); [h = m0*h+m1*x0]; xn = bf16(rms(h)) ----------------
template <int HASMIX>
__global__ __launch_bounds__(256) void residrms_kernel(float* __restrict__ h,
                                                       const float* __restrict__ a0,
                                                       const float* __restrict__ a1,
                                                       const float* __restrict__ scale,
                                                       const float* __restrict__ x0,
                                                       const float* __restrict__ mix,
                                                       ushort* __restrict__ xnout) {
    int row = blockIdx.x, t = threadIdx.x;
    size_t off = (size_t)row * DD + t * 4;
    float4 hv = *(const float4*)&h[off];
    float4 av = *(const float4*)&a0[off];
    float4 bv = *(const float4*)&a1[off];
    float4 sv = *(const float4*)&scale[t * 4];
    hv.x += sv.x * (av.x + bv.x);
    hv.y += sv.y * (av.y + bv.y);
    hv.z += sv.z * (av.z + bv.z);
    hv.w += sv.w * (av.w + bv.w);
    if (HASMIX) {
        float4 m0 = *(const float4*)&mix[t * 4];
        float4 m1 = *(const float4*)&mix[DD + t * 4];
        float4 xv = *(const float4*)&x0[off];
        hv.x = m0.x * hv.x + m1.x * xv.x;
        hv.y = m0.y * hv.y + m1.y * xv.y;
        hv.z = m0.z * hv.z + m1.z * xv.z;
        hv.w = m0.w * hv.w + m1.w * xv.w;
    }
    float ss = hv.x * hv.x + hv.y * hv.y + hv.z * hv.z + hv.w * hv.w;
    for (int o = 32; o; o >>= 1) ss += __shfl_xor(ss, o);
    __shared__ float wsum[4];
    int lane = t & 63, wid = t >> 6;
    if (lane == 0) wsum[wid] = ss;
    __syncthreads();
    float tot = wsum[0] + wsum[1] + wsum[2] + wsum[3];
    float r = rsqrtf(tot * (1.0f / DD) + F32_EPS);
    *(float4*)&h[off] = hv;
    uint2 pk;
    pk.x = f2bf(hv.x * r) | (f2bf(hv.y * r) << 16);
    pk.y = f2bf(hv.z * r) | (f2bf(hv.w * r) << 16);
    *(uint2*)&xnout[off] = pk;
}

// ---------------- bf16 MFMA GEMM, 2-phase double-buffered pipeline (r7, verified) ----------------
template <int EPI>
__global__ __launch_bounds__(256) void gemm_bf16(const ushort* __restrict__ A,
                                                 const ushort* __restrict__ W,
                                                 float* __restrict__ Cf,
                                                 float* __restrict__ Cf2,
                                                 ushort* __restrict__ Cb,
                                                 int M, int N, int K, int lda, int ldw,
                                                 size_t partStride) {
    __shared__ __align__(16) ushort Als[2][128 * 64];
    __shared__ __align__(16) ushort Wls[2][128 * 64];
    const int tid  = threadIdx.x;
    const int wid  = tid >> 6, lane = tid & 63;
    const int wr   = wid >> 1, wc   = wid & 1;
    const int l15  = lane & 15, lhi = lane >> 4;

    const int gx = gridDim.x, gy = gridDim.y;
    int i = (blockIdx.z * gy + blockIdx.y) * gx + blockIdx.x;
    int G = gx * gy * (int)gridDim.z;
    int v = (i & 7) * (G >> 3) + (i >> 3);
    int mt = v % gy;
    int rest = v / gy;
    int nt = rest % gx;
    int zt = rest / gx;
    const int mbase = mt * 128, nbase = nt * 128;

    A  += (size_t)zt * K;
    W  += (size_t)zt * K;
    Cf += (size_t)zt * partStride;

    const int srow8  = lane >> 3;
    const int gchunk = ((lane & 7) ^ srow8) * 8;
    const ushort* Ag = A + (size_t)(mbase + wid * 32 + srow8) * lda + gchunk;
    const ushort* Wg = W + (size_t)(nbase + wid * 32 + srow8) * ldw + gchunk;
    const int ldsoff = (wid * 32) * 64;

    f32x4 acc[4][4] = {};
    const int swz  = (l15 & 7) << 3;
    const int aoff = (wr * 64 + l15) * 64;
    const int woff = (wc * 64 + l15) * 64;

    auto STAGE = [&](ushort* Alb, ushort* Wlb, int kk) {
#pragma unroll
        for (int s = 0; s < 4; ++s) {
            gl_lds16(Ag + kk + (size_t)s * 8 * lda, Alb + ldsoff + s * 8 * 64);
            gl_lds16(Wg + kk + (size_t)s * 8 * ldw, Wlb + ldsoff + s * 8 * 64);
        }
    };
    auto COMPUTE = [&](const ushort* Ab, const ushort* Wb) {
#pragma unroll
        for (int ks = 0; ks < 2; ++ks) {
            const int fcol = (ks * 32 + lhi * 8) ^ swz;
            bf16x8 af[4], bfm[4];
#pragma unroll
            for (int m = 0; m < 4; ++m)
                af[m] = *(const bf16x8*)(Ab + aoff + m * 1024 + fcol);
#pragma unroll
            for (int n = 0; n < 4; ++n)
                bfm[n] = *(const bf16x8*)(Wb + woff + n * 1024 + fcol);
#pragma unroll
            for (int m = 0; m < 4; ++m)
#pragma unroll
                for (int n = 0; n < 4; ++n)
                    acc[m][n] = __builtin_amdgcn_mfma_f32_16x16x32_bf16(
                        af[m], bfm[n], acc[m][n], 0, 0, 0);
        }
    };

    STAGE(Als[0], Wls[0], 0);
    __syncthreads();
    for (int k0 = 0; k0 < K; k0 += 128) {
        if (k0 + 64 < K) STAGE(Als[1], Wls[1], k0 + 64);
        COMPUTE(Als[0], Wls[0]);
        __syncthreads();
        if (k0 + 128 < K) STAGE(Als[0], Wls[0], k0 + 128);
        COMPUTE(Als[1], Wls[1]);
        __syncthreads();
    }

    int   colb = nbase;
    float* fdst = Cf;
    ushort* bdst = Cb;
    if (EPI == 3) {
        if (nbase < 1024)      { fdst = Cf;  colb = nbase; }
        else if (nbase < 2048) { fdst = Cf2; colb = nbase - 1024; }
        else                   { fdst = nullptr; colb = nbase - 2048; }
    }
    const int ldc = (EPI == 3) ? 1024 : N;
    const int row0 = mbase + wr * 64 + lhi * 4;
    const int col0 = colb + wc * 64 + l15;
#pragma unroll
    for (int m = 0; m < 4; ++m)
#pragma unroll
        for (int n = 0; n < 4; ++n) {
            int cc = col0 + n * 16;
#pragma unroll
            for (int r = 0; r < 4; ++r) {
                int rr = row0 + m * 16 + r;
                float v2 = acc[m][n][r];
                if (EPI == 0) {
                    fdst[(size_t)rr * ldc + cc] = v2;
                } else if (EPI == 1) {
                    v2 = fmaxf(v2, 0.0f); v2 = v2 * v2;
                    bdst[(size_t)rr * ldc + cc] = (ushort)f2bf(v2);
                } else {
                    if (fdst) fdst[(size_t)rr * ldc + cc] = v2;
                    else      bdst[(size_t)rr * ldc + cc] = (ushort)f2bf(v2);
                }
            }
        }
}

// ---------------- per-head RMS + RoPE; q gets gain*0.125 folded (score scale) ----------------
__global__ __launch_bounds__(256) void qknorm2_kernel(const float* __restrict__ qin,
                                                      const float* __restrict__ kin,
                                                      ushort* __restrict__ qout,
                                                      ushort* __restrict__ kout,
                                                      const float* __restrict__ cosT,
                                                      const float* __restrict__ sinT,
                                                      const float* __restrict__ gain) {
    int which = blockIdx.y;
    const float* src = which ? kin : qin;
    ushort* dst = which ? kout : qout;
    int gid = blockIdx.x * blockDim.x + threadIdx.x;
    int gw = gid >> 6, lane = gid & 63;
    int head = gw & (HH - 1);
    int c = (gw >> 4) & (CC - 1);
    int b = gw >> 14;
    size_t off = ((size_t)(b * CC + c)) * DD + head * HDIM + lane;
    float v = src[off];
    float ss = v * v;
    for (int o = 32; o; o >>= 1) ss += __shfl_xor(ss, o);
    float r = rsqrtf(ss * (1.0f / HDIM) + F32_EPS);
    float vn = v * r;
    float other = __shfl_xor(vn, 32);
    int i = lane & 31;
    float cv = cosT[c * 32 + i], sv = sinT[c * 32 + i];
    float out = (lane < 32) ? (vn * cv + other * sv) : (vn * cv - other * sv);
    if (which == 0) out *= gain[head] * 0.125f;   // fold 1/sqrt(HD) into q (exact pow2)
    dst[off] = (ushort)f2bf(out);
}

// ---------------- V transpose: v[b*CC+kv][h*64+d] -> vt[(b*16+h)*64+d][kv] ----------------
__global__ __launch_bounds__(256) void vtrans_kernel(const ushort* __restrict__ v,
                                                     ushort* __restrict__ vt) {
    __shared__ ushort Ls[64][72];
    int kt = blockIdx.x, head = blockIdx.y, b = blockIdx.z;
    int tid = threadIdx.x;
    int r = tid >> 3;               // 0..31
    int ch = (tid & 7) * 8;         // element chunk
#pragma unroll
    for (int s = 0; s < 2; ++s) {
        int kv = r + s * 32;
        int4 t4 = *(const int4*)&v[((size_t)(b * CC + kt * 64 + kv)) * DD + head * HDIM + ch];
        *(int4*)&Ls[kv][ch] = t4;
    }
    __syncthreads();
#pragma unroll
    for (int s = 0; s < 2; ++s) {
        int d = r + s * 32;
        ushort o[8];
#pragma unroll
        for (int j = 0; j < 8; ++j) o[j] = Ls[ch + j][d];
        *(int4*)&vt[((size_t)((b * HH + head) * HDIM + d)) * CC + kt * 64 + ch] = *(int4*)o;
    }
}

// ---------------- bf16 MFMA causal flash attention: QBLK=128, 8 waves (512 thr),
// static-max softmax, T14 async-stage (K/V prefetched to regs one tile ahead) ----------------
__global__ __launch_bounds__(512) void attn_mfma(const ushort* __restrict__ q,
                                                 const ushort* __restrict__ k,
                                                 const ushort* __restrict__ vt,
                                                 ushort* __restrict__ y,
                                                 const float* __restrict__ gain) {
    __shared__ __align__(16) ushort Qs[128 * 64]; // [qrow][d  ^ sw]
    __shared__ __align__(16) ushort Ks[64 * 64];  // [kv]  [d  ^ sw]
    __shared__ __align__(16) ushort VT[64 * 64];  // [d]   [kv ^ sw]
    __shared__ __align__(16) ushort Ps[128 * 64]; // [qrow][kv ^ sw] (wave-private rows)
    const int qt = 7 - blockIdx.x;                // longest-first dispatch (qt = 0..7)
    const int head = blockIdx.y, b = blockIdx.z;
    const int tid = threadIdx.x;
    const int wid = tid >> 6, lane = tid & 63;    // 8 waves (512 threads), 16 q-rows each
    const int l15 = lane & 15, lhi = lane >> 4;
    const int wq0 = wid * 16;                     // 0..112
    const int qbase = qt * 128;
    const float mstat = 8.0f * fabsf(gain[head]); // static softmax max bound

    const int srow = tid >> 3;            // 0..63 (512 threads)
    const int scol = (tid & 7) * 8;       // 0..56 step 8

    // stage Q once (128 rows, 2 passes of 64 rows)
#pragma unroll
    for (int s = 0; s < 2; ++s) {
        int r = srow + s * 64;
        int4 t4 = *(const int4*)&q[((size_t)(b * CC + qbase + r)) * DD + head * HDIM + scol];
        *(int4*)&Qs[r * 64 + (scol ^ ((r & 7) << 3))] = t4;
    }

    f32x4 oacc[4] = {};
    float lpart[4] = {0.f, 0.f, 0.f, 0.f};

    const int NT = 2 * qt + 2;            // KV tiles (always even)

    auto LOADK = [&](int4& kr, int4& vr, int kt_) {
        kr = *(const int4*)&k[((size_t)(b * CC + kt_ * 64 + srow)) * DD + head * HDIM + scol];
        vr = *(const int4*)&vt[((size_t)((b * HH + head) * HDIM + srow)) * CC + kt_ * 64 + scol];
    };
    auto WRITEK = [&](const int4& kr, const int4& vr) {
        *(int4*)&Ks[srow * 64 + (scol ^ ((srow & 7) << 3))] = kr;
        *(int4*)&VT[srow * 64 + (scol ^ ((srow & 7) << 3))] = vr;
    };
    auto TILE = [&](int kt) {
        f32x4 sac[4] = {};
        __builtin_amdgcn_s_setprio(1);
#pragma unroll
        for (int ks = 0; ks < 2; ++ks) {
            int dcol = ks * 32 + lhi * 8;
            int arow = wq0 + l15;
            bf16x8 af = *(const bf16x8*)&Qs[arow * 64 + (dcol ^ ((arow & 7) << 3))];
#pragma unroll
            for (int n = 0; n < 4; ++n) {
                int krow = n * 16 + l15;
                bf16x8 bfr = *(const bf16x8*)&Ks[krow * 64 + (dcol ^ ((krow & 7) << 3))];
                sac[n] = __builtin_amdgcn_mfma_f32_16x16x32_bf16(af, bfr, sac[n], 0, 0, 0);
            }
        }
        __builtin_amdgcn_s_setprio(0);

        if (kt >= 2 * qt) {               // diagonal-region tiles (last two)
            const int kb0 = kt * 64;
#pragma unroll
            for (int r = 0; r < 4; ++r) {
                int qrow_g = qbase + wq0 + lhi * 4 + r;
                float p0 = __expf(sac[0][r] - mstat);
                float p1 = __expf(sac[1][r] - mstat);
                float p2 = __expf(sac[2][r] - mstat);
                float p3 = __expf(sac[3][r] - mstat);
                if (kb0 + l15      > qrow_g) p0 = 0.f;
                if (kb0 + 16 + l15 > qrow_g) p1 = 0.f;
                if (kb0 + 32 + l15 > qrow_g) p2 = 0.f;
                if (kb0 + 48 + l15 > qrow_g) p3 = 0.f;
                lpart[r] += (p0 + p1) + (p2 + p3);
                int qrow_l = wq0 + lhi * 4 + r;
                int pb = qrow_l * 64, sw = (qrow_l & 7) << 3;
                Ps[pb + ((l15)      ^ sw)] = (ushort)f2bf(p0);
                Ps[pb + ((16 + l15) ^ sw)] = (ushort)f2bf(p1);
                Ps[pb + ((32 + l15) ^ sw)] = (ushort)f2bf(p2);
                Ps[pb + ((48 + l15) ^ sw)] = (ushort)f2bf(p3);
            }
        } else {
#pragma unroll
            for (int r = 0; r < 4; ++r) {
                float p0 = __expf(sac[0][r] - mstat);
                float p1 = __expf(sac[1][r] - mstat);
                float p2 = __expf(sac[2][r] - mstat);
                float p3 = __expf(sac[3][r] - mstat);
                lpart[r] += (p0 + p1) + (p2 + p3);
                int qrow_l = wq0 + lhi * 4 + r;
                int pb = qrow_l * 64, sw = (qrow_l & 7) << 3;
                Ps[pb + ((l15)      ^ sw)] = (ushort)f2bf(p0);
                Ps[pb + ((16 + l15) ^ sw)] = (ushort)f2bf(p1);
                Ps[pb + ((32 + l15) ^ sw)] = (ushort)f2bf(p2);
                Ps[pb + ((48 + l15) ^ sw)] = (ushort)f2bf(p3);
            }
        }

        __builtin_amdgcn_s_setprio(1);
#pragma unroll
        for (int ks = 0; ks < 2; ++ks) {
            int kcol = ks * 32 + lhi * 8;
            int arow = wq0 + l15;
            bf16x8 pf = *(const bf16x8*)&Ps[arow * 64 + (kcol ^ ((arow & 7) << 3))];
#pragma unroll
            for (int n = 0; n < 4; ++n) {
                int vrow = n * 16 + l15;
                bf16x8 vf = *(const bf16x8*)&VT[vrow * 64 + (kcol ^ ((vrow & 7) << 3))];
                oacc[n] = __builtin_amdgcn_mfma_f32_16x16x32_bf16(pf, vf, oacc[n], 0, 0, 0);
            }
        }
        __builtin_amdgcn_s_setprio(0);
    };

    // T14 2-step pipeline: regs loaded one tile ahead, written after the barrier
    int4 kra, vra, krb, vrb;
    LOADK(kra, vra, 0);
    for (int kt = 0; kt < NT; kt += 2) {
        __syncthreads();                  // prior tile's LDS reads done
        WRITEK(kra, vra);                 // (compiler inserts vmcnt wait on kra/vra)
        __syncthreads();
        LOADK(krb, vrb, kt + 1);          // flies under TILE(kt)
        TILE(kt);
        __syncthreads();
        WRITEK(krb, vrb);
        __syncthreads();
        if (kt + 2 < NT) LOADK(kra, vra, kt + 2);
        TILE(kt + 1);
    }

    // single deferred row-sum reduce (16 lanes per row), then divide + store
#pragma unroll
    for (int r = 0; r < 4; ++r) {
        float ls = lpart[r];
#pragma unroll
        for (int off = 1; off < 16; off <<= 1) ls += __shfl_xor(ls, off);
        float inv = 1.0f / ls;
        int qrow_g = qbase + wq0 + lhi * 4 + r;
        size_t base = ((size_t)(b * CC + qrow_g)) * DD + head * HDIM;
#pragma unroll
        for (int n = 0; n < 4; ++n)
            y[base + n * 16 + l15] = (ushort)f2bf(oacc[n][r] * inv);
    }
}

// ---------------- final: out = (h + scale*(a0+a1)) * valid ----------------
__global__ void residmask_kernel(const float* __restrict__ h, const float* __restrict__ a0,
                                 const float* __restrict__ a1,
                                 const float* __restrict__ scale,
                                 const int* __restrict__ nch,
                                 float* __restrict__ out) {
    int idx = blockIdx.x * blockDim.x + threadIdx.x;   // per float4
    size_t off = (size_t)idx * 4;
    int c = (idx >> 8) & (CC - 1);
    int b = idx >> 18;
    float4 hv = *(const float4*)&h[off];
    float4 av = *(const float4*)&a0[off];
    float4 bv = *(const float4*)&a1[off];
    float4 sv = *(const float4*)&scale[(idx & 255) * 4];
    hv.x += sv.x * (av.x + bv.x);
    hv.y += sv.y * (av.y + bv.y);
    hv.z += sv.z * (av.z + bv.z);
    hv.w += sv.w * (av.w + bv.w);
    if (c >= nch[b]) hv = make_float4(0.f, 0.f, 0.f, 0.f);
    *(float4*)&out[off] = hv;
}

extern "C" void kernel_launch(void* const* d_in, const int* in_sizes, int n_in,
                              void* d_out, int out_size, void* d_ws, size_t ws_size,
                              hipStream_t stream) {
    const float* x        = (const float*)d_in[0];
    const int*   boundary = (const int*)d_in[1];
    const float* Wq       = (const float*)d_in[2];
    const float* Wk       = (const float*)d_in[3];
    const float* Wv       = (const float*)d_in[4];
    const float* Wo       = (const float*)d_in[5];
    const float* qg       = (const float*)d_in[6];
    const float* fcw      = (const float*)d_in[7];
    const float* projw    = (const float*)d_in[8];
    const float* ascale   = (const float*)d_in[9];
    const float* mscale   = (const float*)d_in[10];
    const float* rmix     = (const float*)d_in[11];
    float* out = (float*)d_out;

    const size_t NTOK = (size_t)BB * CC * DD;           // 4M elems
    const size_t NHID = (size_t)BB * CC * DFF;          // 16M elems
    const size_t D2   = (size_t)DD * DD;                // 1M elems

    float* ws   = (float*)d_ws;
    float*  h    = ws;
    float*  x0   = h  + NTOK;
    float*  qb   = x0 + NTOK;            // f32 q (pre-norm) / split-K partial 0
    float*  kb   = qb + NTOK;            // f32 k (pre-norm) / split-K partial 1 (contiguous)
    ushort* xnb  = (ushort*)(kb + NTOK);
    ushort* ybf  = xnb + NTOK;
    ushort* hidb = ybf + NTOK;           // 16M bf16; doubles as qbb/kbb/vbb during attn
    ushort* wbuf = hidb + NHID;          // 16M bf16: per-layer weights (mega-cast)
    ushort* vtb  = wbuf + NHID;          // 4M bf16 (V transposed)
    float*  cosT = (float*)(vtb + NTOK);
    float*  sinT = cosT + (size_t)CC * 32;
    int*    starts = (int*)(sinT + (size_t)CC * 32);
    int*    nch    = starts + BB * (CC + 1);

    ushort* qbb = hidb;                  // bf16 q (post-norm)
    ushort* kbb = hidb + NTOK;           // bf16 k (post-norm)
    ushort* vbb = hidb + 2 * NTOK;       // bf16 v

    ushort* wqkv = wbuf;                 // [0, 3M)
    ushort* wwo  = wbuf + 3 * D2;        // [3M, 4M)
    ushort* wfc  = wbuf + 4 * D2;        // [4M, 8M)
    ushort* wpj  = wbuf + 8 * D2;        // [8M, 12M)

    const int M = BB * CC;  // 4096 rows
    const int CASTL = (int)(12 * D2 / 8 / 256);         // 6144 blocks

    rope_init_kernel<<<CC * 32 / 256, 256, 0, stream>>>(cosT, sinT);
    scan_kernel<<<BB, 1024, 0, stream>>>(boundary, starts, nch);
    latents_kernel<<<dim3(CC, BB), 256, 0, stream>>>(x, starts, h, x0);
    rmsmix_kernel<<<M, 256, 0, stream>>>(h, x0, rmix, h, xnb);   // layer-0 entry

    for (int l = 0; l < LL; ++l) {
        // one mega-cast for all this layer's weights
        castlayer_kernel<<<CASTL, 256, 0, stream>>>(Wq + l * D2, Wk + l * D2, Wv + l * D2,
                                                    Wo + l * D2,
                                                    fcw + (size_t)l * DFF * DD,
                                                    projw + (size_t)l * DD * DFF, wbuf);
        // fused QKV: C[M,3072] routed -> qb(f32), kb(f32), vbb(bf16)
        gemm_bf16<3><<<dim3(3 * DD / 128, M / 128, 1), 256, 0, stream>>>(
            xnb, wqkv, qb, kb, vbb, M, 3 * DD, DD, DD, DD, 0);
        // per-head RMS + RoPE -> bf16 (q with gain/8 folded)
        qknorm2_kernel<<<dim3((BB * CC * HH * 64) / 256, 2), 256, 0, stream>>>(
            qb, kb, qbb, kbb, cosT, sinT, qg + l * HH);
        // V transpose (once), then MFMA attention -> ybf (QBLK=128, 8 waves / 512 thr)
        vtrans_kernel<<<dim3(CC / 64, HH, BB), 256, 0, stream>>>(vbb, vtb);
        attn_mfma<<<dim3(8, HH, BB), 512, 0, stream>>>(qbb, kbb, vtb, ybf, qg + l * HH);
        // a = y @ Wo^T, split-K=2 -> partials qb,kb; fused resid+rms -> xnb
        gemm_bf16<0><<<dim3(DD / 128, M / 128, 2), 256, 0, stream>>>(
            ybf, wwo, qb, nullptr, nullptr, M, DD, DD / 2, DD, DD, NTOK);
        residrms_kernel<0><<<M, 256, 0, stream>>>(h, qb, kb, ascale + l * DD,
                                                  nullptr, nullptr, xnb);
        // MLP: fc (relu^2, bf16) then proj split-K=2
        gemm_bf16<1><<<dim3(DFF / 128, M / 128, 1), 256, 0, stream>>>(
            xnb, wfc, nullptr, nullptr, hidb, M, DFF, DD, DD, DD, 0);
        gemm_bf16<0><<<dim3(DD / 128, M / 128, 2), 256, 0, stream>>>(
            hidb, wpj, qb, nullptr, nullptr, M, DD, DFF / 2, DFF, DFF, NTOK);
        if (l < LL - 1) {
            residrms_kernel<1><<<M, 256, 0, stream>>>(h, qb, kb, mscale + l * DD,
                                                      x0, rmix + (size_t)(l + 1) * 2 * DD, xnb);
        } else {
            residmask_kernel<<<(int)(NTOK / 4 / 256), 256, 0, stream>>>(
                h, qb, kb, mscale + l * DD, nch, out);
        }
    }
}

// Round 11
// 952.622 us; speedup vs baseline: 1.3880x; 1.0262x over previous
//
#include <hip/hip_runtime.h>
#include <math.h>

// Problem constants (fixed by reference)
#define BB   4
#define SS   4096
#define DD   1024
#define HH   16
#define HDIM 64
#define CC   1024      // MAX_CHUNKS
#define DFF  4096
#define LL   4

static constexpr float F32_EPS = 1.1920928955078125e-07f;  // jnp.finfo(f32).eps

typedef __attribute__((ext_vector_type(8))) __bf16 bf16x8;
typedef __attribute__((ext_vector_type(4))) float  f32x4;

__device__ __forceinline__ uint f2bf(float f) {
    uint u = __float_as_uint(f);
    return (u + 0x7fffu + ((u >> 16) & 1u)) >> 16;   // RNE
}
__device__ __forceinline__ float bf2f(uint u) {
    return __uint_as_float(u << 16);
}

// direct global->LDS DMA, 16 bytes per lane; lds dest must be wave-uniform
__device__ __forceinline__ void gl_lds16(const ushort* g, ushort* l) {
    __builtin_amdgcn_global_load_lds(
        (const __attribute__((address_space(1))) unsigned int*)g,
        (__attribute__((address_space(3))) unsigned int*)l, 16, 0, 0);
}

// ---------------- per-layer mega-cast: all 5 weight mats f32 -> bf16 in one launch --------
__global__ __launch_bounds__(256) void castlayer_kernel(const float* __restrict__ Wq,
                                                        const float* __restrict__ Wk,
                                                        const float* __restrict__ Wv,
                                                        const float* __restrict__ Wo,
                                                        const float* __restrict__ fc,
                                                        const float* __restrict__ proj,
                                                        ushort* __restrict__ out) {
    int i = blockIdx.x * blockDim.x + threadIdx.x;      // 8-elem chunk id, 0..12M/8
    const int U = DD * DD / 8;                          // 131072
    const float* src;
    if (i < 3 * U) {
        src = (i < U ? Wq : (i < 2 * U ? Wk : Wv)) + (size_t)(i < U ? i : (i < 2*U ? i-U : i-2*U)) * 8;
    } else if (i < 4 * U) {
        src = Wo + (size_t)(i - 3 * U) * 8;
    } else if (i < 8 * U) {
        src = fc + (size_t)(i - 4 * U) * 8;
    } else {
        src = proj + (size_t)(i - 8 * U) * 8;
    }
    const float4* p = (const float4*)src;
    float4 a = p[0], b = p[1];
    uint4 o;
    o.x = f2bf(a.x) | (f2bf(a.y) << 16);
    o.y = f2bf(a.z) | (f2bf(a.w) << 16);
    o.z = f2bf(b.x) | (f2bf(b.y) << 16);
    o.w = f2bf(b.z) | (f2bf(b.w) << 16);
    *(uint4*)(out + (size_t)i * 8) = o;
}

// ---------------- RoPE tables ----------------
__global__ void rope_init_kernel(float* __restrict__ cosT, float* __restrict__ sinT) {
    int idx = blockIdx.x * blockDim.x + threadIdx.x;   // over CC*32
    int pos = idx >> 5;
    int i   = idx & 31;
    float inv = powf(10000.0f, -(float)i / 32.0f);
    float f = (float)pos * inv;
    cosT[idx] = cosf(f);
    sinT[idx] = sinf(f);
}

// ---------------- boundary scan -> chunk starts, num_chunks ----------------
__global__ __launch_bounds__(1024) void scan_kernel(const int* __restrict__ boundary,
                                                    int* __restrict__ starts,
                                                    int* __restrict__ nch) {
    __shared__ int tmp[1024];
    int b = blockIdx.x, t = threadIdx.x;
    int base = b * SS + t * 4;
    int v0 = boundary[base + 0], v1 = boundary[base + 1];
    int v2 = boundary[base + 2], v3 = boundary[base + 3];
    int p0 = v0, p1 = p0 + v1, p2 = p1 + v2, p3 = p2 + v3;
    tmp[t] = p3;
    __syncthreads();
    for (int off = 1; off < 1024; off <<= 1) {
        int add = (t >= off) ? tmp[t - off] : 0;
        __syncthreads();
        tmp[t] += add;
        __syncthreads();
    }
    int excl = tmp[t] - p3;
    if (v0) starts[b * (CC + 1) + (excl + p0 - 1)] = t * 4 + 0;
    if (v1) starts[b * (CC + 1) + (excl + p1 - 1)] = t * 4 + 1;
    if (v2) starts[b * (CC + 1) + (excl + p2 - 1)] = t * 4 + 2;
    if (v3) starts[b * (CC + 1) + (excl + p3 - 1)] = t * 4 + 3;
    int total = tmp[1023];
    if (t == 0) nch[b] = total;
    for (int c = t; c <= CC; c += 1024)
        if (c >= total) starts[b * (CC + 1) + c] = SS;
}

// ---------------- chunk means -> h and x0 ----------------
__global__ __launch_bounds__(256) void latents_kernel(const float* __restrict__ x,
                                                      const int* __restrict__ starts,
                                                      float* __restrict__ h,
                                                      float* __restrict__ x0) {
    int c = blockIdx.x, b = blockIdx.y, t = threadIdx.x;
    int s0 = starts[b * (CC + 1) + c];
    int s1 = starts[b * (CC + 1) + c + 1];
    float a0 = 0.f, a1 = 0.f, a2 = 0.f, a3 = 0.f;
    for (int r = s0; r < s1; ++r) {
        const float4 xv = *(const float4*)&x[((size_t)(b * SS + r)) * DD + t * 4];
        a0 += xv.x; a1 += xv.y; a2 += xv.z; a3 += xv.w;
    }
    float inv = (s1 > s0) ? 1.0f / (float)(s1 - s0) : 0.0f;
    float4 o = make_float4(a0 * inv, a1 * inv, a2 * inv, a3 * inv);
    size_t off = ((size_t)(b * CC + c)) * DD + t * 4;
    *(float4*)&h[off]  = o;
    *(float4*)&x0[off] = o;
}

// ---------------- resid-mix + row RMS norm (layer-0 entry), bf16 normed out ----------------
__global__ __launch_bounds__(256) void rmsmix_kernel(const float* __restrict__ hin,
                                                     const float* __restrict__ x0,
                                                     const float* __restrict__ mix,
                                                     float* __restrict__ hout,
                                                     ushort* __restrict__ xnout) {
    int row = blockIdx.x, t = threadIdx.x;
    size_t off = (size_t)row * DD + t * 4;
    float4 hv = *(const float4*)&hin[off];
    float4 m0 = *(const float4*)&mix[t * 4];
    float4 m1 = *(const float4*)&mix[DD + t * 4];
    float4 xv = *(const float4*)&x0[off];
    hv.x = m0.x * hv.x + m1.x * xv.x;
    hv.y = m0.y * hv.y + m1.y * xv.y;
    hv.z = m0.z * hv.z + m1.z * xv.z;
    hv.w = m0.w * hv.w + m1.w * xv.w;
    float ss = hv.x * hv.x + hv.y * hv.y + hv.z * hv.z + hv.w * hv.w;
    for (int o = 32; o; o >>= 1) ss += __shfl_xor(ss, o);
    __shared__ float wsum[4];
    int lane = t & 63, wid = t >> 6;
    if (lane == 0) wsum[wid] = ss;
    __syncthreads();
    float tot = wsum[0] + wsum[1] + wsum[2] + wsum[3];
    float r = rsqrtf(tot * (1.0f / DD) + F32_EPS);
    *(float4*)&hout[off] = hv;
    uint2 pk;
    pk.x = f2bf(hv.x * r) | (f2bf(hv.y * r) << 16);
    pk.y = f2bf(hv.z * r) | (f2bf(hv.w * r) << 16);
    *(uint2*)&xnout[off] = pk;
}

// ---------------- fused: h += scale*(a0+a1); [h = m0*h+m1*x0]; xn = bf16(rms(h)) ---------
// a0/a1 are bf16 split-K partials.
template <int HASMIX>
__global__ __launch_bounds__(256) void residrms_kernel(float* __restrict__ h,
                                                       const ushort* __restrict__ a0,
                                                       const ushort* __restrict__ a1,
                                                       const float* __restrict__ scale,
                                                       const float* __restrict__ x0,
                                                       const float* __restrict__ mix,
                                                       ushort* __restrict__ xnout) {
    int row = blockIdx.x, t = threadIdx.x;
    size_t off = (size_t)row * DD + t * 4;
    float4 hv = *(const float4*)&h[off];
    uint2 pa = *(const uint2*)&a0[off];
    uint2 pb = *(const uint2*)&a1[off];
    float4 sv = *(const float4*)&scale[t * 4];
    hv.x += sv.x * (bf2f(pa.x & 0xffff) + bf2f(pb.x & 0xffff));
    hv.y += sv.y * (bf2f(pa.x >> 16)    + bf2f(pb.x >> 16));
    hv.z += sv.z * (bf2f(pa.y & 0xffff) + bf2f(pb.y & 0xffff));
    hv.w += sv.w * (bf2f(pa.y >> 16)    + bf2f(pb.y >> 16));
    if (HASMIX) {
        float4 m0 = *(const float4*)&mix[t * 4];
        float4 m1 = *(const float4*)&mix[DD + t * 4];
        float4 xv = *(const float4*)&x0[off];
        hv.x = m0.x * hv.x + m1.x * xv.x;
        hv.y = m0.y * hv.y + m1.y * xv.y;
        hv.z = m0.z * hv.z + m1.z * xv.z;
        hv.w = m0.w * hv.w + m1.w * xv.w;
    }
    float ss = hv.x * hv.x + hv.y * hv.y + hv.z * hv.z + hv.w * hv.w;
    for (int o = 32; o; o >>= 1) ss += __shfl_xor(ss, o);
    __shared__ float wsum[4];
    int lane = t & 63, wid = t >> 6;
    if (lane == 0) wsum[wid] = ss;
    __syncthreads();
    float tot = wsum[0] + wsum[1] + wsum[2] + wsum[3];
    float r = rsqrtf(tot * (1.0f / DD) + F32_EPS);
    *(float4*)&h[off] = hv;
    uint2 pk;
    pk.x = f2bf(hv.x * r) | (f2bf(hv.y * r) << 16);
    pk.y = f2bf(hv.z * r) | (f2bf(hv.w * r) << 16);
    *(uint2*)&xnout[off] = pk;
}

// ---------------- bf16 MFMA GEMM, 2-phase double-buffered pipeline ----------------
// All outputs bf16 now.
// EPI 0: bf16 partial store to C0 + zt*partStride (split-K)
// EPI 1: relu(x)^2 bf16 store to C0
// EPI 3: fused QKV routing: n<1024 -> C0, n<2048 -> C1, else C2; ldc=1024
template <int EPI>
__global__ __launch_bounds__(256) void gemm_bf16(const ushort* __restrict__ A,
                                                 const ushort* __restrict__ W,
                                                 ushort* __restrict__ C0,
                                                 ushort* __restrict__ C1,
                                                 ushort* __restrict__ C2,
                                                 int M, int N, int K, int lda, int ldw,
                                                 size_t partStride) {
    __shared__ __align__(16) ushort Als[2][128 * 64];
    __shared__ __align__(16) ushort Wls[2][128 * 64];
    const int tid  = threadIdx.x;
    const int wid  = tid >> 6, lane = tid & 63;
    const int wr   = wid >> 1, wc   = wid & 1;
    const int l15  = lane & 15, lhi = lane >> 4;

    const int gx = gridDim.x, gy = gridDim.y;
    int i = (blockIdx.z * gy + blockIdx.y) * gx + blockIdx.x;
    int G = gx * gy * (int)gridDim.z;
    int v = (i & 7) * (G >> 3) + (i >> 3);
    int mt = v % gy;
    int rest = v / gy;
    int nt = rest % gx;
    int zt = rest / gx;
    const int mbase = mt * 128, nbase = nt * 128;

    A  += (size_t)zt * K;
    W  += (size_t)zt * K;
    C0 += (size_t)zt * partStride;

    const int srow8  = lane >> 3;
    const int gchunk = ((lane & 7) ^ srow8) * 8;
    const ushort* Ag = A + (size_t)(mbase + wid * 32 + srow8) * lda + gchunk;
    const ushort* Wg = W + (size_t)(nbase + wid * 32 + srow8) * ldw + gchunk;
    const int ldsoff = (wid * 32) * 64;

    f32x4 acc[4][4] = {};
    const int swz  = (l15 & 7) << 3;
    const int aoff = (wr * 64 + l15) * 64;
    const int woff = (wc * 64 + l15) * 64;

    auto STAGE = [&](ushort* Alb, ushort* Wlb, int kk) {
#pragma unroll
        for (int s = 0; s < 4; ++s) {
            gl_lds16(Ag + kk + (size_t)s * 8 * lda, Alb + ldsoff + s * 8 * 64);
            gl_lds16(Wg + kk + (size_t)s * 8 * ldw, Wlb + ldsoff + s * 8 * 64);
        }
    };
    auto COMPUTE = [&](const ushort* Ab, const ushort* Wb) {
#pragma unroll
        for (int ks = 0; ks < 2; ++ks) {
            const int fcol = (ks * 32 + lhi * 8) ^ swz;
            bf16x8 af[4], bfm[4];
#pragma unroll
            for (int m = 0; m < 4; ++m)
                af[m] = *(const bf16x8*)(Ab + aoff + m * 1024 + fcol);
#pragma unroll
            for (int n = 0; n < 4; ++n)
                bfm[n] = *(const bf16x8*)(Wb + woff + n * 1024 + fcol);
#pragma unroll
            for (int m = 0; m < 4; ++m)
#pragma unroll
                for (int n = 0; n < 4; ++n)
                    acc[m][n] = __builtin_amdgcn_mfma_f32_16x16x32_bf16(
                        af[m], bfm[n], acc[m][n], 0, 0, 0);
        }
    };

    STAGE(Als[0], Wls[0], 0);
    __syncthreads();
    for (int k0 = 0; k0 < K; k0 += 128) {
        if (k0 + 64 < K) STAGE(Als[1], Wls[1], k0 + 64);
        COMPUTE(Als[0], Wls[0]);
        __syncthreads();
        if (k0 + 128 < K) STAGE(Als[0], Wls[0], k0 + 128);
        COMPUTE(Als[1], Wls[1]);
        __syncthreads();
    }

    // epilogue (all-bf16 stores)
    ushort* dst = C0;
    int colb = nbase;
    if (EPI == 3) {
        if (nbase < 1024)      { dst = C0; colb = nbase; }
        else if (nbase < 2048) { dst = C1; colb = nbase - 1024; }
        else                   { dst = C2; colb = nbase - 2048; }
    }
    const int ldc = (EPI == 3) ? 1024 : N;
    const int row0 = mbase + wr * 64 + lhi * 4;
    const int col0 = colb + wc * 64 + l15;
#pragma unroll
    for (int m = 0; m < 4; ++m)
#pragma unroll
        for (int n = 0; n < 4; ++n) {
            int cc = col0 + n * 16;
#pragma unroll
            for (int r = 0; r < 4; ++r) {
                int rr = row0 + m * 16 + r;
                float v2 = acc[m][n][r];
                if (EPI == 1) { v2 = fmaxf(v2, 0.0f); v2 = v2 * v2; }
                dst[(size_t)rr * ldc + cc] = (ushort)f2bf(v2);
            }
        }
}

// ---------------- per-head RMS + RoPE, IN PLACE on bf16 q/k; q gets gain*0.125 folded ------
__global__ __launch_bounds__(256) void qknorm2_kernel(ushort* __restrict__ qbuf,
                                                      ushort* __restrict__ kbuf,
                                                      const float* __restrict__ cosT,
                                                      const float* __restrict__ sinT,
                                                      const float* __restrict__ gain) {
    int which = blockIdx.y;
    ushort* dst = which ? kbuf : qbuf;
    int gid = blockIdx.x * blockDim.x + threadIdx.x;
    int gw = gid >> 6, lane = gid & 63;
    int head = gw & (HH - 1);
    int c = (gw >> 4) & (CC - 1);
    int b = gw >> 14;
    size_t off = ((size_t)(b * CC + c)) * DD + head * HDIM + lane;
    float v = bf2f(dst[off]);
    float ss = v * v;
    for (int o = 32; o; o >>= 1) ss += __shfl_xor(ss, o);
    float r = rsqrtf(ss * (1.0f / HDIM) + F32_EPS);
    float vn = v * r;
    float other = __shfl_xor(vn, 32);
    int i = lane & 31;
    float cv = cosT[c * 32 + i], sv = sinT[c * 32 + i];
    float out = (lane < 32) ? (vn * cv + other * sv) : (vn * cv - other * sv);
    if (which == 0) out *= gain[head] * 0.125f;   // fold 1/sqrt(HD) into q (exact pow2)
    dst[off] = (ushort)f2bf(out);
}

// ---------------- V transpose: v[b*CC+kv][h*64+d] -> vt[(b*16+h)*64+d][kv] ----------------
__global__ __launch_bounds__(256) void vtrans_kernel(const ushort* __restrict__ v,
                                                     ushort* __restrict__ vt) {
    __shared__ ushort Ls[64][72];
    int kt = blockIdx.x, head = blockIdx.y, b = blockIdx.z;
    int tid = threadIdx.x;
    int r = tid >> 3;               // 0..31
    int ch = (tid & 7) * 8;         // element chunk
#pragma unroll
    for (int s = 0; s < 2; ++s) {
        int kv = r + s * 32;
        int4 t4 = *(const int4*)&v[((size_t)(b * CC + kt * 64 + kv)) * DD + head * HDIM + ch];
        *(int4*)&Ls[kv][ch] = t4;
    }
    __syncthreads();
#pragma unroll
    for (int s = 0; s < 2; ++s) {
        int d = r + s * 32;
        ushort o[8];
#pragma unroll
        for (int j = 0; j < 8; ++j) o[j] = Ls[ch + j][d];
        *(int4*)&vt[((size_t)((b * HH + head) * HDIM + d)) * CC + kt * 64 + ch] = *(int4*)o;
    }
}

// ---------------- bf16 MFMA causal flash attention: QBLK=128, 8 waves (512 thr),
// static-max softmax, T14 async-stage (K/V prefetched to regs one tile ahead) ----------------
__global__ __launch_bounds__(512) void attn_mfma(const ushort* __restrict__ q,
                                                 const ushort* __restrict__ k,
                                                 const ushort* __restrict__ vt,
                                                 ushort* __restrict__ y,
                                                 const float* __restrict__ gain) {
    __shared__ __align__(16) ushort Qs[128 * 64]; // [qrow][d  ^ sw]
    __shared__ __align__(16) ushort Ks[64 * 64];  // [kv]  [d  ^ sw]
    __shared__ __align__(16) ushort VT[64 * 64];  // [d]   [kv ^ sw]
    __shared__ __align__(16) ushort Ps[128 * 64]; // [qrow][kv ^ sw] (wave-private rows)
    const int qt = 7 - blockIdx.x;                // longest-first dispatch (qt = 0..7)
    const int head = blockIdx.y, b = blockIdx.z;
    const int tid = threadIdx.x;
    const int wid = tid >> 6, lane = tid & 63;    // 8 waves (512 threads), 16 q-rows each
    const int l15 = lane & 15, lhi = lane >> 4;
    const int wq0 = wid * 16;                     // 0..112
    const int qbase = qt * 128;
    const float mstat = 8.0f * fabsf(gain[head]); // static softmax max bound

    const int srow = tid >> 3;            // 0..63 (512 threads)
    const int scol = (tid & 7) * 8;       // 0..56 step 8

    // stage Q once (128 rows, 2 passes of 64 rows)
#pragma unroll
    for (int s = 0; s < 2; ++s) {
        int r = srow + s * 64;
        int4 t4 = *(const int4*)&q[((size_t)(b * CC + qbase + r)) * DD + head * HDIM + scol];
        *(int4*)&Qs[r * 64 + (scol ^ ((r & 7) << 3))] = t4;
    }

    f32x4 oacc[4] = {};
    float lpart[4] = {0.f, 0.f, 0.f, 0.f};

    const int NT = 2 * qt + 2;            // KV tiles (always even)

    auto LOADK = [&](int4& kr, int4& vr, int kt_) {
        kr = *(const int4*)&k[((size_t)(b * CC + kt_ * 64 + srow)) * DD + head * HDIM + scol];
        vr = *(const int4*)&vt[((size_t)((b * HH + head) * HDIM + srow)) * CC + kt_ * 64 + scol];
    };
    auto WRITEK = [&](const int4& kr, const int4& vr) {
        *(int4*)&Ks[srow * 64 + (scol ^ ((srow & 7) << 3))] = kr;
        *(int4*)&VT[srow * 64 + (scol ^ ((srow & 7) << 3))] = vr;
    };
    auto TILE = [&](int kt) {
        f32x4 sac[4] = {};
        __builtin_amdgcn_s_setprio(1);
#pragma unroll
        for (int ks = 0; ks < 2; ++ks) {
            int dcol = ks * 32 + lhi * 8;
            int arow = wq0 + l15;
            bf16x8 af = *(const bf16x8*)&Qs[arow * 64 + (dcol ^ ((arow & 7) << 3))];
#pragma unroll
            for (int n = 0; n < 4; ++n) {
                int krow = n * 16 + l15;
                bf16x8 bfr = *(const bf16x8*)&Ks[krow * 64 + (dcol ^ ((krow & 7) << 3))];
                sac[n] = __builtin_amdgcn_mfma_f32_16x16x32_bf16(af, bfr, sac[n], 0, 0, 0);
            }
        }
        __builtin_amdgcn_s_setprio(0);

        if (kt >= 2 * qt) {               // diagonal-region tiles (last two)
            const int kb0 = kt * 64;
#pragma unroll
            for (int r = 0; r < 4; ++r) {
                int qrow_g = qbase + wq0 + lhi * 4 + r;
                float p0 = __expf(sac[0][r] - mstat);
                float p1 = __expf(sac[1][r] - mstat);
                float p2 = __expf(sac[2][r] - mstat);
                float p3 = __expf(sac[3][r] - mstat);
                if (kb0 + l15      > qrow_g) p0 = 0.f;
                if (kb0 + 16 + l15 > qrow_g) p1 = 0.f;
                if (kb0 + 32 + l15 > qrow_g) p2 = 0.f;
                if (kb0 + 48 + l15 > qrow_g) p3 = 0.f;
                lpart[r] += (p0 + p1) + (p2 + p3);
                int qrow_l = wq0 + lhi * 4 + r;
                int pb = qrow_l * 64, sw = (qrow_l & 7) << 3;
                Ps[pb + ((l15)      ^ sw)] = (ushort)f2bf(p0);
                Ps[pb + ((16 + l15) ^ sw)] = (ushort)f2bf(p1);
                Ps[pb + ((32 + l15) ^ sw)] = (ushort)f2bf(p2);
                Ps[pb + ((48 + l15) ^ sw)] = (ushort)f2bf(p3);
            }
        } else {
#pragma unroll
            for (int r = 0; r < 4; ++r) {
                float p0 = __expf(sac[0][r] - mstat);
                float p1 = __expf(sac[1][r] - mstat);
                float p2 = __expf(sac[2][r] - mstat);
                float p3 = __expf(sac[3][r] - mstat);
                lpart[r] += (p0 + p1) + (p2 + p3);
                int qrow_l = wq0 + lhi * 4 + r;
                int pb = qrow_l * 64, sw = (qrow_l & 7) << 3;
                Ps[pb + ((l15)      ^ sw)] = (ushort)f2bf(p0);
                Ps[pb + ((16 + l15) ^ sw)] = (ushort)f2bf(p1);
                Ps[pb + ((32 + l15) ^ sw)] = (ushort)f2bf(p2);
                Ps[pb + ((48 + l15) ^ sw)] = (ushort)f2bf(p3);
            }
        }

        __builtin_amdgcn_s_setprio(1);
#pragma unroll
        for (int ks = 0; ks < 2; ++ks) {
            int kcol = ks * 32 + lhi * 8;
            int arow = wq0 + l15;
            bf16x8 pf = *(const bf16x8*)&Ps[arow * 64 + (kcol ^ ((arow & 7) << 3))];
#pragma unroll
            for (int n = 0; n < 4; ++n) {
                int vrow = n * 16 + l15;
                bf16x8 vf = *(const bf16x8*)&VT[vrow * 64 + (kcol ^ ((vrow & 7) << 3))];
                oacc[n] = __builtin_amdgcn_mfma_f32_16x16x32_bf16(pf, vf, oacc[n], 0, 0, 0);
            }
        }
        __builtin_amdgcn_s_setprio(0);
    };

    // T14 2-step pipeline: regs loaded one tile ahead, written after the barrier
    int4 kra, vra, krb, vrb;
    LOADK(kra, vra, 0);
    for (int kt = 0; kt < NT; kt += 2) {
        __syncthreads();                  // prior tile's LDS reads done
        WRITEK(kra, vra);                 // (compiler inserts vmcnt wait on kra/vra)
        __syncthreads();
        LOADK(krb, vrb, kt + 1);          // flies under TILE(kt)
        TILE(kt);
        __syncthreads();
        WRITEK(krb, vrb);
        __syncthreads();
        if (kt + 2 < NT) LOADK(kra, vra, kt + 2);
        TILE(kt + 1);
    }

    // single deferred row-sum reduce (16 lanes per row), then divide + store
#pragma unroll
    for (int r = 0; r < 4; ++r) {
        float ls = lpart[r];
#pragma unroll
        for (int off = 1; off < 16; off <<= 1) ls += __shfl_xor(ls, off);
        float inv = 1.0f / ls;
        int qrow_g = qbase + wq0 + lhi * 4 + r;
        size_t base = ((size_t)(b * CC + qrow_g)) * DD + head * HDIM;
#pragma unroll
        for (int n = 0; n < 4; ++n)
            y[base + n * 16 + l15] = (ushort)f2bf(oacc[n][r] * inv);
    }
}

// ---------------- final: out = (h + scale*(a0+a1)) * valid  (bf16 partials) ----------------
__global__ void residmask_kernel(const float* __restrict__ h, const ushort* __restrict__ a0,
                                 const ushort* __restrict__ a1,
                                 const float* __restrict__ scale,
                                 const int* __restrict__ nch,
                                 float* __restrict__ out) {
    int idx = blockIdx.x * blockDim.x + threadIdx.x;   // per float4
    size_t off = (size_t)idx * 4;
    int c = (idx >> 8) & (CC - 1);
    int b = idx >> 18;
    float4 hv = *(const float4*)&h[off];
    uint2 pa = *(const uint2*)&a0[off];
    uint2 pb = *(const uint2*)&a1[off];
    float4 sv = *(const float4*)&scale[(idx & 255) * 4];
    hv.x += sv.x * (bf2f(pa.x & 0xffff) + bf2f(pb.x & 0xffff));
    hv.y += sv.y * (bf2f(pa.x >> 16)    + bf2f(pb.x >> 16));
    hv.z += sv.z * (bf2f(pa.y & 0xffff) + bf2f(pb.y & 0xffff));
    hv.w += sv.w * (bf2f(pa.y >> 16)    + bf2f(pb.y >> 16));
    if (c >= nch[b]) hv = make_float4(0.f, 0.f, 0.f, 0.f);
    *(float4*)&out[off] = hv;
}

extern "C" void kernel_launch(void* const* d_in, const int* in_sizes, int n_in,
                              void* d_out, int out_size, void* d_ws, size_t ws_size,
                              hipStream_t stream) {
    const float* x        = (const float*)d_in[0];
    const int*   boundary = (const int*)d_in[1];
    const float* Wq       = (const float*)d_in[2];
    const float* Wk       = (const float*)d_in[3];
    const float* Wv       = (const float*)d_in[4];
    const float* Wo       = (const float*)d_in[5];
    const float* qg       = (const float*)d_in[6];
    const float* fcw      = (const float*)d_in[7];
    const float* projw    = (const float*)d_in[8];
    const float* ascale   = (const float*)d_in[9];
    const float* mscale   = (const float*)d_in[10];
    const float* rmix     = (const float*)d_in[11];
    float* out = (float*)d_out;

    const size_t NTOK = (size_t)BB * CC * DD;           // 4M elems
    const size_t NHID = (size_t)BB * CC * DFF;          // 16M elems
    const size_t D2   = (size_t)DD * DD;                // 1M elems

    float* ws   = (float*)d_ws;
    float*  h    = ws;
    float*  x0   = h  + NTOK;
    float*  pbf  = x0 + NTOK;            // 16MB region: bf16 split-K partials (2 x 4M ushort)
    float*  spare= pbf + NTOK;           // (unused f32 lane, kept for layout stability)
    ushort* xnb  = (ushort*)(spare + NTOK);
    ushort* ybf  = xnb + NTOK;
    ushort* hidb = ybf + NTOK;           // 16M bf16; doubles as qbb/kbb/vbb during attn
    ushort* wbuf = hidb + NHID;          // 16M bf16: per-layer weights (mega-cast)
    ushort* vtb  = wbuf + NHID;          // 4M bf16 (V transposed)
    float*  cosT = (float*)(vtb + NTOK);
    float*  sinT = cosT + (size_t)CC * 32;
    int*    starts = (int*)(sinT + (size_t)CC * 32);
    int*    nch    = starts + BB * (CC + 1);

    ushort* pb0 = (ushort*)pbf;          // split-K partial 0 (bf16)
    ushort* pb1 = pb0 + NTOK;            // split-K partial 1 (bf16)

    ushort* qbb = hidb;                  // bf16 q (QKV out, then normed in place)
    ushort* kbb = hidb + NTOK;           // bf16 k
    ushort* vbb = hidb + 2 * NTOK;       // bf16 v

    ushort* wqkv = wbuf;                 // [0, 3M)
    ushort* wwo  = wbuf + 3 * D2;        // [3M, 4M)
    ushort* wfc  = wbuf + 4 * D2;        // [4M, 8M)
    ushort* wpj  = wbuf + 8 * D2;        // [8M, 12M)

    const int M = BB * CC;  // 4096 rows
    const int CASTL = (int)(12 * D2 / 8 / 256);         // 6144 blocks

    rope_init_kernel<<<CC * 32 / 256, 256, 0, stream>>>(cosT, sinT);
    scan_kernel<<<BB, 1024, 0, stream>>>(boundary, starts, nch);
    latents_kernel<<<dim3(CC, BB), 256, 0, stream>>>(x, starts, h, x0);
    rmsmix_kernel<<<M, 256, 0, stream>>>(h, x0, rmix, h, xnb);   // layer-0 entry

    for (int l = 0; l < LL; ++l) {
        // one mega-cast for all this layer's weights
        castlayer_kernel<<<CASTL, 256, 0, stream>>>(Wq + l * D2, Wk + l * D2, Wv + l * D2,
                                                    Wo + l * D2,
                                                    fcw + (size_t)l * DFF * DD,
                                                    projw + (size_t)l * DD * DFF, wbuf);
        // fused QKV: C[M,3072] routed -> qbb, kbb, vbb (all bf16)
        gemm_bf16<3><<<dim3(3 * DD / 128, M / 128, 1), 256, 0, stream>>>(
            xnb, wqkv, qbb, kbb, vbb, M, 3 * DD, DD, DD, DD, 0);
        // per-head RMS + RoPE in place (q with gain/8 folded)
        qknorm2_kernel<<<dim3((BB * CC * HH * 64) / 256, 2), 256, 0, stream>>>(
            qbb, kbb, cosT, sinT, qg + l * HH);
        // V transpose (once), then MFMA attention -> ybf (QBLK=128, 8 waves / 512 thr)
        vtrans_kernel<<<dim3(CC / 64, HH, BB), 256, 0, stream>>>(vbb, vtb);
        attn_mfma<<<dim3(8, HH, BB), 512, 0, stream>>>(qbb, kbb, vtb, ybf, qg + l * HH);
        // a = y @ Wo^T, split-K=2 -> bf16 partials pb0,pb1; fused resid+rms -> xnb
        gemm_bf16<0><<<dim3(DD / 128, M / 128, 2), 256, 0, stream>>>(
            ybf, wwo, pb0, nullptr, nullptr, M, DD, DD / 2, DD, DD, NTOK);
        residrms_kernel<0><<<M, 256, 0, stream>>>(h, pb0, pb1, ascale + l * DD,
                                                  nullptr, nullptr, xnb);
        // MLP: fc (relu^2, bf16) then proj split-K=2 (bf16 partials)
        gemm_bf16<1><<<dim3(DFF / 128, M / 128, 1), 256, 0, stream>>>(
            xnb, wfc, hidb, nullptr, nullptr, M, DFF, DD, DD, DD, 0);
        gemm_bf16<0><<<dim3(DD / 128, M / 128, 2), 256, 0, stream>>>(
            hidb, wpj, pb0, nullptr, nullptr, M, DD, DFF / 2, DFF, DFF, NTOK);
        if (l < LL - 1) {
            residrms_kernel<1><<<M, 256, 0, stream>>>(h, pb0, pb1, mscale + l * DD,
                                                      x0, rmix + (size_t)(l + 1) * 2 * DD, xnb);
        } else {
            residmask_kernel<<<(int)(NTOK / 4 / 256), 256, 0, stream>>>(
                h, pb0, pb1, mscale + l * DD, nch, out);
        }
    }
}

// Round 12
// 849.514 us; speedup vs baseline: 1.5565x; 1.1214x over previous
//
#include <hip/hip_runtime.h>
#include <math.h>

// Problem constants (fixed by reference)
#define BB   4
#define SS   4096
#define DD   1024
#define HH   16
#define HDIM 64
#define CC   1024      // MAX_CHUNKS
#define DFF  4096
#define LL   4

static constexpr float F32_EPS = 1.1920928955078125e-07f;  // jnp.finfo(f32).eps

typedef __attribute__((ext_vector_type(8))) __bf16 bf16x8;
typedef __attribute__((ext_vector_type(4))) float  f32x4;

__device__ __forceinline__ uint f2bf(float f) {
    uint u = __float_as_uint(f);
    return (u + 0x7fffu + ((u >> 16) & 1u)) >> 16;   // RNE
}
__device__ __forceinline__ float bf2f(uint u) {
    return __uint_as_float(u << 16);
}

// direct global->LDS DMA, 16 bytes per lane; lds dest must be wave-uniform
__device__ __forceinline__ void gl_lds16(const ushort* g, ushort* l) {
    __builtin_amdgcn_global_load_lds(
        (const __attribute__((address_space(1))) unsigned int*)g,
        (__attribute__((address_space(3))) unsigned int*)l, 16, 0, 0);
}

// ---------------- per-layer mega-cast: all 5 weight mats f32 -> bf16 in one launch --------
__global__ __launch_bounds__(256) void castlayer_kernel(const float* __restrict__ Wq,
                                                        const float* __restrict__ Wk,
                                                        const float* __restrict__ Wv,
                                                        const float* __restrict__ Wo,
                                                        const float* __restrict__ fc,
                                                        const float* __restrict__ proj,
                                                        ushort* __restrict__ out) {
    int i = blockIdx.x * blockDim.x + threadIdx.x;      // 8-elem chunk id, 0..12M/8
    const int U = DD * DD / 8;                          // 131072
    const float* src;
    if (i < 3 * U) {
        src = (i < U ? Wq : (i < 2 * U ? Wk : Wv)) + (size_t)(i < U ? i : (i < 2*U ? i-U : i-2*U)) * 8;
    } else if (i < 4 * U) {
        src = Wo + (size_t)(i - 3 * U) * 8;
    } else if (i < 8 * U) {
        src = fc + (size_t)(i - 4 * U) * 8;
    } else {
        src = proj + (size_t)(i - 8 * U) * 8;
    }
    const float4* p = (const float4*)src;
    float4 a = p[0], b = p[1];
    uint4 o;
    o.x = f2bf(a.x) | (f2bf(a.y) << 16);
    o.y = f2bf(a.z) | (f2bf(a.w) << 16);
    o.z = f2bf(b.x) | (f2bf(b.y) << 16);
    o.w = f2bf(b.z) | (f2bf(b.w) << 16);
    *(uint4*)(out + (size_t)i * 8) = o;
}

// ---------------- RoPE tables ----------------
__global__ void rope_init_kernel(float* __restrict__ cosT, float* __restrict__ sinT) {
    int idx = blockIdx.x * blockDim.x + threadIdx.x;   // over CC*32
    int pos = idx >> 5;
    int i   = idx & 31;
    float inv = powf(10000.0f, -(float)i / 32.0f);
    float f = (float)pos * inv;
    cosT[idx] = cosf(f);
    sinT[idx] = sinf(f);
}

// ---------------- boundary scan -> chunk starts, num_chunks ----------------
__global__ __launch_bounds__(1024) void scan_kernel(const int* __restrict__ boundary,
                                                    int* __restrict__ starts,
                                                    int* __restrict__ nch) {
    __shared__ int tmp[1024];
    int b = blockIdx.x, t = threadIdx.x;
    int base = b * SS + t * 4;
    int v0 = boundary[base + 0], v1 = boundary[base + 1];
    int v2 = boundary[base + 2], v3 = boundary[base + 3];
    int p0 = v0, p1 = p0 + v1, p2 = p1 + v2, p3 = p2 + v3;
    tmp[t] = p3;
    __syncthreads();
    for (int off = 1; off < 1024; off <<= 1) {
        int add = (t >= off) ? tmp[t - off] : 0;
        __syncthreads();
        tmp[t] += add;
        __syncthreads();
    }
    int excl = tmp[t] - p3;
    if (v0) starts[b * (CC + 1) + (excl + p0 - 1)] = t * 4 + 0;
    if (v1) starts[b * (CC + 1) + (excl + p1 - 1)] = t * 4 + 1;
    if (v2) starts[b * (CC + 1) + (excl + p2 - 1)] = t * 4 + 2;
    if (v3) starts[b * (CC + 1) + (excl + p3 - 1)] = t * 4 + 3;
    int total = tmp[1023];
    if (t == 0) nch[b] = total;
    for (int c = t; c <= CC; c += 1024)
        if (c >= total) starts[b * (CC + 1) + c] = SS;
}

// ---------------- chunk means -> h and x0 ----------------
__global__ __launch_bounds__(256) void latents_kernel(const float* __restrict__ x,
                                                      const int* __restrict__ starts,
                                                      float* __restrict__ h,
                                                      float* __restrict__ x0) {
    int c = blockIdx.x, b = blockIdx.y, t = threadIdx.x;
    int s0 = starts[b * (CC + 1) + c];
    int s1 = starts[b * (CC + 1) + c + 1];
    float a0 = 0.f, a1 = 0.f, a2 = 0.f, a3 = 0.f;
    for (int r = s0; r < s1; ++r) {
        const float4 xv = *(const float4*)&x[((size_t)(b * SS + r)) * DD + t * 4];
        a0 += xv.x; a1 += xv.y; a2 += xv.z; a3 += xv.w;
    }
    float inv = (s1 > s0) ? 1.0f / (float)(s1 - s0) : 0.0f;
    float4 o = make_float4(a0 * inv, a1 * inv, a2 * inv, a3 * inv);
    size_t off = ((size_t)(b * CC + c)) * DD + t * 4;
    *(float4*)&h[off]  = o;
    *(float4*)&x0[off] = o;
}

// ---------------- resid-mix + row RMS norm (layer-0 entry), bf16 normed out ----------------
__global__ __launch_bounds__(256) void rmsmix_kernel(const float* __restrict__ hin,
                                                     const float* __restrict__ x0,
                                                     const float* __restrict__ mix,
                                                     float* __restrict__ hout,
                                                     ushort* __restrict__ xnout) {
    int row = blockIdx.x, t = threadIdx.x;
    size_t off = (size_t)row * DD + t * 4;
    float4 hv = *(const float4*)&hin[off];
    float4 m0 = *(const float4*)&mix[t * 4];
    float4 m1 = *(const float4*)&mix[DD + t * 4];
    float4 xv = *(const float4*)&x0[off];
    hv.x = m0.x * hv.x + m1.x * xv.x;
    hv.y = m0.y * hv.y + m1.y * xv.y;
    hv.z = m0.z * hv.z + m1.z * xv.z;
    hv.w = m0.w * hv.w + m1.w * xv.w;
    float ss = hv.x * hv.x + hv.y * hv.y + hv.z * hv.z + hv.w * hv.w;
    for (int o = 32; o; o >>= 1) ss += __shfl_xor(ss, o);
    __shared__ float wsum[4];
    int lane = t & 63, wid = t >> 6;
    if (lane == 0) wsum[wid] = ss;
    __syncthreads();
    float tot = wsum[0] + wsum[1] + wsum[2] + wsum[3];
    float r = rsqrtf(tot * (1.0f / DD) + F32_EPS);
    *(float4*)&hout[off] = hv;
    uint2 pk;
    pk.x = f2bf(hv.x * r) | (f2bf(hv.y * r) << 16);
    pk.y = f2bf(hv.z * r) | (f2bf(hv.w * r) << 16);
    *(uint2*)&xnout[off] = pk;
}

// ---------------- fused: h += scale*(a0+a1); [h = m0*h+m1*x0]; xn = bf16(rms(h)) ---------
// a0/a1 are bf16 split-K partials.
template <int HASMIX>
__global__ __launch_bounds__(256) void residrms_kernel(float* __restrict__ h,
                                                       const ushort* __restrict__ a0,
                                                       const ushort* __restrict__ a1,
                                                       const float* __restrict__ scale,
                                                       const float* __restrict__ x0,
                                                       const float* __restrict__ mix,
                                                       ushort* __restrict__ xnout) {
    int row = blockIdx.x, t = threadIdx.x;
    size_t off = (size_t)row * DD + t * 4;
    float4 hv = *(const float4*)&h[off];
    uint2 pa = *(const uint2*)&a0[off];
    uint2 pb = *(const uint2*)&a1[off];
    float4 sv = *(const float4*)&scale[t * 4];
    hv.x += sv.x * (bf2f(pa.x & 0xffff) + bf2f(pb.x & 0xffff));
    hv.y += sv.y * (bf2f(pa.x >> 16)    + bf2f(pb.x >> 16));
    hv.z += sv.z * (bf2f(pa.y & 0xffff) + bf2f(pb.y & 0xffff));
    hv.w += sv.w * (bf2f(pa.y >> 16)    + bf2f(pb.y >> 16));
    if (HASMIX) {
        float4 m0 = *(const float4*)&mix[t * 4];
        float4 m1 = *(const float4*)&mix[DD + t * 4];
        float4 xv = *(const float4*)&x0[off];
        hv.x = m0.x * hv.x + m1.x * xv.x;
        hv.y = m0.y * hv.y + m1.y * xv.y;
        hv.z = m0.z * hv.z + m1.z * xv.z;
        hv.w = m0.w * hv.w + m1.w * xv.w;
    }
    float ss = hv.x * hv.x + hv.y * hv.y + hv.z * hv.z + hv.w * hv.w;
    for (int o = 32; o; o >>= 1) ss += __shfl_xor(ss, o);
    __shared__ float wsum[4];
    int lane = t & 63, wid = t >> 6;
    if (lane == 0) wsum[wid] = ss;
    __syncthreads();
    float tot = wsum[0] + wsum[1] + wsum[2] + wsum[3];
    float r = rsqrtf(tot * (1.0f / DD) + F32_EPS);
    *(float4*)&h[off] = hv;
    uint2 pk;
    pk.x = f2bf(hv.x * r) | (f2bf(hv.y * r) << 16);
    pk.y = f2bf(hv.z * r) | (f2bf(hv.w * r) << 16);
    *(uint2*)&xnout[off] = pk;
}

// ---------------- bf16 MFMA GEMM, 2-phase double-buffered pipeline, 512 threads ----------
// 128x128 tile, BK=64, 8 waves in a 4M x 2N grid (per-wave output 32x64, acc[2][4]).
// Staging: global_load_lds w=16, inverse-swizzled source, linear LDS dest; swizzled
// ds_read_b128 fragments (conflict-free). XCD-aware m-fastest remap. K % 128 == 0.
// EPI 0: bf16 partial store to C0 + zt*partStride (split-K)
// EPI 1: relu(x)^2 bf16 store to C0
// EPI 3: fused QKV: q third -> C0 with RMS+RoPE+gain/8; k third -> C1 with RMS+RoPE;
//        v third -> C2 plain. ldc=1024. (wave n-extent = 64 cols = one head band)
template <int EPI>
__global__ __launch_bounds__(512) void gemm_bf16(const ushort* __restrict__ A,
                                                 const ushort* __restrict__ W,
                                                 ushort* __restrict__ C0,
                                                 ushort* __restrict__ C1,
                                                 ushort* __restrict__ C2,
                                                 const float* __restrict__ cosT,
                                                 const float* __restrict__ sinT,
                                                 const float* __restrict__ gain,
                                                 int M, int N, int K, int lda, int ldw,
                                                 size_t partStride) {
    __shared__ __align__(16) ushort Als[2][128 * 64];
    __shared__ __align__(16) ushort Wls[2][128 * 64];
    const int tid  = threadIdx.x;
    const int wid  = tid >> 6, lane = tid & 63;
    const int wr   = wid >> 1, wc   = wid & 1;          // 4x2 wave grid
    const int l15  = lane & 15, lhi = lane >> 4;

    const int gx = gridDim.x, gy = gridDim.y;
    int i = (blockIdx.z * gy + blockIdx.y) * gx + blockIdx.x;
    int G = gx * gy * (int)gridDim.z;
    int v = (i & 7) * (G >> 3) + (i >> 3);
    int mt = v % gy;
    int rest = v / gy;
    int nt = rest % gx;
    int zt = rest / gx;
    const int mbase = mt * 128, nbase = nt * 128;

    A  += (size_t)zt * K;
    W  += (size_t)zt * K;
    C0 += (size_t)zt * partStride;

    // staging: wave w covers rows [w*16, w*16+16) in 2 passes of 8 rows
    const int srow8  = lane >> 3;                       // 0..7
    const int gchunk = ((lane & 7) ^ srow8) * 8;        // inverse-swizzled source chunk
    const ushort* Ag = A + (size_t)(mbase + wid * 16 + srow8) * lda + gchunk;
    const ushort* Wg = W + (size_t)(nbase + wid * 16 + srow8) * ldw + gchunk;
    const int ldsoff = (wid * 16) * 64;                 // wave-uniform LDS base offset

    f32x4 acc[2][4] = {};
    const int swz  = (l15 & 7) << 3;
    const int aoff = (wr * 32 + l15) * 64;
    const int woff = (wc * 64 + l15) * 64;

    auto STAGE = [&](ushort* Alb, ushort* Wlb, int kk) {
#pragma unroll
        for (int s = 0; s < 2; ++s) {
            gl_lds16(Ag + kk + (size_t)s * 8 * lda, Alb + ldsoff + s * 8 * 64);
            gl_lds16(Wg + kk + (size_t)s * 8 * ldw, Wlb + ldsoff + s * 8 * 64);
        }
    };
    auto COMPUTE = [&](const ushort* Ab, const ushort* Wb) {
#pragma unroll
        for (int ks = 0; ks < 2; ++ks) {
            const int fcol = (ks * 32 + lhi * 8) ^ swz;
            bf16x8 af[2], bfm[4];
#pragma unroll
            for (int m = 0; m < 2; ++m)
                af[m] = *(const bf16x8*)(Ab + aoff + m * 1024 + fcol);
#pragma unroll
            for (int n = 0; n < 4; ++n)
                bfm[n] = *(const bf16x8*)(Wb + woff + n * 1024 + fcol);
#pragma unroll
            for (int m = 0; m < 2; ++m)
#pragma unroll
                for (int n = 0; n < 4; ++n)
                    acc[m][n] = __builtin_amdgcn_mfma_f32_16x16x32_bf16(
                        af[m], bfm[n], acc[m][n], 0, 0, 0);
        }
    };

    STAGE(Als[0], Wls[0], 0);
    __syncthreads();
    for (int k0 = 0; k0 < K; k0 += 128) {
        if (k0 + 64 < K) STAGE(Als[1], Wls[1], k0 + 64);
        COMPUTE(Als[0], Wls[0]);
        __syncthreads();
        if (k0 + 128 < K) STAGE(Als[0], Wls[0], k0 + 128);
        COMPUTE(Als[1], Wls[1]);
        __syncthreads();
    }

    const int row0 = mbase + wr * 32 + lhi * 4;

    if (EPI == 3) {
        const int third = nbase >> 10;                  // 0=q, 1=k, 2=v
        const int bandbase = (nbase & 1023) + wc * 64;  // head band start in [0,1024)
        ushort* dst = (third == 0) ? C0 : (third == 1 ? C1 : C2);
        if (third == 2) {
#pragma unroll
            for (int m = 0; m < 2; ++m)
#pragma unroll
                for (int n = 0; n < 4; ++n)
#pragma unroll
                    for (int r = 0; r < 4; ++r) {
                        int rr = row0 + m * 16 + r;
                        dst[(size_t)rr * 1024 + bandbase + n * 16 + l15] =
                            (ushort)f2bf(acc[m][n][r]);
                    }
        } else {
            const int hd = bandbase >> 6;
            const float g = (third == 0) ? gain[hd] * 0.125f : 1.0f;
#pragma unroll
            for (int m = 0; m < 2; ++m)
#pragma unroll
                for (int r = 0; r < 4; ++r) {
                    int rr = row0 + m * 16 + r;
                    float v0 = acc[m][0][r], v1 = acc[m][1][r];
                    float v2 = acc[m][2][r], v3 = acc[m][3][r];
                    float ss = v0 * v0 + v1 * v1 + v2 * v2 + v3 * v3;
#pragma unroll
                    for (int off = 1; off < 16; off <<= 1) ss += __shfl_xor(ss, off);
                    float rn = rsqrtf(ss * (1.0f / HDIM) + F32_EPS);
                    v0 *= rn; v1 *= rn; v2 *= rn; v3 *= rn;
                    int c = rr & (CC - 1);
                    float c0 = cosT[c * 32 + l15],      s0 = sinT[c * 32 + l15];
                    float c1 = cosT[c * 32 + 16 + l15], s1 = sinT[c * 32 + 16 + l15];
                    float o0 = (v0 * c0 + v2 * s0) * g;
                    float o1 = (v1 * c1 + v3 * s1) * g;
                    float o2 = (v2 * c0 - v0 * s0) * g;
                    float o3 = (v3 * c1 - v1 * s1) * g;
                    size_t rbase = (size_t)rr * 1024 + bandbase;
                    dst[rbase + l15]      = (ushort)f2bf(o0);
                    dst[rbase + 16 + l15] = (ushort)f2bf(o1);
                    dst[rbase + 32 + l15] = (ushort)f2bf(o2);
                    dst[rbase + 48 + l15] = (ushort)f2bf(o3);
                }
        }
    } else {
        const int col0 = nbase + wc * 64 + l15;
#pragma unroll
        for (int m = 0; m < 2; ++m)
#pragma unroll
            for (int n = 0; n < 4; ++n) {
                int cc = col0 + n * 16;
#pragma unroll
                for (int r = 0; r < 4; ++r) {
                    int rr = row0 + m * 16 + r;
                    float v2 = acc[m][n][r];
                    if (EPI == 1) { v2 = fmaxf(v2, 0.0f); v2 = v2 * v2; }
                    C0[(size_t)rr * N + cc] = (ushort)f2bf(v2);
                }
            }
    }
}

// ---------------- V transpose: v[b*CC+kv][h*64+d] -> vt[(b*16+h)*64+d][kv] ----------------
__global__ __launch_bounds__(256) void vtrans_kernel(const ushort* __restrict__ v,
                                                     ushort* __restrict__ vt) {
    __shared__ ushort Ls[64][72];
    int kt = blockIdx.x, head = blockIdx.y, b = blockIdx.z;
    int tid = threadIdx.x;
    int r = tid >> 3;               // 0..31
    int ch = (tid & 7) * 8;         // element chunk
#pragma unroll
    for (int s = 0; s < 2; ++s) {
        int kv = r + s * 32;
        int4 t4 = *(const int4*)&v[((size_t)(b * CC + kt * 64 + kv)) * DD + head * HDIM + ch];
        *(int4*)&Ls[kv][ch] = t4;
    }
    __syncthreads();
#pragma unroll
    for (int s = 0; s < 2; ++s) {
        int d = r + s * 32;
        ushort o[8];
#pragma unroll
        for (int j = 0; j < 8; ++j) o[j] = Ls[ch + j][d];
        *(int4*)&vt[((size_t)((b * HH + head) * HDIM + d)) * CC + kt * 64 + ch] = *(int4*)o;
    }
}

// ---------------- bf16 MFMA causal flash attention: QBLK=128, 8 waves (512 thr),
// static-max softmax, T14 async-stage (K/V prefetched to regs one tile ahead) ----------------
__global__ __launch_bounds__(512) void attn_mfma(const ushort* __restrict__ q,
                                                 const ushort* __restrict__ k,
                                                 const ushort* __restrict__ vt,
                                                 ushort* __restrict__ y,
                                                 const float* __restrict__ gain) {
    __shared__ __align__(16) ushort Qs[128 * 64]; // [qrow][d  ^ sw]
    __shared__ __align__(16) ushort Ks[64 * 64];  // [kv]  [d  ^ sw]
    __shared__ __align__(16) ushort VT[64 * 64];  // [d]   [kv ^ sw]
    __shared__ __align__(16) ushort Ps[128 * 64]; // [qrow][kv ^ sw] (wave-private rows)
    const int qt = 7 - blockIdx.x;                // longest-first dispatch (qt = 0..7)
    const int head = blockIdx.y, b = blockIdx.z;
    const int tid = threadIdx.x;
    const int wid = tid >> 6, lane = tid & 63;    // 8 waves (512 threads), 16 q-rows each
    const int l15 = lane & 15, lhi = lane >> 4;
    const int wq0 = wid * 16;                     // 0..112
    const int qbase = qt * 128;
    const float mstat = 8.0f * fabsf(gain[head]); // static softmax max bound

    const int srow = tid >> 3;            // 0..63 (512 threads)
    const int scol = (tid & 7) * 8;       // 0..56 step 8

    // stage Q once (128 rows, 2 passes of 64 rows)
#pragma unroll
    for (int s = 0; s < 2; ++s) {
        int r = srow + s * 64;
        int4 t4 = *(const int4*)&q[((size_t)(b * CC + qbase + r)) * DD + head * HDIM + scol];
        *(int4*)&Qs[r * 64 + (scol ^ ((r & 7) << 3))] = t4;
    }

    f32x4 oacc[4] = {};
    float lpart[4] = {0.f, 0.f, 0.f, 0.f};

    const int NT = 2 * qt + 2;            // KV tiles (always even)

    auto LOADK = [&](int4& kr, int4& vr, int kt_) {
        kr = *(const int4*)&k[((size_t)(b * CC + kt_ * 64 + srow)) * DD + head * HDIM + scol];
        vr = *(const int4*)&vt[((size_t)((b * HH + head) * HDIM + srow)) * CC + kt_ * 64 + scol];
    };
    auto WRITEK = [&](const int4& kr, const int4& vr) {
        *(int4*)&Ks[srow * 64 + (scol ^ ((srow & 7) << 3))] = kr;
        *(int4*)&VT[srow * 64 + (scol ^ ((srow & 7) << 3))] = vr;
    };
    auto TILE = [&](int kt) {
        f32x4 sac[4] = {};
        __builtin_amdgcn_s_setprio(1);
#pragma unroll
        for (int ks = 0; ks < 2; ++ks) {
            int dcol = ks * 32 + lhi * 8;
            int arow = wq0 + l15;
            bf16x8 af = *(const bf16x8*)&Qs[arow * 64 + (dcol ^ ((arow & 7) << 3))];
#pragma unroll
            for (int n = 0; n < 4; ++n) {
                int krow = n * 16 + l15;
                bf16x8 bfr = *(const bf16x8*)&Ks[krow * 64 + (dcol ^ ((krow & 7) << 3))];
                sac[n] = __builtin_amdgcn_mfma_f32_16x16x32_bf16(af, bfr, sac[n], 0, 0, 0);
            }
        }
        __builtin_amdgcn_s_setprio(0);

        if (kt >= 2 * qt) {               // diagonal-region tiles (last two)
            const int kb0 = kt * 64;
#pragma unroll
            for (int r = 0; r < 4; ++r) {
                int qrow_g = qbase + wq0 + lhi * 4 + r;
                float p0 = __expf(sac[0][r] - mstat);
                float p1 = __expf(sac[1][r] - mstat);
                float p2 = __expf(sac[2][r] - mstat);
                float p3 = __expf(sac[3][r] - mstat);
                if (kb0 + l15      > qrow_g) p0 = 0.f;
                if (kb0 + 16 + l15 > qrow_g) p1 = 0.f;
                if (kb0 + 32 + l15 > qrow_g) p2 = 0.f;
                if (kb0 + 48 + l15 > qrow_g) p3 = 0.f;
                lpart[r] += (p0 + p1) + (p2 + p3);
                int qrow_l = wq0 + lhi * 4 + r;
                int pb = qrow_l * 64, sw = (qrow_l & 7) << 3;
                Ps[pb + ((l15)      ^ sw)] = (ushort)f2bf(p0);
                Ps[pb + ((16 + l15) ^ sw)] = (ushort)f2bf(p1);
                Ps[pb + ((32 + l15) ^ sw)] = (ushort)f2bf(p2);
                Ps[pb + ((48 + l15) ^ sw)] = (ushort)f2bf(p3);
            }
        } else {
#pragma unroll
            for (int r = 0; r < 4; ++r) {
                float p0 = __expf(sac[0][r] - mstat);
                float p1 = __expf(sac[1][r] - mstat);
                float p2 = __expf(sac[2][r] - mstat);
                float p3 = __expf(sac[3][r] - mstat);
                lpart[r] += (p0 + p1) + (p2 + p3);
                int qrow_l = wq0 + lhi * 4 + r;
                int pb = qrow_l * 64, sw = (qrow_l & 7) << 3;
                Ps[pb + ((l15)      ^ sw)] = (ushort)f2bf(p0);
                Ps[pb + ((16 + l15) ^ sw)] = (ushort)f2bf(p1);
                Ps[pb + ((32 + l15) ^ sw)] = (ushort)f2bf(p2);
                Ps[pb + ((48 + l15) ^ sw)] = (ushort)f2bf(p3);
            }
        }

        __builtin_amdgcn_s_setprio(1);
#pragma unroll
        for (int ks = 0; ks < 2; ++ks) {
            int kcol = ks * 32 + lhi * 8;
            int arow = wq0 + l15;
            bf16x8 pf = *(const bf16x8*)&Ps[arow * 64 + (kcol ^ ((arow & 7) << 3))];
#pragma unroll
            for (int n = 0; n < 4; ++n) {
                int vrow = n * 16 + l15;
                bf16x8 vf = *(const bf16x8*)&VT[vrow * 64 + (kcol ^ ((vrow & 7) << 3))];
                oacc[n] = __builtin_amdgcn_mfma_f32_16x16x32_bf16(pf, vf, oacc[n], 0, 0, 0);
            }
        }
        __builtin_amdgcn_s_setprio(0);
    };

    // T14 2-step pipeline: regs loaded one tile ahead, written after the barrier
    int4 kra, vra, krb, vrb;
    LOADK(kra, vra, 0);
    for (int kt = 0; kt < NT; kt += 2) {
        __syncthreads();                  // prior tile's LDS reads done
        WRITEK(kra, vra);                 // (compiler inserts vmcnt wait on kra/vra)
        __syncthreads();
        LOADK(krb, vrb, kt + 1);          // flies under TILE(kt)
        TILE(kt);
        __syncthreads();
        WRITEK(krb, vrb);
        __syncthreads();
        if (kt + 2 < NT) LOADK(kra, vra, kt + 2);
        TILE(kt + 1);
    }

    // single deferred row-sum reduce (16 lanes per row), then divide + store
#pragma unroll
    for (int r = 0; r < 4; ++r) {
        float ls = lpart[r];
#pragma unroll
        for (int off = 1; off < 16; off <<= 1) ls += __shfl_xor(ls, off);
        float inv = 1.0f / ls;
        int qrow_g = qbase + wq0 + lhi * 4 + r;
        size_t base = ((size_t)(b * CC + qrow_g)) * DD + head * HDIM;
#pragma unroll
        for (int n = 0; n < 4; ++n)
            y[base + n * 16 + l15] = (ushort)f2bf(oacc[n][r] * inv);
    }
}

// ---------------- final: out = (h + scale*(a0+a1)) * valid  (bf16 partials) ----------------
__global__ void residmask_kernel(const float* __restrict__ h, const ushort* __restrict__ a0,
                                 const ushort* __restrict__ a1,
                                 const float* __restrict__ scale,
                                 const int* __restrict__ nch,
                                 float* __restrict__ out) {
    int idx = blockIdx.x * blockDim.x + threadIdx.x;   // per float4
    size_t off = (size_t)idx * 4;
    int c = (idx >> 8) & (CC - 1);
    int b = idx >> 18;
    float4 hv = *(const float4*)&h[off];
    uint2 pa = *(const uint2*)&a0[off];
    uint2 pb = *(const uint2*)&a1[off];
    float4 sv = *(const float4*)&scale[(idx & 255) * 4];
    hv.x += sv.x * (bf2f(pa.x & 0xffff) + bf2f(pb.x & 0xffff));
    hv.y += sv.y * (bf2f(pa.x >> 16)    + bf2f(pb.x >> 16));
    hv.z += sv.z * (bf2f(pa.y & 0xffff) + bf2f(pb.y & 0xffff));
    hv.w += sv.w * (bf2f(pa.y >> 16)    + bf2f(pb.y >> 16));
    if (c >= nch[b]) hv = make_float4(0.f, 0.f, 0.f, 0.f);
    *(float4*)&out[off] = hv;
}

extern "C" void kernel_launch(void* const* d_in, const int* in_sizes, int n_in,
                              void* d_out, int out_size, void* d_ws, size_t ws_size,
                              hipStream_t stream) {
    const float* x        = (const float*)d_in[0];
    const int*   boundary = (const int*)d_in[1];
    const float* Wq       = (const float*)d_in[2];
    const float* Wk       = (const float*)d_in[3];
    const float* Wv       = (const float*)d_in[4];
    const float* Wo       = (const float*)d_in[5];
    const float* qg       = (const float*)d_in[6];
    const float* fcw      = (const float*)d_in[7];
    const float* projw    = (const float*)d_in[8];
    const float* ascale   = (const float*)d_in[9];
    const float* mscale   = (const float*)d_in[10];
    const float* rmix     = (const float*)d_in[11];
    float* out = (float*)d_out;

    const size_t NTOK = (size_t)BB * CC * DD;           // 4M elems
    const size_t NHID = (size_t)BB * CC * DFF;          // 16M elems
    const size_t D2   = (size_t)DD * DD;                // 1M elems

    float* ws   = (float*)d_ws;
    float*  h    = ws;
    float*  x0   = h  + NTOK;
    float*  pbf  = x0 + NTOK;            // 16MB region: bf16 split-K partials (2 x 4M ushort)
    float*  spare= pbf + NTOK;           // (unused f32 lane, kept for layout stability)
    ushort* xnb  = (ushort*)(spare + NTOK);
    ushort* ybf  = xnb + NTOK;
    ushort* hidb = ybf + NTOK;           // 16M bf16; doubles as qbb/kbb/vbb during attn
    ushort* wbuf = hidb + NHID;          // 16M bf16: per-layer weights (mega-cast)
    ushort* vtb  = wbuf + NHID;          // 4M bf16 (V transposed)
    float*  cosT = (float*)(vtb + NTOK);
    float*  sinT = cosT + (size_t)CC * 32;
    int*    starts = (int*)(sinT + (size_t)CC * 32);
    int*    nch    = starts + BB * (CC + 1);

    ushort* pb0 = (ushort*)pbf;          // split-K partial 0 (bf16)
    ushort* pb1 = pb0 + NTOK;            // split-K partial 1 (bf16)

    ushort* qbb = hidb;                  // bf16 q (normed+RoPE'd by fused epilogue)
    ushort* kbb = hidb + NTOK;           // bf16 k
    ushort* vbb = hidb + 2 * NTOK;       // bf16 v

    ushort* wqkv = wbuf;                 // [0, 3M)
    ushort* wwo  = wbuf + 3 * D2;        // [3M, 4M)
    ushort* wfc  = wbuf + 4 * D2;        // [4M, 8M)
    ushort* wpj  = wbuf + 8 * D2;        // [8M, 12M)

    const int M = BB * CC;  // 4096 rows
    const int CASTL = (int)(12 * D2 / 8 / 256);         // 6144 blocks

    rope_init_kernel<<<CC * 32 / 256, 256, 0, stream>>>(cosT, sinT);
    scan_kernel<<<BB, 1024, 0, stream>>>(boundary, starts, nch);
    latents_kernel<<<dim3(CC, BB), 256, 0, stream>>>(x, starts, h, x0);
    rmsmix_kernel<<<M, 256, 0, stream>>>(h, x0, rmix, h, xnb);   // layer-0 entry

    for (int l = 0; l < LL; ++l) {
        // one mega-cast for all this layer's weights
        castlayer_kernel<<<CASTL, 256, 0, stream>>>(Wq + l * D2, Wk + l * D2, Wv + l * D2,
                                                    Wo + l * D2,
                                                    fcw + (size_t)l * DFF * DD,
                                                    projw + (size_t)l * DD * DFF, wbuf);
        // fused QKV + per-head RMS/RoPE/gain epilogue: -> qbb, kbb (normed), vbb
        gemm_bf16<3><<<dim3(3 * DD / 128, M / 128, 1), 512, 0, stream>>>(
            xnb, wqkv, qbb, kbb, vbb, cosT, sinT, qg + l * HH, M, 3 * DD, DD, DD, DD, 0);
        // V transpose (once), then MFMA attention -> ybf (QBLK=128, 8 waves / 512 thr)
        vtrans_kernel<<<dim3(CC / 64, HH, BB), 256, 0, stream>>>(vbb, vtb);
        attn_mfma<<<dim3(8, HH, BB), 512, 0, stream>>>(qbb, kbb, vtb, ybf, qg + l * HH);
        // a = y @ Wo^T, split-K=2 -> bf16 partials pb0,pb1; fused resid+rms -> xnb
        gemm_bf16<0><<<dim3(DD / 128, M / 128, 2), 512, 0, stream>>>(
            ybf, wwo, pb0, nullptr, nullptr, nullptr, nullptr, nullptr,
            M, DD, DD / 2, DD, DD, NTOK);
        residrms_kernel<0><<<M, 256, 0, stream>>>(h, pb0, pb1, ascale + l * DD,
                                                  nullptr, nullptr, xnb);
        // MLP: fc (relu^2, bf16) then proj split-K=2 (bf16 partials)
        gemm_bf16<1><<<dim3(DFF / 128, M / 128, 1), 512, 0, stream>>>(
            xnb, wfc, hidb, nullptr, nullptr, nullptr, nullptr, nullptr,
            M, DFF, DD, DD, DD, 0);
        gemm_bf16<0><<<dim3(DD / 128, M / 128, 2), 512, 0, stream>>>(
            hidb, wpj, pb0, nullptr, nullptr, nullptr, nullptr, nullptr,
            M, DD, DFF / 2, DFF, DFF, NTOK);
        if (l < LL - 1) {
            residrms_kernel<1><<<M, 256, 0, stream>>>(h, pb0, pb1, mscale + l * DD,
                                                      x0, rmix + (size_t)(l + 1) * 2 * DD, xnb);
        } else {
            residmask_kernel<<<(int)(NTOK / 4 / 256), 256, 0, stream>>>(
                h, pb0, pb1, mscale + l * DD, nch, out);
        }
    }
}